// Round 4
// baseline (319.120 us; speedup 1.0000x reference)
//
#include <hip/hip_runtime.h>
#include <cstdint>
#include <cstddef>
#include <cmath>

#pragma clang fp contract(off)

namespace {

constexpr int kCandMax = 4096;

__device__ __constant__ int c_N[5] = {196608, 49152, 12288, 3072, 768};
__device__ __constant__ int c_K[5] = {1000, 1000, 1000, 1000, 768};

struct RPNParams {
  const float* deltas[5];
  const float* ctr[5];
  const float* anchors[5];
  float* scores;         // [8][5][1024] masked scores, per-level sorted desc
  float* boxes;          // [8][5][1024][4] clipped boxes, per-level sorted
  unsigned char* keep;   // [8][5][1024]
  unsigned int* mask;    // [8][5][1024][32] suppression bits (j in bits, row i)
  unsigned int* ghist0;  // [40][256]
  unsigned int* ghist1;  // [40][256]
  unsigned int* ccount;  // [40] candidate counts
  unsigned int* thresh;  // [40] 16-bit-refined key threshold
  unsigned long long* cand;  // [40][4096] (aliases mask region; used before k_mask)
  float* out;            // [8][1000][5]
};

// monotonic float->uint map (larger float => larger uint)
__device__ __forceinline__ unsigned int fkey(float f) {
  unsigned int u = __float_as_uint(f);
  return (u & 0x80000000u) ? ~u : (u | 0x80000000u);
}

__device__ __forceinline__ unsigned long long shfl64(unsigned long long v, int src) {
  unsigned int lo = __shfl((unsigned int)(v & 0xFFFFFFFFu), src, 64);
  unsigned int hi = __shfl((unsigned int)(v >> 32), src, 64);
  return ((unsigned long long)hi << 32) | (unsigned long long)lo;
}

// ---------------- Phase 1a: 8-bit histogram of score keys ----------------
__global__ __launch_bounds__(256) void k_hist0(RPNParams P) {
  int bl = blockIdx.x, b = bl / 5, l = bl % 5;
  int N = c_N[l];
  int chunk = (N + 31) / 32;
  int i0 = blockIdx.y * chunk;
  int i1 = i0 + chunk; if (i1 > N) i1 = N;
  const float* ctr = P.ctr[l] + (size_t)b * N;
  __shared__ unsigned int wh[4][256];
  int tid = threadIdx.x, wid = tid >> 6;
  for (int i = tid; i < 1024; i += 256) ((unsigned int*)wh)[i] = 0u;
  __syncthreads();
  for (int i = i0 + tid; i < i1; i += 256) {
    unsigned int u = fkey(ctr[i]);
    atomicAdd(&wh[wid][u >> 24], 1u);
  }
  __syncthreads();
  int bin = tid;
  unsigned int s = wh[0][bin] + wh[1][bin] + wh[2][bin] + wh[3][bin];
  if (s) atomicAdd(&P.ghist0[bl * 256 + bin], s);
}

// ---------------- Phase 1b: refine to 16-bit within chosen top byte ------
__global__ __launch_bounds__(256) void k_hist1(RPNParams P) {
  int bl = blockIdx.x, b = bl / 5, l = bl % 5;
  int N = c_N[l], K = c_K[l];
  int chunk = (N + 31) / 32;
  int i0 = blockIdx.y * chunk;
  int i1 = i0 + chunk; if (i1 > N) i1 = N;
  const float* ctr = P.ctr[l] + (size_t)b * N;
  __shared__ unsigned int wh[4][256];
  __shared__ unsigned int sV0;
  int tid = threadIdx.x, wid = tid >> 6;
  if (tid < 256) wh[0][tid] = P.ghist0[bl * 256 + tid];
  __syncthreads();
  if (tid == 0) {
    unsigned int kk = (unsigned int)K, cum = 0;
    int v = 255;
    for (; v > 0; --v) { unsigned int x = wh[0][v]; if (cum + x >= kk) break; cum += x; }
    sV0 = (unsigned int)v;
  }
  __syncthreads();
  unsigned int v0 = sV0;
  for (int i = tid; i < 1024; i += 256) ((unsigned int*)wh)[i] = 0u;
  __syncthreads();
  for (int i = i0 + tid; i < i1; i += 256) {
    unsigned int u = fkey(ctr[i]);
    if ((u >> 24) == v0) atomicAdd(&wh[wid][(u >> 16) & 255u], 1u);
  }
  __syncthreads();
  int bin = tid;
  unsigned int s = wh[0][bin] + wh[1][bin] + wh[2][bin] + wh[3][bin];
  if (s) atomicAdd(&P.ghist1[bl * 256 + bin], s);
}

// ------- Phase 1c: per-(img,lvl) threshold via suffix-scan + bsearch -----
// v0 = max v with S0[v] >= K (S0 = suffix sum of ghist0); kk = K - S0[v0+1];
// v1 = max v with S1[v] >= kk. Identical result to the descending serial
// loop (first break from the top == maximum satisfying v; default 0).
__global__ __launch_bounds__(256) void k_thresh(RPNParams P) {
  int bl = blockIdx.x;
  int K = c_K[bl % 5];
  __shared__ unsigned int S[257];
  __shared__ unsigned int sV0, sKK;
  int tid = threadIdx.x;
  S[tid] = P.ghist0[bl * 256 + tid];
  if (tid == 0) S[256] = 0u;
  __syncthreads();
  for (int d = 1; d < 256; d <<= 1) {
    unsigned int v = (tid + d < 256) ? S[tid + d] : 0u;
    __syncthreads();
    S[tid] += v;
    __syncthreads();
  }
  if (tid == 0) {
    int lo = 0, hi = 255;
    while (lo < hi) { int mid = (lo + hi + 1) >> 1; if (S[mid] >= (unsigned int)K) lo = mid; else hi = mid - 1; }
    sV0 = (unsigned int)lo;
    sKK = (unsigned int)K - S[lo + 1];
  }
  __syncthreads();
  S[tid] = P.ghist1[bl * 256 + tid];
  __syncthreads();
  for (int d = 1; d < 256; d <<= 1) {
    unsigned int v = (tid + d < 256) ? S[tid + d] : 0u;
    __syncthreads();
    S[tid] += v;
    __syncthreads();
  }
  if (tid == 0) {
    unsigned int kk = sKK;
    int lo = 0, hi = 255;
    while (lo < hi) { int mid = (lo + hi + 1) >> 1; if (S[mid] >= kk) lo = mid; else hi = mid - 1; }
    P.thresh[bl] = ((sV0 << 8) | (unsigned int)lo) << 16;
  }
}

// ------- Phase 1d: chip-wide compaction of candidates (key >= T) ---------
__global__ __launch_bounds__(256) void k_compact(RPNParams P) {
  int bl = blockIdx.x, b = bl / 5, l = bl % 5;
  int N = c_N[l];
  int chunk = (N + 31) / 32;
  int i0 = blockIdx.y * chunk;
  int i1 = i0 + chunk; if (i1 > N) i1 = N;
  const float* ctr = P.ctr[l] + (size_t)b * N;
  unsigned int T = P.thresh[bl];
  unsigned long long* cand = P.cand + (size_t)bl * kCandMax;
  int tid = threadIdx.x, lane = tid & 63;
  for (int i = i0 + tid; i < i1; i += 256) {
    unsigned int u = fkey(ctr[i]);
    bool pred = (u >= T);
    unsigned long long m = __ballot(pred);
    if (m) {
      int leader = (int)__builtin_ctzll(m);
      unsigned int base = 0u;
      if (lane == leader) base = atomicAdd(&P.ccount[bl], (unsigned int)__popcll(m));
      base = (unsigned int)__shfl((int)base, leader, 64);
      if (pred) {
        unsigned int pos = base + (unsigned int)__popcll(m & ((1ull << lane) - 1ull));
        if (pos < (unsigned int)kCandMax)
          cand[pos] = ((unsigned long long)u << 32) |
                      (unsigned long long)(0xFFFFFFFFu - (unsigned int)i);
      }
    }
  }
}

// ---- Phase 1e: sort candidates, decode+clip boxes (40 blocks) -----------
__global__ __launch_bounds__(1024) void k_select(RPNParams P) {
  int bl = blockIdx.x, b = bl / 5, l = bl % 5;
  int N = c_N[l], K = c_K[l];
  const float* ctr = P.ctr[l] + (size_t)b * N;
  __shared__ unsigned long long cand[kCandMax];
  int tid = threadIdx.x;
  int cc = (int)P.ccount[bl]; if (cc > kCandMax) cc = kCandMax;
  const unsigned long long* gc = P.cand + (size_t)bl * kCandMax;
  for (int i = tid; i < cc; i += 1024) cand[i] = gc[i];
  int n2 = 1; while (n2 < cc) n2 <<= 1;
  for (int i = cc + tid; i < n2; i += 1024) cand[i] = 0ull;
  __syncthreads();
  // bitonic sort descending by (key desc, idx asc) composite
  for (int size = 2; size <= n2; size <<= 1) {
    for (int stride = size >> 1; stride > 0; stride >>= 1) {
      for (int i = tid; i < n2; i += 1024) {
        int j = i ^ stride;
        if (j > i) {
          unsigned long long a = cand[i], c2 = cand[j];
          bool sw = ((i & size) == 0) ? (a < c2) : (a > c2);
          if (sw) { cand[i] = c2; cand[j] = a; }
        }
      }
      __syncthreads();
    }
  }
  size_t sbase = ((size_t)b * 5 + l) * 1024;
  for (int r = tid; r < K; r += 1024) {
    unsigned long long cv = cand[r];
    unsigned int idx = 0xFFFFFFFFu - (unsigned int)(cv & 0xFFFFFFFFu);
    float s = ctr[idx];
    float4 anc = *(const float4*)(P.anchors[l] + (size_t)idx * 4);
    float4 dd  = *(const float4*)(P.deltas[l] + ((size_t)b * N + idx) * 4);
    // Box2BoxTransformLinear decode (same op order as reference, no fma)
    float w = anc.z - anc.x, hgt = anc.w - anc.y;
    float cx = (anc.x + anc.z) * 0.5f, cy = (anc.y + anc.w) * 0.5f;
    float x1 = cx - dd.x * w;
    float y1 = cy - dd.y * hgt;
    float x2 = cx + dd.z * w;
    float y2 = cy + dd.w * hgt;
    x1 = fminf(fmaxf(x1, 0.0f), 1024.0f);
    y1 = fminf(fmaxf(y1, 0.0f), 1024.0f);
    x2 = fminf(fmaxf(x2, 0.0f), 1024.0f);
    y2 = fminf(fmaxf(y2, 0.0f), 1024.0f);
    bool valid = ((x2 - x1) > 0.0f) && ((y2 - y1) > 0.0f);
    P.scores[sbase + r] = valid ? s : -INFINITY;
    *(float4*)(P.boxes + (sbase + r) * 4) = make_float4(x1, y1, x2, y2);
  }
}

// ---------------- Phase 2a: suppression bitmask (per level) ---------------
// One lane per row i; all lanes sweep the same j together -> every LDS read
// of box j is a same-address broadcast (zero bank conflicts). Boxes stored
// SoA, zero-padded to 1024 so no j<K guard is needed (pad IoU == 0).
__global__ __launch_bounds__(64) void k_mask(RPNParams P) {
  int bl = blockIdx.x, b = bl / 5, l = bl % 5;
  int K = c_K[l];
  int yg = blockIdx.y;   // rows yg*64 .. yg*64+63
  int zc = blockIdx.z;   // column half
  float off = (float)l * 1025.0f;  // lvl * (IMG + 1) — replicate offset rounding!
  size_t sbase = ((size_t)b * 5 + l) * 1024;
  __shared__ float bx1[1024], by1[1024], bx2[1024], by2[1024], barea[1024];
  int tid = threadIdx.x;
  for (int i = tid; i < 1024; i += 64) {
    float4 v = make_float4(0.f, 0.f, 0.f, 0.f);
    if (i < K) {
      v = ((const float4*)P.boxes)[sbase + i];
      v.x += off; v.y += off; v.z += off; v.w += off;
    }
    bx1[i] = v.x; by1[i] = v.y; bx2[i] = v.z; by2[i] = v.w;
    barea[i] = fmaxf(v.z - v.x, 0.0f) * fmaxf(v.w - v.y, 0.0f);
  }
  __syncthreads();
  int i = yg * 64 + tid;
  if (i >= K) return;  // (after the barrier; no further barriers below)
  float x1 = bx1[i], y1 = by1[i], x2 = bx2[i], y2 = by2[i], ai = barea[i];
  unsigned int* mrow = P.mask + (sbase + (size_t)i) * 32;
  int w0 = (yg * 64 + 1) >> 5;      // wave-uniform first word with any j > row
  int nw = 32 - w0;
  int half0 = (nw + 1) >> 1;
  int wbeg = (zc == 0) ? w0 : (w0 + half0);
  int wend = (zc == 0) ? (w0 + half0) : 32;
  if (zc == 0)
    for (int w = 0; w < w0; ++w) mrow[w] = 0u;  // low words: all j <= min row
  for (int w = wbeg; w < wend; ++w) {
    unsigned int bits = 0u;
    int j0 = w << 5;
    for (int jj = 0; jj < 32; ++jj) {
      int j = j0 + jj;
      float xx1 = fmaxf(x1, bx1[j]);
      float yy1 = fmaxf(y1, by1[j]);
      float xx2 = fminf(x2, bx2[j]);
      float yy2 = fminf(y2, by2[j]);
      float ww = fmaxf(xx2 - xx1, 0.0f);
      float hh = fmaxf(yy2 - yy1, 0.0f);
      float inter = ww * hh;
      float uni = ai + barea[j] - inter + 1e-8f;  // ((ai+aj)-inter)+eps
      if ((inter / uni > 0.7f) && (j > i)) bits |= (1u << jj);
    }
    mrow[w] = bits;
  }
}

// ---------------- Phase 2b: serial greedy sweep (1 wave / (img,lvl)) ------
__global__ __launch_bounds__(1024) void k_sweep(RPNParams P) {
  int bl = blockIdx.x, b = bl / 5, l = bl % 5;
  int K = c_K[l];
  size_t sbase = ((size_t)b * 5 + l) * 1024;
  __shared__ unsigned long long lmask[16 * 1000];  // 125 KiB
  int tid = threadIdx.x;
  const unsigned long long* gm = (const unsigned long long*)(P.mask + sbase * 32);
  for (int i = tid; i < K * 16; i += 1024) lmask[i] = gm[i];
  __syncthreads();
  if (tid < 64) {
    int lane = tid;
    unsigned long long kw = 0ull;  // lanes 0..15 hold keep words
    for (int g = 0; g < 16; ++g) {
      int e = g * 64 + lane;
      bool pred = (e < K) && (P.scores[sbase + e] > -INFINITY);
      unsigned long long m = __ballot(pred);
      if (lane == g) kw = m;
    }
    for (int i = 0; i < K; ++i) {
      unsigned long long w64 = shfl64(kw, i >> 6);
      if ((w64 >> (i & 63)) & 1ull) {
        kw &= ~lmask[i * 16 + (lane & 15)];
      }
    }
    for (int g = 0; g < 16; ++g) {
      unsigned long long w64 = shfl64(kw, g);
      int e = g * 64 + lane;
      if (e < K) P.keep[sbase + e] = (unsigned char)((w64 >> lane) & 1ull);
    }
  }
}

// ------- Phase 3: per-image 5-way merge-by-rank + keep-partition + out ----
__global__ __launch_bounds__(1024) void k_merge(RPNParams P) {
  int b = blockIdx.x;
  __shared__ unsigned long long keyL[5][1000];  // 40 KB, strictly desc per level
  __shared__ unsigned short srt[4768];          // rank -> concat idx
  __shared__ unsigned int wsum[16];
  __shared__ unsigned int sTot;
  int tid = threadIdx.x;
  int lane = tid & 63, wid = tid >> 6;

  // ---- Step 1: load + stable partition (valid first) per level ----
  for (int l = 0; l < 5; ++l) {
    int Kl = c_K[l];
    int r = tid;
    bool active = r < Kl;
    unsigned long long k = 0ull;
    bool flag = false;
    if (active) {
      float s = P.scores[((size_t)b * 5 + l) * 1024 + r];
      unsigned int fk = fkey(s);
      flag = fk > 0x007FFFFFu;  // score > -inf
      unsigned int cidx = (unsigned int)(l * 1000 + r);
      k = ((unsigned long long)fk << 32) |
          (unsigned long long)(0xFFFFFFFFu - cidx);
    }
    unsigned int fv = flag ? 1u : 0u;
    unsigned int v = fv;
    for (int d = 1; d < 64; d <<= 1) {
      unsigned int n = __shfl_up(v, (unsigned int)d, 64);
      if (lane >= d) v += n;
    }
    if (lane == 63) wsum[wid] = v;
    __syncthreads();
    if (tid == 0) {
      unsigned int acc = 0;
      for (int w = 0; w < 16; ++w) { unsigned int x = wsum[w]; wsum[w] = acc; acc += x; }
      sTot = acc;
    }
    __syncthreads();
    unsigned int excl = wsum[wid] + (v - fv);
    unsigned int nValid = sTot;
    if (active) {
      unsigned int dest = flag ? excl : (nValid + ((unsigned int)r - excl));
      keyL[l][dest] = k;
    }
    __syncthreads();
  }

  // ---- Step 2: global rank via binary search in the other 4 lists ----
  for (int e = tid; e < 4768; e += 1024) {
    int l = (e < 4000) ? (e / 1000) : 4;
    int p = e - l * 1000;
    unsigned long long k = keyL[l][p];
    int rank = p;
    #pragma unroll
    for (int l2 = 0; l2 < 5; ++l2) {
      if (l2 == l) continue;
      int lo = 0, hi = c_K[l2];
      while (lo < hi) {
        int mid = (lo + hi) >> 1;
        if (keyL[l2][mid] > k) lo = mid + 1; else hi = mid;
      }
      rank += lo;
    }
    srt[rank] = (unsigned short)(0xFFFFFFFFu - (unsigned int)(k & 0xFFFFFFFFu));
  }
  __syncthreads();

  // ---- Step 3: keep flags for 5 contiguous sorted slots per thread ----
  int base = tid * 5;
  unsigned char lf[5];
  unsigned short lc[5];
  unsigned int lsum = 0;
  for (int q = 0; q < 5; ++q) {
    int i = base + q;
    unsigned char f = 0; unsigned short cx = 0;
    if (i < 4768) {
      cx = srt[i];
      int l = cx / 1000;
      int r = (int)cx - l * 1000;
      f = P.keep[((size_t)b * 5 + l) * 1024 + r];
    }
    lf[q] = f; lc[q] = cx; lsum += f;
  }
  unsigned int v = lsum;
  for (int d = 1; d < 64; d <<= 1) {
    unsigned int n = __shfl_up(v, (unsigned int)d, 64);
    if (lane >= d) v += n;
  }
  if (lane == 63) wsum[wid] = v;
  __syncthreads();
  if (tid == 0) {
    unsigned int acc = 0;
    for (int w = 0; w < 16; ++w) { unsigned int x = wsum[w]; wsum[w] = acc; acc += x; }
    sTot = acc;
  }
  __syncthreads();
  unsigned int excl = wsum[wid] + (v - lsum);  // kept count before slot `base`
  unsigned int tot = sTot;
  for (int q = 0; q < 5; ++q) {
    int i = base + q;
    if (i >= 4768) break;
    unsigned int cidx = (unsigned int)lc[q];
    int l = (int)(cidx / 1000u);
    int r = (int)cidx - l * 1000;
    size_t sb = ((size_t)b * 5 + l) * 1024 + r;
    unsigned char f = lf[q];
    unsigned int pos = f ? excl : (tot + ((unsigned int)i - excl));
    excl += f;
    if (pos < 1000u) {
      float4 bx = ((const float4*)P.boxes)[sb];
      float sc = f ? P.scores[sb] : -INFINITY;
      float* o = P.out + ((size_t)b * 1000 + pos) * 5;
      o[0] = bx.x; o[1] = bx.y; o[2] = bx.z; o[3] = bx.w; o[4] = sc;
    }
  }
}

}  // namespace

extern "C" void kernel_launch(void* const* d_in, const int* in_sizes, int n_in,
                              void* d_out, int out_size, void* d_ws, size_t ws_size,
                              hipStream_t stream) {
  (void)out_size; (void)ws_size;
  RPNParams P;
  bool interleaved = (n_in >= 3) && (in_sizes[2] == 786432);
  for (int l = 0; l < 5; ++l) {
    if (interleaved) {
      P.deltas[l]  = (const float*)d_in[3 * l + 0];
      P.ctr[l]     = (const float*)d_in[3 * l + 1];
      P.anchors[l] = (const float*)d_in[3 * l + 2];
    } else {
      P.deltas[l]  = (const float*)d_in[l];
      P.ctr[l]     = (const float*)d_in[5 + l];
      P.anchors[l] = (const float*)d_in[10 + l];
    }
  }
  char* ws = (char*)d_ws;
  P.scores = (float*)(ws + 0);               // 163840 B
  P.boxes  = (float*)(ws + 163840);          // 655360 B
  P.keep   = (unsigned char*)(ws + 819200);  // 40960 B
  P.mask   = (unsigned int*)(ws + 860160);   // 5242880 B
  P.cand   = (unsigned long long*)(ws + 860160);  // 1310720 B, aliases mask (used before k_mask)
  P.ghist0 = (unsigned int*)(ws + 6103040);  // 40960 B
  P.ghist1 = (unsigned int*)(ws + 6144000);  // 40960 B
  P.ccount = (unsigned int*)(ws + 6184960);  // 160 B
  P.thresh = (unsigned int*)(ws + 6185120);  // 160 B
  P.out    = (float*)d_out;

  hipMemsetAsync(ws + 6103040, 0, 82240, stream);  // hists + ccount + thresh
  hipLaunchKernelGGL(k_hist0, dim3(40, 32), dim3(256), 0, stream, P);
  hipLaunchKernelGGL(k_hist1, dim3(40, 32), dim3(256), 0, stream, P);
  hipLaunchKernelGGL(k_thresh, dim3(40), dim3(256), 0, stream, P);
  hipLaunchKernelGGL(k_compact, dim3(40, 32), dim3(256), 0, stream, P);
  hipLaunchKernelGGL(k_select, dim3(40), dim3(1024), 0, stream, P);
  hipLaunchKernelGGL(k_mask, dim3(40, 16, 2), dim3(64), 0, stream, P);
  hipLaunchKernelGGL(k_sweep, dim3(40), dim3(1024), 0, stream, P);
  hipLaunchKernelGGL(k_merge, dim3(8), dim3(1024), 0, stream, P);
}

// Round 5
// 276.483 us; speedup vs baseline: 1.1542x; 1.1542x over previous
//
#include <hip/hip_runtime.h>
#include <cstdint>
#include <cstddef>
#include <cmath>

#pragma clang fp contract(off)

namespace {

constexpr int kCandMax = 4096;

__device__ __constant__ int c_N[5] = {196608, 49152, 12288, 3072, 768};
__device__ __constant__ int c_K[5] = {1000, 1000, 1000, 1000, 768};

struct RPNParams {
  const float* deltas[5];
  const float* ctr[5];
  const float* anchors[5];
  float* scores;         // [8][5][1024] masked scores, per-level sorted desc
  float* boxes;          // [8][5][1024][4] clipped boxes, per-level sorted
  unsigned char* keep;   // [8][5][1024]
  unsigned int* mask;    // [8][5][1024][32] suppression bits (j in bits, row i)
  unsigned int* ghist0;  // [40][256]
  unsigned int* ghist1;  // [40][256]
  unsigned int* ccount;  // [40] candidate counts
  unsigned int* thresh;  // [40] 16-bit-refined key threshold
  unsigned long long* cand;  // [40][4096] (aliases mask region; used before k_mask)
  float* out;            // [8][1000][5]
};

// monotonic float->uint map (larger float => larger uint)
__device__ __forceinline__ unsigned int fkey(float f) {
  unsigned int u = __float_as_uint(f);
  return (u & 0x80000000u) ? ~u : (u | 0x80000000u);
}

// ---------------- Phase 1a: 8-bit histogram of score keys ----------------
__global__ __launch_bounds__(256) void k_hist0(RPNParams P) {
  int bl = blockIdx.x, b = bl / 5, l = bl % 5;
  int N = c_N[l];
  int chunk = (N + 31) / 32;
  int i0 = blockIdx.y * chunk;
  int i1 = i0 + chunk; if (i1 > N) i1 = N;
  const float* ctr = P.ctr[l] + (size_t)b * N;
  __shared__ unsigned int wh[4][256];
  int tid = threadIdx.x, wid = tid >> 6;
  for (int i = tid; i < 1024; i += 256) ((unsigned int*)wh)[i] = 0u;
  __syncthreads();
  for (int i = i0 + tid; i < i1; i += 256) {
    unsigned int u = fkey(ctr[i]);
    atomicAdd(&wh[wid][u >> 24], 1u);
  }
  __syncthreads();
  int bin = tid;
  unsigned int s = wh[0][bin] + wh[1][bin] + wh[2][bin] + wh[3][bin];
  if (s) atomicAdd(&P.ghist0[bl * 256 + bin], s);
}

// ---------------- Phase 1b: refine to 16-bit within chosen top byte ------
__global__ __launch_bounds__(256) void k_hist1(RPNParams P) {
  int bl = blockIdx.x, b = bl / 5, l = bl % 5;
  int N = c_N[l], K = c_K[l];
  int chunk = (N + 31) / 32;
  int i0 = blockIdx.y * chunk;
  int i1 = i0 + chunk; if (i1 > N) i1 = N;
  const float* ctr = P.ctr[l] + (size_t)b * N;
  __shared__ unsigned int wh[4][256];
  __shared__ unsigned int sV0;
  int tid = threadIdx.x, wid = tid >> 6;
  if (tid < 256) wh[0][tid] = P.ghist0[bl * 256 + tid];
  __syncthreads();
  if (tid == 0) {
    unsigned int kk = (unsigned int)K, cum = 0;
    int v = 255;
    for (; v > 0; --v) { unsigned int x = wh[0][v]; if (cum + x >= kk) break; cum += x; }
    sV0 = (unsigned int)v;
  }
  __syncthreads();
  unsigned int v0 = sV0;
  for (int i = tid; i < 1024; i += 256) ((unsigned int*)wh)[i] = 0u;
  __syncthreads();
  for (int i = i0 + tid; i < i1; i += 256) {
    unsigned int u = fkey(ctr[i]);
    if ((u >> 24) == v0) atomicAdd(&wh[wid][(u >> 16) & 255u], 1u);
  }
  __syncthreads();
  int bin = tid;
  unsigned int s = wh[0][bin] + wh[1][bin] + wh[2][bin] + wh[3][bin];
  if (s) atomicAdd(&P.ghist1[bl * 256 + bin], s);
}

// ------- Phase 1c: per-(img,lvl) threshold via suffix-scan + bsearch -----
__global__ __launch_bounds__(256) void k_thresh(RPNParams P) {
  int bl = blockIdx.x;
  int K = c_K[bl % 5];
  __shared__ unsigned int S[257];
  __shared__ unsigned int sV0, sKK;
  int tid = threadIdx.x;
  S[tid] = P.ghist0[bl * 256 + tid];
  if (tid == 0) S[256] = 0u;
  __syncthreads();
  for (int d = 1; d < 256; d <<= 1) {
    unsigned int v = (tid + d < 256) ? S[tid + d] : 0u;
    __syncthreads();
    S[tid] += v;
    __syncthreads();
  }
  if (tid == 0) {
    int lo = 0, hi = 255;
    while (lo < hi) { int mid = (lo + hi + 1) >> 1; if (S[mid] >= (unsigned int)K) lo = mid; else hi = mid - 1; }
    sV0 = (unsigned int)lo;
    sKK = (unsigned int)K - S[lo + 1];
  }
  __syncthreads();
  S[tid] = P.ghist1[bl * 256 + tid];
  __syncthreads();
  for (int d = 1; d < 256; d <<= 1) {
    unsigned int v = (tid + d < 256) ? S[tid + d] : 0u;
    __syncthreads();
    S[tid] += v;
    __syncthreads();
  }
  if (tid == 0) {
    unsigned int kk = sKK;
    int lo = 0, hi = 255;
    while (lo < hi) { int mid = (lo + hi + 1) >> 1; if (S[mid] >= kk) lo = mid; else hi = mid - 1; }
    P.thresh[bl] = ((sV0 << 8) | (unsigned int)lo) << 16;
  }
}

// ------- Phase 1d: chip-wide compaction of candidates (key >= T) ---------
__global__ __launch_bounds__(256) void k_compact(RPNParams P) {
  int bl = blockIdx.x, b = bl / 5, l = bl % 5;
  int N = c_N[l];
  int chunk = (N + 31) / 32;
  int i0 = blockIdx.y * chunk;
  int i1 = i0 + chunk; if (i1 > N) i1 = N;
  const float* ctr = P.ctr[l] + (size_t)b * N;
  unsigned int T = P.thresh[bl];
  unsigned long long* cand = P.cand + (size_t)bl * kCandMax;
  int tid = threadIdx.x, lane = tid & 63;
  for (int i = i0 + tid; i < i1; i += 256) {
    unsigned int u = fkey(ctr[i]);
    bool pred = (u >= T);
    unsigned long long m = __ballot(pred);
    if (m) {
      int leader = (int)__builtin_ctzll(m);
      unsigned int base = 0u;
      if (lane == leader) base = atomicAdd(&P.ccount[bl], (unsigned int)__popcll(m));
      base = (unsigned int)__shfl((int)base, leader, 64);
      if (pred) {
        unsigned int pos = base + (unsigned int)__popcll(m & ((1ull << lane) - 1ull));
        if (pos < (unsigned int)kCandMax)
          cand[pos] = ((unsigned long long)u << 32) |
                      (unsigned long long)(0xFFFFFFFFu - (unsigned int)i);
      }
    }
  }
}

// ---- Phase 1e: sort candidates, decode+clip boxes (40 blocks) -----------
__global__ __launch_bounds__(1024) void k_select(RPNParams P) {
  int bl = blockIdx.x, b = bl / 5, l = bl % 5;
  int N = c_N[l], K = c_K[l];
  const float* ctr = P.ctr[l] + (size_t)b * N;
  __shared__ unsigned long long cand[kCandMax];
  int tid = threadIdx.x;
  int cc = (int)P.ccount[bl]; if (cc > kCandMax) cc = kCandMax;
  const unsigned long long* gc = P.cand + (size_t)bl * kCandMax;
  for (int i = tid; i < cc; i += 1024) cand[i] = gc[i];
  int n2 = 1; while (n2 < cc) n2 <<= 1;
  for (int i = cc + tid; i < n2; i += 1024) cand[i] = 0ull;
  __syncthreads();
  // bitonic sort descending by (key desc, idx asc) composite
  for (int size = 2; size <= n2; size <<= 1) {
    for (int stride = size >> 1; stride > 0; stride >>= 1) {
      for (int i = tid; i < n2; i += 1024) {
        int j = i ^ stride;
        if (j > i) {
          unsigned long long a = cand[i], c2 = cand[j];
          bool sw = ((i & size) == 0) ? (a < c2) : (a > c2);
          if (sw) { cand[i] = c2; cand[j] = a; }
        }
      }
      __syncthreads();
    }
  }
  size_t sbase = ((size_t)b * 5 + l) * 1024;
  for (int r = tid; r < K; r += 1024) {
    unsigned long long cv = cand[r];
    unsigned int idx = 0xFFFFFFFFu - (unsigned int)(cv & 0xFFFFFFFFu);
    float s = ctr[idx];
    float4 anc = *(const float4*)(P.anchors[l] + (size_t)idx * 4);
    float4 dd  = *(const float4*)(P.deltas[l] + ((size_t)b * N + idx) * 4);
    // Box2BoxTransformLinear decode (same op order as reference, no fma)
    float w = anc.z - anc.x, hgt = anc.w - anc.y;
    float cx = (anc.x + anc.z) * 0.5f, cy = (anc.y + anc.w) * 0.5f;
    float x1 = cx - dd.x * w;
    float y1 = cy - dd.y * hgt;
    float x2 = cx + dd.z * w;
    float y2 = cy + dd.w * hgt;
    x1 = fminf(fmaxf(x1, 0.0f), 1024.0f);
    y1 = fminf(fmaxf(y1, 0.0f), 1024.0f);
    x2 = fminf(fmaxf(x2, 0.0f), 1024.0f);
    y2 = fminf(fmaxf(y2, 0.0f), 1024.0f);
    bool valid = ((x2 - x1) > 0.0f) && ((y2 - y1) > 0.0f);
    P.scores[sbase + r] = valid ? s : -INFINITY;
    *(float4*)(P.boxes + (sbase + r) * 4) = make_float4(x1, y1, x2, y2);
  }
}

// ---------------- Phase 2a: suppression bitmask (per level) ---------------
__global__ __launch_bounds__(64) void k_mask(RPNParams P) {
  int bl = blockIdx.x, b = bl / 5, l = bl % 5;
  int K = c_K[l];
  int yg = blockIdx.y;   // rows yg*64 .. yg*64+63
  int zc = blockIdx.z;   // column half
  float off = (float)l * 1025.0f;  // lvl * (IMG + 1) — replicate offset rounding!
  size_t sbase = ((size_t)b * 5 + l) * 1024;
  __shared__ float bx1[1024], by1[1024], bx2[1024], by2[1024], barea[1024];
  int tid = threadIdx.x;
  for (int i = tid; i < 1024; i += 64) {
    float4 v = make_float4(0.f, 0.f, 0.f, 0.f);
    if (i < K) {
      v = ((const float4*)P.boxes)[sbase + i];
      v.x += off; v.y += off; v.z += off; v.w += off;
    }
    bx1[i] = v.x; by1[i] = v.y; bx2[i] = v.z; by2[i] = v.w;
    barea[i] = fmaxf(v.z - v.x, 0.0f) * fmaxf(v.w - v.y, 0.0f);
  }
  __syncthreads();
  int i = yg * 64 + tid;
  if (i >= K) return;  // (after the barrier; no further barriers below)
  float x1 = bx1[i], y1 = by1[i], x2 = bx2[i], y2 = by2[i], ai = barea[i];
  unsigned int* mrow = P.mask + (sbase + (size_t)i) * 32;
  int w0 = (yg * 64 + 1) >> 5;      // wave-uniform first word with any j > row
  int nw = 32 - w0;
  int half0 = (nw + 1) >> 1;
  int wbeg = (zc == 0) ? w0 : (w0 + half0);
  int wend = (zc == 0) ? (w0 + half0) : 32;
  if (zc == 0)
    for (int w = 0; w < w0; ++w) mrow[w] = 0u;  // low words: all j <= min row
  for (int w = wbeg; w < wend; ++w) {
    unsigned int bits = 0u;
    int j0 = w << 5;
    for (int jj = 0; jj < 32; ++jj) {
      int j = j0 + jj;
      float xx1 = fmaxf(x1, bx1[j]);
      float yy1 = fmaxf(y1, by1[j]);
      float xx2 = fminf(x2, bx2[j]);
      float yy2 = fminf(y2, by2[j]);
      float ww = fmaxf(xx2 - xx1, 0.0f);
      float hh = fmaxf(yy2 - yy1, 0.0f);
      float inter = ww * hh;
      float uni = ai + barea[j] - inter + 1e-8f;  // ((ai+aj)-inter)+eps
      if ((inter / uni > 0.7f) && (j > i)) bits |= (1u << jj);
    }
    mrow[w] = bits;
  }
}

// ---------------- Phase 2b: greedy sweep, word-serial scalar chain --------
// Critical path per kept box: ctz -> 2x v_readlane (diag word from per-lane
// regs) -> andn2 -> next ctz (~40 cyc). Cross-word suppression rows are read
// from LDS but folded into per-lane acc two iterations later (2-deep SW
// pipeline), keeping the ~120cyc LDS latency OFF the critical chain.
__global__ __launch_bounds__(1024) void k_sweep(RPNParams P) {
  int bl = blockIdx.x, b = bl / 5, l = bl % 5;
  int K = c_K[l];
  int NW = (K + 63) >> 6;
  size_t sbase = ((size_t)b * 5 + l) * 1024;
  __shared__ unsigned long long lmask[16 * 1000];  // 125 KiB, [row][16 words]
  __shared__ unsigned long long diag[1024];        // 8 KiB: lmask[i][i>>6]
  __shared__ unsigned long long svalid[16];
  __shared__ unsigned long long skept[16];
  int tid = threadIdx.x;
  const unsigned long long* gm = (const unsigned long long*)(P.mask + sbase * 32);
  for (int i = tid; i < K * 16; i += 1024) lmask[i] = gm[i];
  __syncthreads();
  if (tid < 1024) {
    int i = tid;
    diag[i] = (i < K) ? lmask[i * 16 + (i >> 6)] : 0ull;
  }
  __syncthreads();
  if (tid >= 64) return;  // no further barriers
  int lane = tid;
  // valid ballots (one global read per word, pipelined)
  for (int g = 0; g < 16; ++g) {
    int e = g * 64 + lane;
    bool pred = (e < K) && (P.scores[sbase + e] > -INFINITY);
    unsigned long long m = __ballot(pred);
    if (lane == 0) svalid[g] = m;
  }
  unsigned long long acc = 0ull;  // per-lane (cols 0..15): deferred suppression
  unsigned long long m1 = 0ull, m2 = 0ull;
  for (int g = 0; g < NW; ++g) {
    acc |= m1 | m2; m1 = 0ull; m2 = 0ull;  // drain pipeline at word boundary
    unsigned int alo = __builtin_amdgcn_readlane((unsigned int)acc, g);
    unsigned int ahi = __builtin_amdgcn_readlane((unsigned int)(acc >> 32), g);
    unsigned long long w = svalid[g] &
        ~(((unsigned long long)ahi << 32) | (unsigned long long)alo);
    unsigned long long dreg = diag[g * 64 + lane];  // lane b: diag of bit b
    unsigned long long kept = 0ull;
    while (w) {
      int bpos = (int)__builtin_ctzll(w);
      kept |= (1ull << bpos);
      unsigned int dlo = __builtin_amdgcn_readlane((unsigned int)dreg, bpos);
      unsigned int dhi = __builtin_amdgcn_readlane((unsigned int)(dreg >> 32), bpos);
      unsigned long long m = lmask[(g * 64 + bpos) * 16 + (lane & 15)];
      w &= ~(1ull << bpos);
      w &= ~(((unsigned long long)dhi << 32) | (unsigned long long)dlo);
      acc |= m2; m2 = m1; m1 = m;  // fold 2-iterations-old mask (latency slack)
    }
    if (lane == 0) skept[g] = kept;
  }
  for (int g = 0; g < NW; ++g) {
    unsigned long long kv = skept[g];
    int e = g * 64 + lane;
    if (e < K) P.keep[sbase + e] = (unsigned char)((kv >> lane) & 1ull);
  }
}

// ------- Phase 3: per-image 5-way merge-by-rank + keep-partition + out ----
__global__ __launch_bounds__(1024) void k_merge(RPNParams P) {
  int b = blockIdx.x;
  __shared__ unsigned long long keyL[5][1000];  // 40 KB, strictly desc per level
  __shared__ unsigned short srt[4768];          // rank -> concat idx
  __shared__ unsigned int wsum[16];
  __shared__ unsigned int sTot;
  int tid = threadIdx.x;
  int lane = tid & 63, wid = tid >> 6;

  // ---- Step 1: load + stable partition (valid first) per level ----
  for (int l = 0; l < 5; ++l) {
    int Kl = c_K[l];
    int r = tid;
    bool active = r < Kl;
    unsigned long long k = 0ull;
    bool flag = false;
    if (active) {
      float s = P.scores[((size_t)b * 5 + l) * 1024 + r];
      unsigned int fk = fkey(s);
      flag = fk > 0x007FFFFFu;  // score > -inf
      unsigned int cidx = (unsigned int)(l * 1000 + r);
      k = ((unsigned long long)fk << 32) |
          (unsigned long long)(0xFFFFFFFFu - cidx);
    }
    unsigned int fv = flag ? 1u : 0u;
    unsigned int v = fv;
    for (int d = 1; d < 64; d <<= 1) {
      unsigned int n = __shfl_up(v, (unsigned int)d, 64);
      if (lane >= d) v += n;
    }
    if (lane == 63) wsum[wid] = v;
    __syncthreads();
    if (tid == 0) {
      unsigned int acc = 0;
      for (int w = 0; w < 16; ++w) { unsigned int x = wsum[w]; wsum[w] = acc; acc += x; }
      sTot = acc;
    }
    __syncthreads();
    unsigned int excl = wsum[wid] + (v - fv);
    unsigned int nValid = sTot;
    if (active) {
      unsigned int dest = flag ? excl : (nValid + ((unsigned int)r - excl));
      keyL[l][dest] = k;
    }
    __syncthreads();
  }

  // ---- Step 2: global rank via binary search in the other 4 lists ----
  for (int e = tid; e < 4768; e += 1024) {
    int l = (e < 4000) ? (e / 1000) : 4;
    int p = e - l * 1000;
    unsigned long long k = keyL[l][p];
    int rank = p;
    #pragma unroll
    for (int l2 = 0; l2 < 5; ++l2) {
      if (l2 == l) continue;
      int lo = 0, hi = c_K[l2];
      while (lo < hi) {
        int mid = (lo + hi) >> 1;
        if (keyL[l2][mid] > k) lo = mid + 1; else hi = mid;
      }
      rank += lo;
    }
    srt[rank] = (unsigned short)(0xFFFFFFFFu - (unsigned int)(k & 0xFFFFFFFFu));
  }
  __syncthreads();

  // ---- Step 3: keep flags for 5 contiguous sorted slots per thread ----
  int base = tid * 5;
  unsigned char lf[5];
  unsigned short lc[5];
  unsigned int lsum = 0;
  for (int q = 0; q < 5; ++q) {
    int i = base + q;
    unsigned char f = 0; unsigned short cx = 0;
    if (i < 4768) {
      cx = srt[i];
      int l = cx / 1000;
      int r = (int)cx - l * 1000;
      f = P.keep[((size_t)b * 5 + l) * 1024 + r];
    }
    lf[q] = f; lc[q] = cx; lsum += f;
  }
  unsigned int v = lsum;
  for (int d = 1; d < 64; d <<= 1) {
    unsigned int n = __shfl_up(v, (unsigned int)d, 64);
    if (lane >= d) v += n;
  }
  if (lane == 63) wsum[wid] = v;
  __syncthreads();
  if (tid == 0) {
    unsigned int acc = 0;
    for (int w = 0; w < 16; ++w) { unsigned int x = wsum[w]; wsum[w] = acc; acc += x; }
    sTot = acc;
  }
  __syncthreads();
  unsigned int excl = wsum[wid] + (v - lsum);  // kept count before slot `base`
  unsigned int tot = sTot;
  for (int q = 0; q < 5; ++q) {
    int i = base + q;
    if (i >= 4768) break;
    unsigned int cidx = (unsigned int)lc[q];
    int l = (int)(cidx / 1000u);
    int r = (int)cidx - l * 1000;
    size_t sb = ((size_t)b * 5 + l) * 1024 + r;
    unsigned char f = lf[q];
    unsigned int pos = f ? excl : (tot + ((unsigned int)i - excl));
    excl += f;
    if (pos < 1000u) {
      float4 bx = ((const float4*)P.boxes)[sb];
      float sc = f ? P.scores[sb] : -INFINITY;
      float* o = P.out + ((size_t)b * 1000 + pos) * 5;
      o[0] = bx.x; o[1] = bx.y; o[2] = bx.z; o[3] = bx.w; o[4] = sc;
    }
  }
}

}  // namespace

extern "C" void kernel_launch(void* const* d_in, const int* in_sizes, int n_in,
                              void* d_out, int out_size, void* d_ws, size_t ws_size,
                              hipStream_t stream) {
  (void)out_size; (void)ws_size;
  RPNParams P;
  bool interleaved = (n_in >= 3) && (in_sizes[2] == 786432);
  for (int l = 0; l < 5; ++l) {
    if (interleaved) {
      P.deltas[l]  = (const float*)d_in[3 * l + 0];
      P.ctr[l]     = (const float*)d_in[3 * l + 1];
      P.anchors[l] = (const float*)d_in[3 * l + 2];
    } else {
      P.deltas[l]  = (const float*)d_in[l];
      P.ctr[l]     = (const float*)d_in[5 + l];
      P.anchors[l] = (const float*)d_in[10 + l];
    }
  }
  char* ws = (char*)d_ws;
  P.scores = (float*)(ws + 0);               // 163840 B
  P.boxes  = (float*)(ws + 163840);          // 655360 B
  P.keep   = (unsigned char*)(ws + 819200);  // 40960 B
  P.mask   = (unsigned int*)(ws + 860160);   // 5242880 B
  P.cand   = (unsigned long long*)(ws + 860160);  // 1310720 B, aliases mask (used before k_mask)
  P.ghist0 = (unsigned int*)(ws + 6103040);  // 40960 B
  P.ghist1 = (unsigned int*)(ws + 6144000);  // 40960 B
  P.ccount = (unsigned int*)(ws + 6184960);  // 160 B
  P.thresh = (unsigned int*)(ws + 6185120);  // 160 B
  P.out    = (float*)d_out;

  hipMemsetAsync(ws + 6103040, 0, 82240, stream);  // hists + ccount + thresh
  hipLaunchKernelGGL(k_hist0, dim3(40, 32), dim3(256), 0, stream, P);
  hipLaunchKernelGGL(k_hist1, dim3(40, 32), dim3(256), 0, stream, P);
  hipLaunchKernelGGL(k_thresh, dim3(40), dim3(256), 0, stream, P);
  hipLaunchKernelGGL(k_compact, dim3(40, 32), dim3(256), 0, stream, P);
  hipLaunchKernelGGL(k_select, dim3(40), dim3(1024), 0, stream, P);
  hipLaunchKernelGGL(k_mask, dim3(40, 16, 2), dim3(64), 0, stream, P);
  hipLaunchKernelGGL(k_sweep, dim3(40), dim3(1024), 0, stream, P);
  hipLaunchKernelGGL(k_merge, dim3(8), dim3(1024), 0, stream, P);
}

// Round 6
// 199.206 us; speedup vs baseline: 1.6020x; 1.3879x over previous
//
#include <hip/hip_runtime.h>
#include <cstdint>
#include <cstddef>
#include <cmath>

#pragma clang fp contract(off)

namespace {

constexpr int kCandMax = 4096;

__device__ __constant__ int c_N[5] = {196608, 49152, 12288, 3072, 768};
__device__ __constant__ int c_K[5] = {1000, 1000, 1000, 1000, 768};

struct RPNParams {
  const float* deltas[5];
  const float* ctr[5];
  const float* anchors[5];
  float* scores;         // [8][5][1024] masked scores, per-level sorted desc
  float* boxes;          // [8][5][1024][4] clipped boxes, per-level sorted
  unsigned char* keep;   // [8][5][1024]
  unsigned int* mask;    // [8][5][1024][32] suppression bits (j in bits, row i)
  unsigned int* ghist0;  // [40][256]
  unsigned int* ghist1;  // [40][256]
  unsigned int* ccount;  // aliases ghist0: counter bl at [bl*256] (1KB apart, own L2 line)
  unsigned int* thresh;  // [40] 16-bit-refined key threshold
  unsigned long long* cand;  // [40][4096] (aliases mask region; used before k_mask)
  float* out;            // [8][1000][5]
};

// monotonic float->uint map (larger float => larger uint)
__device__ __forceinline__ unsigned int fkey(float f) {
  unsigned int u = __float_as_uint(f);
  return (u & 0x80000000u) ? ~u : (u | 0x80000000u);
}

// ---------------- Phase 1a: 8-bit histogram of score keys ----------------
__global__ __launch_bounds__(256) void k_hist0(RPNParams P) {
  int bl = blockIdx.x, b = bl / 5, l = bl % 5;
  int N = c_N[l];
  int chunk = (N + 31) / 32;  // all chunks are multiples of 4
  int i0 = blockIdx.y * chunk;
  int i1 = i0 + chunk; if (i1 > N) i1 = N;
  const float4* c4 = (const float4*)(P.ctr[l] + (size_t)b * N);
  __shared__ unsigned int wh[4][256];
  int tid = threadIdx.x, wid = tid >> 6;
  for (int i = tid; i < 1024; i += 256) ((unsigned int*)wh)[i] = 0u;
  __syncthreads();
  int q0 = i0 >> 2, q1 = i1 >> 2;
  for (int q = q0 + tid; q < q1; q += 256) {
    float4 v = c4[q];
    atomicAdd(&wh[wid][fkey(v.x) >> 24], 1u);
    atomicAdd(&wh[wid][fkey(v.y) >> 24], 1u);
    atomicAdd(&wh[wid][fkey(v.z) >> 24], 1u);
    atomicAdd(&wh[wid][fkey(v.w) >> 24], 1u);
  }
  __syncthreads();
  int bin = tid;
  unsigned int s = wh[0][bin] + wh[1][bin] + wh[2][bin] + wh[3][bin];
  if (s) atomicAdd(&P.ghist0[bl * 256 + bin], s);
}

// ---------------- Phase 1b: refine to 16-bit within chosen top byte ------
__global__ __launch_bounds__(256) void k_hist1(RPNParams P) {
  int bl = blockIdx.x, b = bl / 5, l = bl % 5;
  int N = c_N[l], K = c_K[l];
  int chunk = (N + 31) / 32;
  int i0 = blockIdx.y * chunk;
  int i1 = i0 + chunk; if (i1 > N) i1 = N;
  const float4* c4 = (const float4*)(P.ctr[l] + (size_t)b * N);
  __shared__ unsigned int wh[4][256];
  __shared__ unsigned int sV0;
  int tid = threadIdx.x, wid = tid >> 6;
  if (tid < 256) wh[0][tid] = P.ghist0[bl * 256 + tid];
  __syncthreads();
  if (tid == 0) {
    unsigned int kk = (unsigned int)K, cum = 0;
    int v = 255;
    for (; v > 0; --v) { unsigned int x = wh[0][v]; if (cum + x >= kk) break; cum += x; }
    sV0 = (unsigned int)v;
  }
  __syncthreads();
  unsigned int v0 = sV0;
  for (int i = tid; i < 1024; i += 256) ((unsigned int*)wh)[i] = 0u;
  __syncthreads();
  int q0 = i0 >> 2, q1 = i1 >> 2;
  for (int q = q0 + tid; q < q1; q += 256) {
    float4 v = c4[q];
    unsigned int u0 = fkey(v.x), u1 = fkey(v.y), u2 = fkey(v.z), u3 = fkey(v.w);
    if ((u0 >> 24) == v0) atomicAdd(&wh[wid][(u0 >> 16) & 255u], 1u);
    if ((u1 >> 24) == v0) atomicAdd(&wh[wid][(u1 >> 16) & 255u], 1u);
    if ((u2 >> 24) == v0) atomicAdd(&wh[wid][(u2 >> 16) & 255u], 1u);
    if ((u3 >> 24) == v0) atomicAdd(&wh[wid][(u3 >> 16) & 255u], 1u);
  }
  __syncthreads();
  int bin = tid;
  unsigned int s = wh[0][bin] + wh[1][bin] + wh[2][bin] + wh[3][bin];
  if (s) atomicAdd(&P.ghist1[bl * 256 + bin], s);
}

// ------- Phase 1c: per-(img,lvl) threshold via suffix-scan + bsearch -----
// Also zeroes this bl's candidate counter (aliases ghist0[bl][0]; only this
// block reads row bl, and the zero happens after the row is loaded into S).
__global__ __launch_bounds__(256) void k_thresh(RPNParams P) {
  int bl = blockIdx.x;
  int K = c_K[bl % 5];
  __shared__ unsigned int S[257];
  __shared__ unsigned int sV0, sKK;
  int tid = threadIdx.x;
  S[tid] = P.ghist0[bl * 256 + tid];
  if (tid == 0) S[256] = 0u;
  __syncthreads();
  if (tid == 0) P.ccount[bl * 256] = 0u;  // after row read; row bl is block-private
  for (int d = 1; d < 256; d <<= 1) {
    unsigned int v = (tid + d < 256) ? S[tid + d] : 0u;
    __syncthreads();
    S[tid] += v;
    __syncthreads();
  }
  if (tid == 0) {
    int lo = 0, hi = 255;
    while (lo < hi) { int mid = (lo + hi + 1) >> 1; if (S[mid] >= (unsigned int)K) lo = mid; else hi = mid - 1; }
    sV0 = (unsigned int)lo;
    sKK = (unsigned int)K - S[lo + 1];
  }
  __syncthreads();
  S[tid] = P.ghist1[bl * 256 + tid];
  __syncthreads();
  for (int d = 1; d < 256; d <<= 1) {
    unsigned int v = (tid + d < 256) ? S[tid + d] : 0u;
    __syncthreads();
    S[tid] += v;
    __syncthreads();
  }
  if (tid == 0) {
    unsigned int kk = sKK;
    int lo = 0, hi = 255;
    while (lo < hi) { int mid = (lo + hi + 1) >> 1; if (S[mid] >= kk) lo = mid; else hi = mid - 1; }
    P.thresh[bl] = ((sV0 << 8) | (unsigned int)lo) << 16;
  }
}

// ------- Phase 1d: compaction, ONE global atomic per block ---------------
// Pass 1: per-thread count (no atomics) -> wave shfl-reduce -> block total ->
// single atomicAdd reserving [base, base+tot). Pass 2: re-scan (L1/L2-hot),
// ballot-prefix scatter at deterministic per-wave offsets.
__global__ __launch_bounds__(256) void k_compact(RPNParams P) {
  int bl = blockIdx.x, b = bl / 5, l = bl % 5;
  int N = c_N[l];
  int chunk = (N + 31) / 32;
  int i0 = blockIdx.y * chunk;
  int i1 = i0 + chunk; if (i1 > N) i1 = N;
  const float4* c4 = (const float4*)(P.ctr[l] + (size_t)b * N);
  unsigned int T = P.thresh[bl];
  unsigned long long* cand = P.cand + (size_t)bl * kCandMax;
  __shared__ unsigned int wcnt[4], wbase[4];
  int tid = threadIdx.x, lane = tid & 63, wid = tid >> 6;
  int q0 = i0 >> 2, q1 = i1 >> 2;
  // pass 1: count
  unsigned int cnt = 0;
  for (int q = q0 + tid; q < q1; q += 256) {
    float4 v = c4[q];
    cnt += (fkey(v.x) >= T) + (fkey(v.y) >= T) + (fkey(v.z) >= T) + (fkey(v.w) >= T);
  }
  for (int d = 32; d > 0; d >>= 1) cnt += (unsigned int)__shfl_xor((int)cnt, d, 64);
  if (lane == 0) wcnt[wid] = cnt;
  __syncthreads();
  if (tid == 0) {
    unsigned int tot = wcnt[0] + wcnt[1] + wcnt[2] + wcnt[3];
    unsigned int base = tot ? atomicAdd(&P.ccount[bl * 256], tot) : 0u;
    unsigned int acc = base;
    for (int w = 0; w < 4; ++w) { unsigned int x = wcnt[w]; wbase[w] = acc; acc += x; }
  }
  __syncthreads();
  unsigned int off = wbase[wid];
  unsigned long long lmlt = (1ull << lane) - 1ull;
  for (int q = q0 + tid; q < q1; q += 256) {
    float4 v = c4[q];
    unsigned int u[4] = {fkey(v.x), fkey(v.y), fkey(v.z), fkey(v.w)};
    #pragma unroll
    for (int k = 0; k < 4; ++k) {
      bool pred = (u[k] >= T);
      unsigned long long m = __ballot(pred);
      if (pred) {
        unsigned int pos = off + (unsigned int)__popcll(m & lmlt);
        if (pos < (unsigned int)kCandMax) {
          unsigned int idx = (unsigned int)(q * 4 + k);
          cand[pos] = ((unsigned long long)u[k] << 32) |
                      (unsigned long long)(0xFFFFFFFFu - idx);
        }
      }
      off += (unsigned int)__popcll(m);
    }
  }
}

// ---- Phase 1e: sort candidates, decode+clip boxes (40 blocks) -----------
__global__ __launch_bounds__(1024) void k_select(RPNParams P) {
  int bl = blockIdx.x, b = bl / 5, l = bl % 5;
  int N = c_N[l], K = c_K[l];
  const float* ctr = P.ctr[l] + (size_t)b * N;
  __shared__ unsigned long long cand[kCandMax];
  int tid = threadIdx.x;
  int cc = (int)P.ccount[bl * 256]; if (cc > kCandMax) cc = kCandMax;
  const unsigned long long* gc = P.cand + (size_t)bl * kCandMax;
  for (int i = tid; i < cc; i += 1024) cand[i] = gc[i];
  int n2 = 1; while (n2 < cc) n2 <<= 1;
  for (int i = cc + tid; i < n2; i += 1024) cand[i] = 0ull;
  __syncthreads();
  // bitonic sort descending by (key desc, idx asc) composite
  for (int size = 2; size <= n2; size <<= 1) {
    for (int stride = size >> 1; stride > 0; stride >>= 1) {
      for (int i = tid; i < n2; i += 1024) {
        int j = i ^ stride;
        if (j > i) {
          unsigned long long a = cand[i], c2 = cand[j];
          bool sw = ((i & size) == 0) ? (a < c2) : (a > c2);
          if (sw) { cand[i] = c2; cand[j] = a; }
        }
      }
      __syncthreads();
    }
  }
  size_t sbase = ((size_t)b * 5 + l) * 1024;
  for (int r = tid; r < K; r += 1024) {
    unsigned long long cv = cand[r];
    unsigned int idx = 0xFFFFFFFFu - (unsigned int)(cv & 0xFFFFFFFFu);
    float s = ctr[idx];
    float4 anc = *(const float4*)(P.anchors[l] + (size_t)idx * 4);
    float4 dd  = *(const float4*)(P.deltas[l] + ((size_t)b * N + idx) * 4);
    // Box2BoxTransformLinear decode (same op order as reference, no fma)
    float w = anc.z - anc.x, hgt = anc.w - anc.y;
    float cx = (anc.x + anc.z) * 0.5f, cy = (anc.y + anc.w) * 0.5f;
    float x1 = cx - dd.x * w;
    float y1 = cy - dd.y * hgt;
    float x2 = cx + dd.z * w;
    float y2 = cy + dd.w * hgt;
    x1 = fminf(fmaxf(x1, 0.0f), 1024.0f);
    y1 = fminf(fmaxf(y1, 0.0f), 1024.0f);
    x2 = fminf(fmaxf(x2, 0.0f), 1024.0f);
    y2 = fminf(fmaxf(y2, 0.0f), 1024.0f);
    bool valid = ((x2 - x1) > 0.0f) && ((y2 - y1) > 0.0f);
    P.scores[sbase + r] = valid ? s : -INFINITY;
    *(float4*)(P.boxes + (sbase + r) * 4) = make_float4(x1, y1, x2, y2);
  }
}

// ---------------- Phase 2a: suppression bitmask (per level) ---------------
__global__ __launch_bounds__(64) void k_mask(RPNParams P) {
  int bl = blockIdx.x, b = bl / 5, l = bl % 5;
  int K = c_K[l];
  int yg = blockIdx.y;   // rows yg*64 .. yg*64+63
  int zc = blockIdx.z;   // column half
  float off = (float)l * 1025.0f;  // lvl * (IMG + 1) — replicate offset rounding!
  size_t sbase = ((size_t)b * 5 + l) * 1024;
  __shared__ float bx1[1024], by1[1024], bx2[1024], by2[1024], barea[1024];
  int tid = threadIdx.x;
  for (int i = tid; i < 1024; i += 64) {
    float4 v = make_float4(0.f, 0.f, 0.f, 0.f);
    if (i < K) {
      v = ((const float4*)P.boxes)[sbase + i];
      v.x += off; v.y += off; v.z += off; v.w += off;
    }
    bx1[i] = v.x; by1[i] = v.y; bx2[i] = v.z; by2[i] = v.w;
    barea[i] = fmaxf(v.z - v.x, 0.0f) * fmaxf(v.w - v.y, 0.0f);
  }
  __syncthreads();
  int i = yg * 64 + tid;
  if (i >= K) return;  // (after the barrier; no further barriers below)
  float x1 = bx1[i], y1 = by1[i], x2 = bx2[i], y2 = by2[i], ai = barea[i];
  unsigned int* mrow = P.mask + (sbase + (size_t)i) * 32;
  int w0 = (yg * 64 + 1) >> 5;      // wave-uniform first word with any j > row
  int nw = 32 - w0;
  int half0 = (nw + 1) >> 1;
  int wbeg = (zc == 0) ? w0 : (w0 + half0);
  int wend = (zc == 0) ? (w0 + half0) : 32;
  if (zc == 0)
    for (int w = 0; w < w0; ++w) mrow[w] = 0u;  // low words: all j <= min row
  for (int w = wbeg; w < wend; ++w) {
    unsigned int bits = 0u;
    int j0 = w << 5;
    for (int jj = 0; jj < 32; ++jj) {
      int j = j0 + jj;
      float xx1 = fmaxf(x1, bx1[j]);
      float yy1 = fmaxf(y1, by1[j]);
      float xx2 = fminf(x2, bx2[j]);
      float yy2 = fminf(y2, by2[j]);
      float ww = fmaxf(xx2 - xx1, 0.0f);
      float hh = fmaxf(yy2 - yy1, 0.0f);
      float inter = ww * hh;
      float uni = ai + barea[j] - inter + 1e-8f;  // ((ai+aj)-inter)+eps
      if ((inter / uni > 0.7f) && (j > i)) bits |= (1u << jj);
    }
    mrow[w] = bits;
  }
}

// ---------------- Phase 2b: greedy sweep, word-serial scalar chain --------
__global__ __launch_bounds__(1024) void k_sweep(RPNParams P) {
  int bl = blockIdx.x, b = bl / 5, l = bl % 5;
  int K = c_K[l];
  int NW = (K + 63) >> 6;
  size_t sbase = ((size_t)b * 5 + l) * 1024;
  __shared__ unsigned long long lmask[16 * 1000];  // 125 KiB, [row][16 words]
  __shared__ unsigned long long diag[1024];        // 8 KiB: lmask[i][i>>6]
  __shared__ unsigned long long svalid[16];
  __shared__ unsigned long long skept[16];
  int tid = threadIdx.x;
  const unsigned long long* gm = (const unsigned long long*)(P.mask + sbase * 32);
  for (int i = tid; i < K * 16; i += 1024) lmask[i] = gm[i];
  __syncthreads();
  if (tid < 1024) {
    int i = tid;
    diag[i] = (i < K) ? lmask[i * 16 + (i >> 6)] : 0ull;
  }
  __syncthreads();
  if (tid >= 64) return;  // no further barriers
  int lane = tid;
  for (int g = 0; g < 16; ++g) {
    int e = g * 64 + lane;
    bool pred = (e < K) && (P.scores[sbase + e] > -INFINITY);
    unsigned long long m = __ballot(pred);
    if (lane == 0) svalid[g] = m;
  }
  unsigned long long acc = 0ull;  // per-lane (cols 0..15): deferred suppression
  unsigned long long m1 = 0ull, m2 = 0ull;
  for (int g = 0; g < NW; ++g) {
    acc |= m1 | m2; m1 = 0ull; m2 = 0ull;  // drain pipeline at word boundary
    unsigned int alo = __builtin_amdgcn_readlane((unsigned int)acc, g);
    unsigned int ahi = __builtin_amdgcn_readlane((unsigned int)(acc >> 32), g);
    unsigned long long w = svalid[g] &
        ~(((unsigned long long)ahi << 32) | (unsigned long long)alo);
    unsigned long long dreg = diag[g * 64 + lane];  // lane b: diag of bit b
    unsigned long long kept = 0ull;
    while (w) {
      int bpos = (int)__builtin_ctzll(w);
      kept |= (1ull << bpos);
      unsigned int dlo = __builtin_amdgcn_readlane((unsigned int)dreg, bpos);
      unsigned int dhi = __builtin_amdgcn_readlane((unsigned int)(dreg >> 32), bpos);
      unsigned long long m = lmask[(g * 64 + bpos) * 16 + (lane & 15)];
      w &= ~(1ull << bpos);
      w &= ~(((unsigned long long)dhi << 32) | (unsigned long long)dlo);
      acc |= m2; m2 = m1; m1 = m;  // fold 2-iterations-old mask (latency slack)
    }
    if (lane == 0) skept[g] = kept;
  }
  for (int g = 0; g < NW; ++g) {
    unsigned long long kv = skept[g];
    int e = g * 64 + lane;
    if (e < K) P.keep[sbase + e] = (unsigned char)((kv >> lane) & 1ull);
  }
}

// ------- Phase 3: per-image 5-way merge-by-rank + keep-partition + out ----
__global__ __launch_bounds__(1024) void k_merge(RPNParams P) {
  int b = blockIdx.x;
  __shared__ unsigned long long keyL[5][1000];  // 40 KB, strictly desc per level
  __shared__ unsigned short srt[4768];          // rank -> concat idx
  __shared__ unsigned int wsum[16];
  __shared__ unsigned int sTot;
  int tid = threadIdx.x;
  int lane = tid & 63, wid = tid >> 6;

  // ---- Step 1: load + stable partition (valid first) per level ----
  for (int l = 0; l < 5; ++l) {
    int Kl = c_K[l];
    int r = tid;
    bool active = r < Kl;
    unsigned long long k = 0ull;
    bool flag = false;
    if (active) {
      float s = P.scores[((size_t)b * 5 + l) * 1024 + r];
      unsigned int fk = fkey(s);
      flag = fk > 0x007FFFFFu;  // score > -inf
      unsigned int cidx = (unsigned int)(l * 1000 + r);
      k = ((unsigned long long)fk << 32) |
          (unsigned long long)(0xFFFFFFFFu - cidx);
    }
    unsigned int fv = flag ? 1u : 0u;
    unsigned int v = fv;
    for (int d = 1; d < 64; d <<= 1) {
      unsigned int n = __shfl_up(v, (unsigned int)d, 64);
      if (lane >= d) v += n;
    }
    if (lane == 63) wsum[wid] = v;
    __syncthreads();
    if (tid == 0) {
      unsigned int acc = 0;
      for (int w = 0; w < 16; ++w) { unsigned int x = wsum[w]; wsum[w] = acc; acc += x; }
      sTot = acc;
    }
    __syncthreads();
    unsigned int excl = wsum[wid] + (v - fv);
    unsigned int nValid = sTot;
    if (active) {
      unsigned int dest = flag ? excl : (nValid + ((unsigned int)r - excl));
      keyL[l][dest] = k;
    }
    __syncthreads();
  }

  // ---- Step 2: global rank via binary search in the other 4 lists ----
  for (int e = tid; e < 4768; e += 1024) {
    int l = (e < 4000) ? (e / 1000) : 4;
    int p = e - l * 1000;
    unsigned long long k = keyL[l][p];
    int rank = p;
    #pragma unroll
    for (int l2 = 0; l2 < 5; ++l2) {
      if (l2 == l) continue;
      int lo = 0, hi = c_K[l2];
      while (lo < hi) {
        int mid = (lo + hi) >> 1;
        if (keyL[l2][mid] > k) lo = mid + 1; else hi = mid;
      }
      rank += lo;
    }
    srt[rank] = (unsigned short)(0xFFFFFFFFu - (unsigned int)(k & 0xFFFFFFFFu));
  }
  __syncthreads();

  // ---- Step 3: keep flags for 5 contiguous sorted slots per thread ----
  int base = tid * 5;
  unsigned char lf[5];
  unsigned short lc[5];
  unsigned int lsum = 0;
  for (int q = 0; q < 5; ++q) {
    int i = base + q;
    unsigned char f = 0; unsigned short cx = 0;
    if (i < 4768) {
      cx = srt[i];
      int l = cx / 1000;
      int r = (int)cx - l * 1000;
      f = P.keep[((size_t)b * 5 + l) * 1024 + r];
    }
    lf[q] = f; lc[q] = cx; lsum += f;
  }
  unsigned int v = lsum;
  for (int d = 1; d < 64; d <<= 1) {
    unsigned int n = __shfl_up(v, (unsigned int)d, 64);
    if (lane >= d) v += n;
  }
  if (lane == 63) wsum[wid] = v;
  __syncthreads();
  if (tid == 0) {
    unsigned int acc = 0;
    for (int w = 0; w < 16; ++w) { unsigned int x = wsum[w]; wsum[w] = acc; acc += x; }
    sTot = acc;
  }
  __syncthreads();
  unsigned int excl = wsum[wid] + (v - lsum);  // kept count before slot `base`
  unsigned int tot = sTot;
  for (int q = 0; q < 5; ++q) {
    int i = base + q;
    if (i >= 4768) break;
    unsigned int cidx = (unsigned int)lc[q];
    int l = (int)(cidx / 1000u);
    int r = (int)cidx - l * 1000;
    size_t sb = ((size_t)b * 5 + l) * 1024 + r;
    unsigned char f = lf[q];
    unsigned int pos = f ? excl : (tot + ((unsigned int)i - excl));
    excl += f;
    if (pos < 1000u) {
      float4 bx = ((const float4*)P.boxes)[sb];
      float sc = f ? P.scores[sb] : -INFINITY;
      float* o = P.out + ((size_t)b * 1000 + pos) * 5;
      o[0] = bx.x; o[1] = bx.y; o[2] = bx.z; o[3] = bx.w; o[4] = sc;
    }
  }
}

}  // namespace

extern "C" void kernel_launch(void* const* d_in, const int* in_sizes, int n_in,
                              void* d_out, int out_size, void* d_ws, size_t ws_size,
                              hipStream_t stream) {
  (void)out_size; (void)ws_size;
  RPNParams P;
  bool interleaved = (n_in >= 3) && (in_sizes[2] == 786432);
  for (int l = 0; l < 5; ++l) {
    if (interleaved) {
      P.deltas[l]  = (const float*)d_in[3 * l + 0];
      P.ctr[l]     = (const float*)d_in[3 * l + 1];
      P.anchors[l] = (const float*)d_in[3 * l + 2];
    } else {
      P.deltas[l]  = (const float*)d_in[l];
      P.ctr[l]     = (const float*)d_in[5 + l];
      P.anchors[l] = (const float*)d_in[10 + l];
    }
  }
  char* ws = (char*)d_ws;
  P.scores = (float*)(ws + 0);               // 163840 B
  P.boxes  = (float*)(ws + 163840);          // 655360 B
  P.keep   = (unsigned char*)(ws + 819200);  // 40960 B
  P.mask   = (unsigned int*)(ws + 860160);   // 5242880 B
  P.cand   = (unsigned long long*)(ws + 860160);  // 1310720 B, aliases mask (used before k_mask)
  P.ghist0 = (unsigned int*)(ws + 6103040);  // 40960 B
  P.ghist1 = (unsigned int*)(ws + 6144000);  // 40960 B
  P.ccount = (unsigned int*)(ws + 6103040);  // aliases ghist0; entry bl at [bl*256] (zeroed in k_thresh)
  P.thresh = (unsigned int*)(ws + 6184960);  // 160 B
  P.out    = (float*)d_out;

  hipMemsetAsync(ws + 6103040, 0, 81920, stream);  // zero both histograms
  hipLaunchKernelGGL(k_hist0, dim3(40, 32), dim3(256), 0, stream, P);
  hipLaunchKernelGGL(k_hist1, dim3(40, 32), dim3(256), 0, stream, P);
  hipLaunchKernelGGL(k_thresh, dim3(40), dim3(256), 0, stream, P);
  hipLaunchKernelGGL(k_compact, dim3(40, 32), dim3(256), 0, stream, P);
  hipLaunchKernelGGL(k_select, dim3(40), dim3(1024), 0, stream, P);
  hipLaunchKernelGGL(k_mask, dim3(40, 16, 2), dim3(64), 0, stream, P);
  hipLaunchKernelGGL(k_sweep, dim3(40), dim3(1024), 0, stream, P);
  hipLaunchKernelGGL(k_merge, dim3(8), dim3(1024), 0, stream, P);
}

// Round 7
// 197.048 us; speedup vs baseline: 1.6195x; 1.0110x over previous
//
#include <hip/hip_runtime.h>
#include <cstdint>
#include <cstddef>
#include <cmath>

#pragma clang fp contract(off)

namespace {

constexpr int kCandMax = 4096;

__device__ __constant__ int c_N[5] = {196608, 49152, 12288, 3072, 768};
__device__ __constant__ int c_K[5] = {1000, 1000, 1000, 1000, 768};

struct RPNParams {
  const float* deltas[5];
  const float* ctr[5];
  const float* anchors[5];
  float* scores;         // [8][5][1024] masked scores, per-level sorted desc
  float* boxes;          // [8][5][1024][4] clipped boxes, per-level sorted
  unsigned char* keep;   // [8][5][1024]
  unsigned int* mask;    // [8][5][1024][32] suppression bits (j in bits, row i)
  unsigned int* ghist0;  // [40][256]
  unsigned int* ghist1;  // [40][256]
  unsigned int* ccount;  // aliases ghist0: counter bl at [bl*256] (1KB apart, own L2 line)
  unsigned int* thresh;  // [40] 16-bit-refined key threshold
  unsigned long long* cand;  // [40][4096] (aliases mask region; used before k_mask)
  float* out;            // [8][1000][5]
};

// monotonic float->uint map (larger float => larger uint)
__device__ __forceinline__ unsigned int fkey(float f) {
  unsigned int u = __float_as_uint(f);
  return (u & 0x80000000u) ? ~u : (u | 0x80000000u);
}

__device__ __forceinline__ unsigned long long readlane64(unsigned long long v, int lane) {
  unsigned int lo = __builtin_amdgcn_readlane((unsigned int)v, lane);
  unsigned int hi = __builtin_amdgcn_readlane((unsigned int)(v >> 32), lane);
  return ((unsigned long long)hi << 32) | (unsigned long long)lo;
}

// ---------------- Phase 1a: 8-bit histogram of score keys ----------------
__global__ __launch_bounds__(256) void k_hist0(RPNParams P) {
  int bl = blockIdx.x, b = bl / 5, l = bl % 5;
  int N = c_N[l];
  int chunk = (N + 31) / 32;  // all chunks are multiples of 4
  int i0 = blockIdx.y * chunk;
  int i1 = i0 + chunk; if (i1 > N) i1 = N;
  const float4* c4 = (const float4*)(P.ctr[l] + (size_t)b * N);
  __shared__ unsigned int wh[4][256];
  int tid = threadIdx.x, wid = tid >> 6;
  for (int i = tid; i < 1024; i += 256) ((unsigned int*)wh)[i] = 0u;
  __syncthreads();
  int q0 = i0 >> 2, q1 = i1 >> 2;
  for (int q = q0 + tid; q < q1; q += 256) {
    float4 v = c4[q];
    atomicAdd(&wh[wid][fkey(v.x) >> 24], 1u);
    atomicAdd(&wh[wid][fkey(v.y) >> 24], 1u);
    atomicAdd(&wh[wid][fkey(v.z) >> 24], 1u);
    atomicAdd(&wh[wid][fkey(v.w) >> 24], 1u);
  }
  __syncthreads();
  int bin = tid;
  unsigned int s = wh[0][bin] + wh[1][bin] + wh[2][bin] + wh[3][bin];
  if (s) atomicAdd(&P.ghist0[bl * 256 + bin], s);
}

// ---------------- Phase 1b: refine to 16-bit within chosen top byte ------
__global__ __launch_bounds__(256) void k_hist1(RPNParams P) {
  int bl = blockIdx.x, b = bl / 5, l = bl % 5;
  int N = c_N[l], K = c_K[l];
  int chunk = (N + 31) / 32;
  int i0 = blockIdx.y * chunk;
  int i1 = i0 + chunk; if (i1 > N) i1 = N;
  const float4* c4 = (const float4*)(P.ctr[l] + (size_t)b * N);
  __shared__ unsigned int wh[4][256];
  __shared__ unsigned int sV0;
  int tid = threadIdx.x, wid = tid >> 6;
  if (tid < 256) wh[0][tid] = P.ghist0[bl * 256 + tid];
  __syncthreads();
  if (tid == 0) {
    unsigned int kk = (unsigned int)K, cum = 0;
    int v = 255;
    for (; v > 0; --v) { unsigned int x = wh[0][v]; if (cum + x >= kk) break; cum += x; }
    sV0 = (unsigned int)v;
  }
  __syncthreads();
  unsigned int v0 = sV0;
  for (int i = tid; i < 1024; i += 256) ((unsigned int*)wh)[i] = 0u;
  __syncthreads();
  int q0 = i0 >> 2, q1 = i1 >> 2;
  for (int q = q0 + tid; q < q1; q += 256) {
    float4 v = c4[q];
    unsigned int u0 = fkey(v.x), u1 = fkey(v.y), u2 = fkey(v.z), u3 = fkey(v.w);
    if ((u0 >> 24) == v0) atomicAdd(&wh[wid][(u0 >> 16) & 255u], 1u);
    if ((u1 >> 24) == v0) atomicAdd(&wh[wid][(u1 >> 16) & 255u], 1u);
    if ((u2 >> 24) == v0) atomicAdd(&wh[wid][(u2 >> 16) & 255u], 1u);
    if ((u3 >> 24) == v0) atomicAdd(&wh[wid][(u3 >> 16) & 255u], 1u);
  }
  __syncthreads();
  int bin = tid;
  unsigned int s = wh[0][bin] + wh[1][bin] + wh[2][bin] + wh[3][bin];
  if (s) atomicAdd(&P.ghist1[bl * 256 + bin], s);
}

// ------- Phase 1c: per-(img,lvl) threshold via suffix-scan + bsearch -----
__global__ __launch_bounds__(256) void k_thresh(RPNParams P) {
  int bl = blockIdx.x;
  int K = c_K[bl % 5];
  __shared__ unsigned int S[257];
  __shared__ unsigned int sV0, sKK;
  int tid = threadIdx.x;
  S[tid] = P.ghist0[bl * 256 + tid];
  if (tid == 0) S[256] = 0u;
  __syncthreads();
  if (tid == 0) P.ccount[bl * 256] = 0u;  // after row read; row bl is block-private
  for (int d = 1; d < 256; d <<= 1) {
    unsigned int v = (tid + d < 256) ? S[tid + d] : 0u;
    __syncthreads();
    S[tid] += v;
    __syncthreads();
  }
  if (tid == 0) {
    int lo = 0, hi = 255;
    while (lo < hi) { int mid = (lo + hi + 1) >> 1; if (S[mid] >= (unsigned int)K) lo = mid; else hi = mid - 1; }
    sV0 = (unsigned int)lo;
    sKK = (unsigned int)K - S[lo + 1];
  }
  __syncthreads();
  S[tid] = P.ghist1[bl * 256 + tid];
  __syncthreads();
  for (int d = 1; d < 256; d <<= 1) {
    unsigned int v = (tid + d < 256) ? S[tid + d] : 0u;
    __syncthreads();
    S[tid] += v;
    __syncthreads();
  }
  if (tid == 0) {
    unsigned int kk = sKK;
    int lo = 0, hi = 255;
    while (lo < hi) { int mid = (lo + hi + 1) >> 1; if (S[mid] >= kk) lo = mid; else hi = mid - 1; }
    P.thresh[bl] = ((sV0 << 8) | (unsigned int)lo) << 16;
  }
}

// ------- Phase 1d: compaction, ONE global atomic per block ---------------
__global__ __launch_bounds__(256) void k_compact(RPNParams P) {
  int bl = blockIdx.x, b = bl / 5, l = bl % 5;
  int N = c_N[l];
  int chunk = (N + 31) / 32;
  int i0 = blockIdx.y * chunk;
  int i1 = i0 + chunk; if (i1 > N) i1 = N;
  const float4* c4 = (const float4*)(P.ctr[l] + (size_t)b * N);
  unsigned int T = P.thresh[bl];
  unsigned long long* cand = P.cand + (size_t)bl * kCandMax;
  __shared__ unsigned int wcnt[4], wbase[4];
  int tid = threadIdx.x, lane = tid & 63, wid = tid >> 6;
  int q0 = i0 >> 2, q1 = i1 >> 2;
  // pass 1: count
  unsigned int cnt = 0;
  for (int q = q0 + tid; q < q1; q += 256) {
    float4 v = c4[q];
    cnt += (fkey(v.x) >= T) + (fkey(v.y) >= T) + (fkey(v.z) >= T) + (fkey(v.w) >= T);
  }
  for (int d = 32; d > 0; d >>= 1) cnt += (unsigned int)__shfl_xor((int)cnt, d, 64);
  if (lane == 0) wcnt[wid] = cnt;
  __syncthreads();
  if (tid == 0) {
    unsigned int tot = wcnt[0] + wcnt[1] + wcnt[2] + wcnt[3];
    unsigned int base = tot ? atomicAdd(&P.ccount[bl * 256], tot) : 0u;
    unsigned int acc = base;
    for (int w = 0; w < 4; ++w) { unsigned int x = wcnt[w]; wbase[w] = acc; acc += x; }
  }
  __syncthreads();
  unsigned int off = wbase[wid];
  unsigned long long lmlt = (1ull << lane) - 1ull;
  for (int q = q0 + tid; q < q1; q += 256) {
    float4 v = c4[q];
    unsigned int u[4] = {fkey(v.x), fkey(v.y), fkey(v.z), fkey(v.w)};
    #pragma unroll
    for (int k = 0; k < 4; ++k) {
      bool pred = (u[k] >= T);
      unsigned long long m = __ballot(pred);
      if (pred) {
        unsigned int pos = off + (unsigned int)__popcll(m & lmlt);
        if (pos < (unsigned int)kCandMax) {
          unsigned int idx = (unsigned int)(q * 4 + k);
          cand[pos] = ((unsigned long long)u[k] << 32) |
                      (unsigned long long)(0xFFFFFFFFu - idx);
        }
      }
      off += (unsigned int)__popcll(m);
    }
  }
}

// ---- Phase 1e: sort candidates, decode+clip boxes (40 blocks) -----------
__global__ __launch_bounds__(1024) void k_select(RPNParams P) {
  int bl = blockIdx.x, b = bl / 5, l = bl % 5;
  int N = c_N[l], K = c_K[l];
  const float* ctr = P.ctr[l] + (size_t)b * N;
  __shared__ unsigned long long cand[kCandMax];
  int tid = threadIdx.x;
  int cc = (int)P.ccount[bl * 256]; if (cc > kCandMax) cc = kCandMax;
  const unsigned long long* gc = P.cand + (size_t)bl * kCandMax;
  for (int i = tid; i < cc; i += 1024) cand[i] = gc[i];
  int n2 = 1; while (n2 < cc) n2 <<= 1;
  for (int i = cc + tid; i < n2; i += 1024) cand[i] = 0ull;
  __syncthreads();
  // bitonic sort descending by (key desc, idx asc) composite
  for (int size = 2; size <= n2; size <<= 1) {
    for (int stride = size >> 1; stride > 0; stride >>= 1) {
      for (int i = tid; i < n2; i += 1024) {
        int j = i ^ stride;
        if (j > i) {
          unsigned long long a = cand[i], c2 = cand[j];
          bool sw = ((i & size) == 0) ? (a < c2) : (a > c2);
          if (sw) { cand[i] = c2; cand[j] = a; }
        }
      }
      __syncthreads();
    }
  }
  size_t sbase = ((size_t)b * 5 + l) * 1024;
  for (int r = tid; r < K; r += 1024) {
    unsigned long long cv = cand[r];
    unsigned int idx = 0xFFFFFFFFu - (unsigned int)(cv & 0xFFFFFFFFu);
    float s = ctr[idx];
    float4 anc = *(const float4*)(P.anchors[l] + (size_t)idx * 4);
    float4 dd  = *(const float4*)(P.deltas[l] + ((size_t)b * N + idx) * 4);
    // Box2BoxTransformLinear decode (same op order as reference, no fma)
    float w = anc.z - anc.x, hgt = anc.w - anc.y;
    float cx = (anc.x + anc.z) * 0.5f, cy = (anc.y + anc.w) * 0.5f;
    float x1 = cx - dd.x * w;
    float y1 = cy - dd.y * hgt;
    float x2 = cx + dd.z * w;
    float y2 = cy + dd.w * hgt;
    x1 = fminf(fmaxf(x1, 0.0f), 1024.0f);
    y1 = fminf(fmaxf(y1, 0.0f), 1024.0f);
    x2 = fminf(fmaxf(x2, 0.0f), 1024.0f);
    y2 = fminf(fmaxf(y2, 0.0f), 1024.0f);
    bool valid = ((x2 - x1) > 0.0f) && ((y2 - y1) > 0.0f);
    P.scores[sbase + r] = valid ? s : -INFINITY;
    *(float4*)(P.boxes + (sbase + r) * 4) = make_float4(x1, y1, x2, y2);
  }
}

// ---------------- Phase 2a: suppression bitmask (per level) ---------------
__global__ __launch_bounds__(64) void k_mask(RPNParams P) {
  int bl = blockIdx.x, b = bl / 5, l = bl % 5;
  int K = c_K[l];
  int yg = blockIdx.y;   // rows yg*64 .. yg*64+63
  int zc = blockIdx.z;   // column half
  float off = (float)l * 1025.0f;  // lvl * (IMG + 1) — replicate offset rounding!
  size_t sbase = ((size_t)b * 5 + l) * 1024;
  __shared__ float bx1[1024], by1[1024], bx2[1024], by2[1024], barea[1024];
  int tid = threadIdx.x;
  for (int i = tid; i < 1024; i += 64) {
    float4 v = make_float4(0.f, 0.f, 0.f, 0.f);
    if (i < K) {
      v = ((const float4*)P.boxes)[sbase + i];
      v.x += off; v.y += off; v.z += off; v.w += off;
    }
    bx1[i] = v.x; by1[i] = v.y; bx2[i] = v.z; by2[i] = v.w;
    barea[i] = fmaxf(v.z - v.x, 0.0f) * fmaxf(v.w - v.y, 0.0f);
  }
  __syncthreads();
  int i = yg * 64 + tid;
  if (i >= K) return;  // (after the barrier; no further barriers below)
  float x1 = bx1[i], y1 = by1[i], x2 = bx2[i], y2 = by2[i], ai = barea[i];
  unsigned int* mrow = P.mask + (sbase + (size_t)i) * 32;
  int w0 = (yg * 64 + 1) >> 5;      // wave-uniform first word with any j > row
  int nw = 32 - w0;
  int half0 = (nw + 1) >> 1;
  int wbeg = (zc == 0) ? w0 : (w0 + half0);
  int wend = (zc == 0) ? (w0 + half0) : 32;
  if (zc == 0)
    for (int w = 0; w < w0; ++w) mrow[w] = 0u;  // low words: all j <= min row
  for (int w = wbeg; w < wend; ++w) {
    unsigned int bits = 0u;
    int j0 = w << 5;
    for (int jj = 0; jj < 32; ++jj) {
      int j = j0 + jj;
      float xx1 = fmaxf(x1, bx1[j]);
      float yy1 = fmaxf(y1, by1[j]);
      float xx2 = fminf(x2, bx2[j]);
      float yy2 = fminf(y2, by2[j]);
      float ww = fmaxf(xx2 - xx1, 0.0f);
      float hh = fmaxf(yy2 - yy1, 0.0f);
      float inter = ww * hh;
      float uni = ai + barea[j] - inter + 1e-8f;  // ((ai+aj)-inter)+eps
      if ((inter / uni > 0.7f) && (j > i)) bits |= (1u << jj);
    }
    mrow[w] = bits;
  }
}

// ---------------- Phase 2b: greedy sweep -----------------------------------
// Serial decision chain is REGISTER-ONLY: within a 64-box word, w/kept are
// wave-uniform scalars; per kept box: ctz -> readlane64(diag) -> andn
// (~23 cyc, no memory). Cross-word suppression is a separate data-parallel
// phase after each word: lanes OR the kept rows' mask words into per-lane
// accumulators (lane>>4 picks kept-bit subset mod 4, lane&15 the column;
// dual accumulators break the read->OR chain). Acc consumed only at word
// boundaries via readlane64 combine of the 4 subset lanes.
__global__ __launch_bounds__(1024) void k_sweep(RPNParams P) {
  int bl = blockIdx.x, b = bl / 5, l = bl % 5;
  int K = c_K[l];
  int NW = (K + 63) >> 6;
  size_t sbase = ((size_t)b * 5 + l) * 1024;
  __shared__ alignas(16) unsigned long long lmask[16 * 1000];  // 125 KiB [row][16]
  __shared__ unsigned long long diag[1024];        // diag[i] = lmask[i][i>>6]
  __shared__ unsigned long long svalid[16];
  __shared__ unsigned long long skept[16];
  int tid = threadIdx.x;
  const ulonglong2* gm2 = (const ulonglong2*)(P.mask + sbase * 32);
  // staged load (16B/thread) + diag derived from the loaded registers
  for (int j = tid; j < K * 8; j += 1024) {
    ulonglong2 v = gm2[j];
    ((ulonglong2*)lmask)[j] = v;
    int w0i = j * 2;
    int row = w0i >> 4;
    int dcol = row >> 6;
    int col0 = w0i & 15;
    if (col0 == dcol) diag[row] = v.x;
    else if (col0 + 1 == dcol) diag[row] = v.y;
  }
  for (int i = K + tid; i < 1024; i += 1024) diag[i] = 0ull;
  __syncthreads();
  if (tid >= 64) return;  // single wave from here; no further barriers
  int lane = tid;
  for (int g = 0; g < NW; ++g) {
    int e = g * 64 + lane;
    bool pred = (e < K) && (P.scores[sbase + e] > -INFINITY);
    unsigned long long m = __ballot(pred);
    if (lane == 0) svalid[g] = m;
  }
  int sub = lane >> 4, col = lane & 15;
  unsigned long long submask = 0x1111111111111111ull << sub;
  unsigned long long accA = 0ull, accB = 0ull;  // per-lane partial OR of kept rows
  for (int g = 0; g < NW; ++g) {
    // combine the 4 subset-partials for column g (lanes g, g+16, g+32, g+48)
    unsigned long long am = accA | accB;
    unsigned long long suppr = readlane64(am, g) | readlane64(am, g + 16) |
                               readlane64(am, g + 32) | readlane64(am, g + 48);
    unsigned long long w = svalid[g] & ~suppr;
    unsigned long long dreg = diag[g * 64 + lane];  // lane p holds diag of box p
    unsigned long long kept = 0ull;
    while (w) {  // wave-uniform scalar chain, registers only
      int p = (int)__builtin_ctzll(w);
      kept |= (1ull << p);
      unsigned long long d = readlane64(dreg, p);
      w &= ~((1ull << p) | d);
    }
    if (lane == 0) skept[g] = kept;
    // data-parallel OR of kept rows into acc (for later words)
    unsigned long long kk = kept & submask;
    while (kk) {
      int p = (int)__builtin_ctzll(kk); kk &= kk - 1ull;
      unsigned long long mA = lmask[(g * 64 + p) * 16 + col];
      if (kk) {
        int p2 = (int)__builtin_ctzll(kk); kk &= kk - 1ull;
        accB |= lmask[(g * 64 + p2) * 16 + col];
      }
      accA |= mA;
    }
  }
  for (int g = 0; g < NW; ++g) {
    unsigned long long kv = skept[g];
    int e = g * 64 + lane;
    if (e < K) P.keep[sbase + e] = (unsigned char)((kv >> lane) & 1ull);
  }
}

// ------- Phase 3: per-image 5-way merge-by-rank + keep-partition + out ----
__global__ __launch_bounds__(1024) void k_merge(RPNParams P) {
  int b = blockIdx.x;
  __shared__ unsigned long long keyL[5][1000];  // 40 KB, strictly desc per level
  __shared__ unsigned short srt[4768];          // rank -> concat idx
  __shared__ unsigned int wsum[16];
  __shared__ unsigned int sTot;
  int tid = threadIdx.x;
  int lane = tid & 63, wid = tid >> 6;

  // ---- Step 1: load + stable partition (valid first) per level ----
  for (int l = 0; l < 5; ++l) {
    int Kl = c_K[l];
    int r = tid;
    bool active = r < Kl;
    unsigned long long k = 0ull;
    bool flag = false;
    if (active) {
      float s = P.scores[((size_t)b * 5 + l) * 1024 + r];
      unsigned int fk = fkey(s);
      flag = fk > 0x007FFFFFu;  // score > -inf
      unsigned int cidx = (unsigned int)(l * 1000 + r);
      k = ((unsigned long long)fk << 32) |
          (unsigned long long)(0xFFFFFFFFu - cidx);
    }
    unsigned int fv = flag ? 1u : 0u;
    unsigned int v = fv;
    for (int d = 1; d < 64; d <<= 1) {
      unsigned int n = __shfl_up(v, (unsigned int)d, 64);
      if (lane >= d) v += n;
    }
    if (lane == 63) wsum[wid] = v;
    __syncthreads();
    if (tid == 0) {
      unsigned int acc = 0;
      for (int w = 0; w < 16; ++w) { unsigned int x = wsum[w]; wsum[w] = acc; acc += x; }
      sTot = acc;
    }
    __syncthreads();
    unsigned int excl = wsum[wid] + (v - fv);
    unsigned int nValid = sTot;
    if (active) {
      unsigned int dest = flag ? excl : (nValid + ((unsigned int)r - excl));
      keyL[l][dest] = k;
    }
    __syncthreads();
  }

  // ---- Step 2: global rank via binary search in the other 4 lists ----
  for (int e = tid; e < 4768; e += 1024) {
    int l = (e < 4000) ? (e / 1000) : 4;
    int p = e - l * 1000;
    unsigned long long k = keyL[l][p];
    int rank = p;
    #pragma unroll
    for (int l2 = 0; l2 < 5; ++l2) {
      if (l2 == l) continue;
      int lo = 0, hi = c_K[l2];
      while (lo < hi) {
        int mid = (lo + hi) >> 1;
        if (keyL[l2][mid] > k) lo = mid + 1; else hi = mid;
      }
      rank += lo;
    }
    srt[rank] = (unsigned short)(0xFFFFFFFFu - (unsigned int)(k & 0xFFFFFFFFu));
  }
  __syncthreads();

  // ---- Step 3: keep flags for 5 contiguous sorted slots per thread ----
  int base = tid * 5;
  unsigned char lf[5];
  unsigned short lc[5];
  unsigned int lsum = 0;
  for (int q = 0; q < 5; ++q) {
    int i = base + q;
    unsigned char f = 0; unsigned short cx = 0;
    if (i < 4768) {
      cx = srt[i];
      int l = cx / 1000;
      int r = (int)cx - l * 1000;
      f = P.keep[((size_t)b * 5 + l) * 1024 + r];
    }
    lf[q] = f; lc[q] = cx; lsum += f;
  }
  unsigned int v = lsum;
  for (int d = 1; d < 64; d <<= 1) {
    unsigned int n = __shfl_up(v, (unsigned int)d, 64);
    if (lane >= d) v += n;
  }
  if (lane == 63) wsum[wid] = v;
  __syncthreads();
  if (tid == 0) {
    unsigned int acc = 0;
    for (int w = 0; w < 16; ++w) { unsigned int x = wsum[w]; wsum[w] = acc; acc += x; }
    sTot = acc;
  }
  __syncthreads();
  unsigned int excl = wsum[wid] + (v - lsum);  // kept count before slot `base`
  unsigned int tot = sTot;
  for (int q = 0; q < 5; ++q) {
    int i = base + q;
    if (i >= 4768) break;
    unsigned int cidx = (unsigned int)lc[q];
    int l = (int)(cidx / 1000u);
    int r = (int)cidx - l * 1000;
    size_t sb = ((size_t)b * 5 + l) * 1024 + r;
    unsigned char f = lf[q];
    unsigned int pos = f ? excl : (tot + ((unsigned int)i - excl));
    excl += f;
    if (pos < 1000u) {
      float4 bx = ((const float4*)P.boxes)[sb];
      float sc = f ? P.scores[sb] : -INFINITY;
      float* o = P.out + ((size_t)b * 1000 + pos) * 5;
      o[0] = bx.x; o[1] = bx.y; o[2] = bx.z; o[3] = bx.w; o[4] = sc;
    }
  }
}

}  // namespace

extern "C" void kernel_launch(void* const* d_in, const int* in_sizes, int n_in,
                              void* d_out, int out_size, void* d_ws, size_t ws_size,
                              hipStream_t stream) {
  (void)out_size; (void)ws_size;
  RPNParams P;
  bool interleaved = (n_in >= 3) && (in_sizes[2] == 786432);
  for (int l = 0; l < 5; ++l) {
    if (interleaved) {
      P.deltas[l]  = (const float*)d_in[3 * l + 0];
      P.ctr[l]     = (const float*)d_in[3 * l + 1];
      P.anchors[l] = (const float*)d_in[3 * l + 2];
    } else {
      P.deltas[l]  = (const float*)d_in[l];
      P.ctr[l]     = (const float*)d_in[5 + l];
      P.anchors[l] = (const float*)d_in[10 + l];
    }
  }
  char* ws = (char*)d_ws;
  P.scores = (float*)(ws + 0);               // 163840 B
  P.boxes  = (float*)(ws + 163840);          // 655360 B
  P.keep   = (unsigned char*)(ws + 819200);  // 40960 B
  P.mask   = (unsigned int*)(ws + 860160);   // 5242880 B
  P.cand   = (unsigned long long*)(ws + 860160);  // 1310720 B, aliases mask (used before k_mask)
  P.ghist0 = (unsigned int*)(ws + 6103040);  // 40960 B
  P.ghist1 = (unsigned int*)(ws + 6144000);  // 40960 B
  P.ccount = (unsigned int*)(ws + 6103040);  // aliases ghist0; entry bl at [bl*256] (zeroed in k_thresh)
  P.thresh = (unsigned int*)(ws + 6184960);  // 160 B
  P.out    = (float*)d_out;

  hipMemsetAsync(ws + 6103040, 0, 81920, stream);  // zero both histograms
  hipLaunchKernelGGL(k_hist0, dim3(40, 32), dim3(256), 0, stream, P);
  hipLaunchKernelGGL(k_hist1, dim3(40, 32), dim3(256), 0, stream, P);
  hipLaunchKernelGGL(k_thresh, dim3(40), dim3(256), 0, stream, P);
  hipLaunchKernelGGL(k_compact, dim3(40, 32), dim3(256), 0, stream, P);
  hipLaunchKernelGGL(k_select, dim3(40), dim3(1024), 0, stream, P);
  hipLaunchKernelGGL(k_mask, dim3(40, 16, 2), dim3(64), 0, stream, P);
  hipLaunchKernelGGL(k_sweep, dim3(40), dim3(1024), 0, stream, P);
  hipLaunchKernelGGL(k_merge, dim3(8), dim3(1024), 0, stream, P);
}

// Round 8
// 164.793 us; speedup vs baseline: 1.9365x; 1.1957x over previous
//
#include <hip/hip_runtime.h>
#include <cstdint>
#include <cstddef>
#include <cmath>

#pragma clang fp contract(off)

namespace {

constexpr int kCandMax = 4096;

__device__ __constant__ int c_N[5] = {196608, 49152, 12288, 3072, 768};
__device__ __constant__ int c_K[5] = {1000, 1000, 1000, 1000, 768};

struct RPNParams {
  const float* deltas[5];
  const float* ctr[5];
  const float* anchors[5];
  float* scores;         // [8][5][1024] masked scores, per-level sorted desc
  float* boxes;          // [8][5][1024][4] clipped boxes, per-level sorted
  unsigned char* keep;   // [8][5][1024]
  unsigned int* mask;    // [8][5][1024][32]; diag u64 slot holds TRANSPOSED in-word bits
  unsigned int* ghist0;  // [40][256]
  unsigned int* ghist1;  // [40][256]
  unsigned int* ccount;  // aliases ghist0: counter bl at [bl*256]
  unsigned int* thresh;  // [40]
  unsigned long long* cand;  // [40][4096] (aliases mask region; used before k_mask)
  float* out;            // [8][1000][5]
};

// monotonic float->uint map (larger float => larger uint)
__device__ __forceinline__ unsigned int fkey(float f) {
  unsigned int u = __float_as_uint(f);
  return (u & 0x80000000u) ? ~u : (u | 0x80000000u);
}

__device__ __forceinline__ unsigned long long readlane64(unsigned long long v, int lane) {
  unsigned int lo = __builtin_amdgcn_readlane((unsigned int)v, lane);
  unsigned int hi = __builtin_amdgcn_readlane((unsigned int)(v >> 32), lane);
  return ((unsigned long long)hi << 32) | (unsigned long long)lo;
}

// ---------------- Phase 1a: 8-bit histogram of score keys ----------------
__global__ __launch_bounds__(256) void k_hist0(RPNParams P) {
  int bl = blockIdx.x, b = bl / 5, l = bl % 5;
  int N = c_N[l];
  int chunk = (N + 31) / 32;  // all chunks are multiples of 4
  int i0 = blockIdx.y * chunk;
  int i1 = i0 + chunk; if (i1 > N) i1 = N;
  const float4* c4 = (const float4*)(P.ctr[l] + (size_t)b * N);
  __shared__ unsigned int wh[4][256];
  int tid = threadIdx.x, wid = tid >> 6;
  for (int i = tid; i < 1024; i += 256) ((unsigned int*)wh)[i] = 0u;
  __syncthreads();
  int q0 = i0 >> 2, q1 = i1 >> 2;
  for (int q = q0 + tid; q < q1; q += 256) {
    float4 v = c4[q];
    atomicAdd(&wh[wid][fkey(v.x) >> 24], 1u);
    atomicAdd(&wh[wid][fkey(v.y) >> 24], 1u);
    atomicAdd(&wh[wid][fkey(v.z) >> 24], 1u);
    atomicAdd(&wh[wid][fkey(v.w) >> 24], 1u);
  }
  __syncthreads();
  int bin = tid;
  unsigned int s = wh[0][bin] + wh[1][bin] + wh[2][bin] + wh[3][bin];
  if (s) atomicAdd(&P.ghist0[bl * 256 + bin], s);
}

// ---------------- Phase 1b: refine to 16-bit within chosen top byte ------
__global__ __launch_bounds__(256) void k_hist1(RPNParams P) {
  int bl = blockIdx.x, b = bl / 5, l = bl % 5;
  int N = c_N[l], K = c_K[l];
  int chunk = (N + 31) / 32;
  int i0 = blockIdx.y * chunk;
  int i1 = i0 + chunk; if (i1 > N) i1 = N;
  const float4* c4 = (const float4*)(P.ctr[l] + (size_t)b * N);
  __shared__ unsigned int wh[4][256];
  __shared__ unsigned int sV0;
  int tid = threadIdx.x, wid = tid >> 6;
  if (tid < 256) wh[0][tid] = P.ghist0[bl * 256 + tid];
  __syncthreads();
  if (tid == 0) {
    unsigned int kk = (unsigned int)K, cum = 0;
    int v = 255;
    for (; v > 0; --v) { unsigned int x = wh[0][v]; if (cum + x >= kk) break; cum += x; }
    sV0 = (unsigned int)v;
  }
  __syncthreads();
  unsigned int v0 = sV0;
  for (int i = tid; i < 1024; i += 256) ((unsigned int*)wh)[i] = 0u;
  __syncthreads();
  int q0 = i0 >> 2, q1 = i1 >> 2;
  for (int q = q0 + tid; q < q1; q += 256) {
    float4 v = c4[q];
    unsigned int u0 = fkey(v.x), u1 = fkey(v.y), u2 = fkey(v.z), u3 = fkey(v.w);
    if ((u0 >> 24) == v0) atomicAdd(&wh[wid][(u0 >> 16) & 255u], 1u);
    if ((u1 >> 24) == v0) atomicAdd(&wh[wid][(u1 >> 16) & 255u], 1u);
    if ((u2 >> 24) == v0) atomicAdd(&wh[wid][(u2 >> 16) & 255u], 1u);
    if ((u3 >> 24) == v0) atomicAdd(&wh[wid][(u3 >> 16) & 255u], 1u);
  }
  __syncthreads();
  int bin = tid;
  unsigned int s = wh[0][bin] + wh[1][bin] + wh[2][bin] + wh[3][bin];
  if (s) atomicAdd(&P.ghist1[bl * 256 + bin], s);
}

// ------- Phase 1c: per-(img,lvl) threshold via suffix-scan + bsearch -----
__global__ __launch_bounds__(256) void k_thresh(RPNParams P) {
  int bl = blockIdx.x;
  int K = c_K[bl % 5];
  __shared__ unsigned int S[257];
  __shared__ unsigned int sV0, sKK;
  int tid = threadIdx.x;
  S[tid] = P.ghist0[bl * 256 + tid];
  if (tid == 0) S[256] = 0u;
  __syncthreads();
  if (tid == 0) P.ccount[bl * 256] = 0u;  // after row read; row bl is block-private
  for (int d = 1; d < 256; d <<= 1) {
    unsigned int v = (tid + d < 256) ? S[tid + d] : 0u;
    __syncthreads();
    S[tid] += v;
    __syncthreads();
  }
  if (tid == 0) {
    int lo = 0, hi = 255;
    while (lo < hi) { int mid = (lo + hi + 1) >> 1; if (S[mid] >= (unsigned int)K) lo = mid; else hi = mid - 1; }
    sV0 = (unsigned int)lo;
    sKK = (unsigned int)K - S[lo + 1];
  }
  __syncthreads();
  S[tid] = P.ghist1[bl * 256 + tid];
  __syncthreads();
  for (int d = 1; d < 256; d <<= 1) {
    unsigned int v = (tid + d < 256) ? S[tid + d] : 0u;
    __syncthreads();
    S[tid] += v;
    __syncthreads();
  }
  if (tid == 0) {
    unsigned int kk = sKK;
    int lo = 0, hi = 255;
    while (lo < hi) { int mid = (lo + hi + 1) >> 1; if (S[mid] >= kk) lo = mid; else hi = mid - 1; }
    P.thresh[bl] = ((sV0 << 8) | (unsigned int)lo) << 16;
  }
}

// ------- Phase 1d: compaction, ONE global atomic per block ---------------
__global__ __launch_bounds__(256) void k_compact(RPNParams P) {
  int bl = blockIdx.x, b = bl / 5, l = bl % 5;
  int N = c_N[l];
  int chunk = (N + 31) / 32;
  int i0 = blockIdx.y * chunk;
  int i1 = i0 + chunk; if (i1 > N) i1 = N;
  const float4* c4 = (const float4*)(P.ctr[l] + (size_t)b * N);
  unsigned int T = P.thresh[bl];
  unsigned long long* cand = P.cand + (size_t)bl * kCandMax;
  __shared__ unsigned int wcnt[4], wbase[4];
  int tid = threadIdx.x, lane = tid & 63, wid = tid >> 6;
  int q0 = i0 >> 2, q1 = i1 >> 2;
  // pass 1: count
  unsigned int cnt = 0;
  for (int q = q0 + tid; q < q1; q += 256) {
    float4 v = c4[q];
    cnt += (fkey(v.x) >= T) + (fkey(v.y) >= T) + (fkey(v.z) >= T) + (fkey(v.w) >= T);
  }
  for (int d = 32; d > 0; d >>= 1) cnt += (unsigned int)__shfl_xor((int)cnt, d, 64);
  if (lane == 0) wcnt[wid] = cnt;
  __syncthreads();
  if (tid == 0) {
    unsigned int tot = wcnt[0] + wcnt[1] + wcnt[2] + wcnt[3];
    unsigned int base = tot ? atomicAdd(&P.ccount[bl * 256], tot) : 0u;
    unsigned int acc = base;
    for (int w = 0; w < 4; ++w) { unsigned int x = wcnt[w]; wbase[w] = acc; acc += x; }
  }
  __syncthreads();
  unsigned int off = wbase[wid];
  unsigned long long lmlt = (1ull << lane) - 1ull;
  for (int q = q0 + tid; q < q1; q += 256) {
    float4 v = c4[q];
    unsigned int u[4] = {fkey(v.x), fkey(v.y), fkey(v.z), fkey(v.w)};
    #pragma unroll
    for (int k = 0; k < 4; ++k) {
      bool pred = (u[k] >= T);
      unsigned long long m = __ballot(pred);
      if (pred) {
        unsigned int pos = off + (unsigned int)__popcll(m & lmlt);
        if (pos < (unsigned int)kCandMax) {
          unsigned int idx = (unsigned int)(q * 4 + k);
          cand[pos] = ((unsigned long long)u[k] << 32) |
                      (unsigned long long)(0xFFFFFFFFu - idx);
        }
      }
      off += (unsigned int)__popcll(m);
    }
  }
}

// ---- Phase 1e: sort candidates, decode+clip boxes (40 blocks) -----------
__global__ __launch_bounds__(1024) void k_select(RPNParams P) {
  int bl = blockIdx.x, b = bl / 5, l = bl % 5;
  int N = c_N[l], K = c_K[l];
  const float* ctr = P.ctr[l] + (size_t)b * N;
  __shared__ unsigned long long cand[kCandMax];
  int tid = threadIdx.x;
  int cc = (int)P.ccount[bl * 256]; if (cc > kCandMax) cc = kCandMax;
  const unsigned long long* gc = P.cand + (size_t)bl * kCandMax;
  for (int i = tid; i < cc; i += 1024) cand[i] = gc[i];
  int n2 = 1; while (n2 < cc) n2 <<= 1;
  for (int i = cc + tid; i < n2; i += 1024) cand[i] = 0ull;
  __syncthreads();
  // bitonic sort descending by (key desc, idx asc) composite
  for (int size = 2; size <= n2; size <<= 1) {
    for (int stride = size >> 1; stride > 0; stride >>= 1) {
      for (int i = tid; i < n2; i += 1024) {
        int j = i ^ stride;
        if (j > i) {
          unsigned long long a = cand[i], c2 = cand[j];
          bool sw = ((i & size) == 0) ? (a < c2) : (a > c2);
          if (sw) { cand[i] = c2; cand[j] = a; }
        }
      }
      __syncthreads();
    }
  }
  size_t sbase = ((size_t)b * 5 + l) * 1024;
  for (int r = tid; r < K; r += 1024) {
    unsigned long long cv = cand[r];
    unsigned int idx = 0xFFFFFFFFu - (unsigned int)(cv & 0xFFFFFFFFu);
    float s = ctr[idx];
    float4 anc = *(const float4*)(P.anchors[l] + (size_t)idx * 4);
    float4 dd  = *(const float4*)(P.deltas[l] + ((size_t)b * N + idx) * 4);
    // Box2BoxTransformLinear decode (same op order as reference, no fma)
    float w = anc.z - anc.x, hgt = anc.w - anc.y;
    float cx = (anc.x + anc.z) * 0.5f, cy = (anc.y + anc.w) * 0.5f;
    float x1 = cx - dd.x * w;
    float y1 = cy - dd.y * hgt;
    float x2 = cx + dd.z * w;
    float y2 = cy + dd.w * hgt;
    x1 = fminf(fmaxf(x1, 0.0f), 1024.0f);
    y1 = fminf(fmaxf(y1, 0.0f), 1024.0f);
    x2 = fminf(fmaxf(x2, 0.0f), 1024.0f);
    y2 = fminf(fmaxf(y2, 0.0f), 1024.0f);
    bool valid = ((x2 - x1) > 0.0f) && ((y2 - y1) > 0.0f);
    P.scores[sbase + r] = valid ? s : -INFINITY;
    *(float4*)(P.boxes + (sbase + r) * 4) = make_float4(x1, y1, x2, y2);
  }
}

// ---------------- Phase 2a: suppression bitmask (per level) ---------------
// Row-major forward bits (j > i), EXCEPT the row's own 64-box word pair
// (u32 words 2*yg, 2*yg+1): there we store TRANSPOSED bits (j < i) — the
// row's earlier in-word suppressors — consumed by k_sweep's parallel peel.
// Safe: column g of word-g rows is consumed before those rows are OR'd.
__global__ __launch_bounds__(64) void k_mask(RPNParams P) {
  int bl = blockIdx.x, b = bl / 5, l = bl % 5;
  int K = c_K[l];
  int yg = blockIdx.y;   // rows yg*64 .. yg*64+63
  int zc = blockIdx.z;   // column half
  float off = (float)l * 1025.0f;  // lvl * (IMG + 1) — replicate offset rounding!
  size_t sbase = ((size_t)b * 5 + l) * 1024;
  __shared__ float bx1[1024], by1[1024], bx2[1024], by2[1024], barea[1024];
  int tid = threadIdx.x;
  for (int i = tid; i < 1024; i += 64) {
    float4 v = make_float4(0.f, 0.f, 0.f, 0.f);
    if (i < K) {
      v = ((const float4*)P.boxes)[sbase + i];
      v.x += off; v.y += off; v.z += off; v.w += off;
    }
    bx1[i] = v.x; by1[i] = v.y; bx2[i] = v.z; by2[i] = v.w;
    barea[i] = fmaxf(v.z - v.x, 0.0f) * fmaxf(v.w - v.y, 0.0f);
  }
  __syncthreads();
  int i = yg * 64 + tid;
  if (i >= K) return;  // (after the barrier; no further barriers below)
  float x1 = bx1[i], y1 = by1[i], x2 = bx2[i], y2 = by2[i], ai = barea[i];
  unsigned int* mrow = P.mask + (sbase + (size_t)i) * 32;
  int w0 = (yg * 64 + 1) >> 5;      // wave-uniform first word with any j > row
  int nw = 32 - w0;
  int half0 = (nw + 1) >> 1;
  int wbeg = (zc == 0) ? w0 : (w0 + half0);
  int wend = (zc == 0) ? (w0 + half0) : 32;
  if (zc == 0)
    for (int w = 0; w < w0; ++w) mrow[w] = 0u;  // low words: all j <= min row
  for (int w = wbeg; w < wend; ++w) {
    bool own = ((w >> 1) == yg);    // own 64-box word pair -> transposed bits
    unsigned int bits = 0u;
    int j0 = w << 5;
    for (int jj = 0; jj < 32; ++jj) {
      int j = j0 + jj;
      float xx1 = fmaxf(x1, bx1[j]);
      float yy1 = fmaxf(y1, by1[j]);
      float xx2 = fminf(x2, bx2[j]);
      float yy2 = fminf(y2, by2[j]);
      float ww = fmaxf(xx2 - xx1, 0.0f);
      float hh = fmaxf(yy2 - yy1, 0.0f);
      float inter = ww * hh;
      float uni = ai + barea[j] - inter + 1e-8f;  // ((ai+aj)-inter)+eps
      bool dir = own ? (j < i) : (j > i);
      if ((inter / uni > 0.7f) && dir) bits |= (1u << jj);
    }
    mrow[w] = bits;
  }
}

// ---------------- Phase 2b: greedy sweep, parallel peel -------------------
// Within-word greedy via level-synchronous peeling on colmask (earlier
// in-word suppressors, from the repurposed diag word): no per-kept-box
// serial readlane chain. Cross-word suppression: static 16-iter unrolled
// OR with sign-mask select -> all LDS reads issue independently.
__global__ __launch_bounds__(1024) void k_sweep(RPNParams P) {
  int bl = blockIdx.x, b = bl / 5, l = bl % 5;
  int K = c_K[l];
  int NW = (K + 63) >> 6;
  size_t sbase = ((size_t)b * 5 + l) * 1024;
  __shared__ alignas(16) unsigned long long lmask[16 * 1000];  // 125 KiB [row][16]
  __shared__ unsigned long long rdiag[1024];  // colmask per row (earlier in-word)
  __shared__ unsigned long long svalid[16];
  __shared__ unsigned long long skept[16];
  int tid = threadIdx.x;
  const ulonglong2* gm2 = (const ulonglong2*)(P.mask + sbase * 32);
  for (int j = tid; j < K * 8; j += 1024) {
    ulonglong2 v = gm2[j];
    ((ulonglong2*)lmask)[j] = v;
    int w0i = j * 2;       // u64 index within the matrix
    int row = w0i >> 4;
    int dcol = row >> 6;   // the row's own-word u64 slot
    int col0 = w0i & 15;
    if (col0 == dcol) rdiag[row] = v.x;
    else if (col0 + 1 == dcol) rdiag[row] = v.y;
  }
  __syncthreads();
  if (tid >= 64) return;  // single wave from here; no further barriers
  int lane = tid;
  for (int g = 0; g < NW; ++g) {
    int e = g * 64 + lane;
    bool pred = (e < K) && (P.scores[sbase + e] > -INFINITY);
    unsigned long long m = __ballot(pred);
    if (lane == 0) svalid[g] = m;
  }
  int sub = lane >> 4, col = lane & 15;
  unsigned long long accA = 0ull, accB = 0ull;  // per-lane partial OR of kept rows
  for (int g = 0; g < NW; ++g) {
    // combine the 4 subset-partials for column g (lanes g, g+16, g+32, g+48)
    unsigned long long am = accA | accB;
    unsigned long long suppr = readlane64(am, g) | readlane64(am, g + 16) |
                               readlane64(am, g + 32) | readlane64(am, g + 48);
    unsigned long long A = svalid[g] & ~suppr;   // alive set (wave-uniform value)
    unsigned long long colmask = rdiag[g * 64 + lane];  // earlier in-word suppressors
    unsigned long long kept = 0ull;
    while (A) {  // level-synchronous peel == sequential greedy
      bool cand = (A >> lane) & 1ull;
      unsigned long long D = __ballot(cand && ((colmask & A) == 0ull));
      kept |= D;
      unsigned long long sup = __ballot((colmask & D) != 0ull);
      A &= ~(D | sup);
    }
    if (lane == 0) skept[g] = kept;
    // static unrolled OR of kept rows into per-lane acc (columns for later words)
    const unsigned long long* rowbase = &lmask[((size_t)g * 64 + (size_t)sub) * 16 + col];
    #pragma unroll
    for (int t = 0; t < 8; ++t) {
      int p0 = (2 * t) * 4 + sub;
      int p1 = (2 * t + 1) * 4 + sub;
      unsigned long long s0 = 0ull - ((kept >> p0) & 1ull);
      unsigned long long s1 = 0ull - ((kept >> p1) & 1ull);
      accA |= rowbase[(size_t)(2 * t) * 64] & s0;
      accB |= rowbase[(size_t)(2 * t + 1) * 64] & s1;
    }
  }
  for (int g = 0; g < NW; ++g) {
    unsigned long long kv = skept[g];
    int e = g * 64 + lane;
    if (e < K) P.keep[sbase + e] = (unsigned char)((kv >> lane) & 1ull);
  }
}

// ------- Phase 3: per-image 5-way merge-by-rank + keep-partition + out ----
__global__ __launch_bounds__(1024) void k_merge(RPNParams P) {
  int b = blockIdx.x;
  __shared__ unsigned long long keyL[5][1000];  // 40 KB, strictly desc per level
  __shared__ unsigned short srt[4768];          // rank -> concat idx
  __shared__ unsigned int wsum[16];
  __shared__ unsigned int sTot;
  int tid = threadIdx.x;
  int lane = tid & 63, wid = tid >> 6;

  // ---- Step 1: load + stable partition (valid first) per level ----
  for (int l = 0; l < 5; ++l) {
    int Kl = c_K[l];
    int r = tid;
    bool active = r < Kl;
    unsigned long long k = 0ull;
    bool flag = false;
    if (active) {
      float s = P.scores[((size_t)b * 5 + l) * 1024 + r];
      unsigned int fk = fkey(s);
      flag = fk > 0x007FFFFFu;  // score > -inf
      unsigned int cidx = (unsigned int)(l * 1000 + r);
      k = ((unsigned long long)fk << 32) |
          (unsigned long long)(0xFFFFFFFFu - cidx);
    }
    unsigned int fv = flag ? 1u : 0u;
    unsigned int v = fv;
    for (int d = 1; d < 64; d <<= 1) {
      unsigned int n = __shfl_up(v, (unsigned int)d, 64);
      if (lane >= d) v += n;
    }
    if (lane == 63) wsum[wid] = v;
    __syncthreads();
    if (tid == 0) {
      unsigned int acc = 0;
      for (int w = 0; w < 16; ++w) { unsigned int x = wsum[w]; wsum[w] = acc; acc += x; }
      sTot = acc;
    }
    __syncthreads();
    unsigned int excl = wsum[wid] + (v - fv);
    unsigned int nValid = sTot;
    if (active) {
      unsigned int dest = flag ? excl : (nValid + ((unsigned int)r - excl));
      keyL[l][dest] = k;
    }
    __syncthreads();
  }

  // ---- Step 2: global rank via binary search in the other 4 lists ----
  for (int e = tid; e < 4768; e += 1024) {
    int l = (e < 4000) ? (e / 1000) : 4;
    int p = e - l * 1000;
    unsigned long long k = keyL[l][p];
    int rank = p;
    #pragma unroll
    for (int l2 = 0; l2 < 5; ++l2) {
      if (l2 == l) continue;
      int lo = 0, hi = c_K[l2];
      while (lo < hi) {
        int mid = (lo + hi) >> 1;
        if (keyL[l2][mid] > k) lo = mid + 1; else hi = mid;
      }
      rank += lo;
    }
    srt[rank] = (unsigned short)(0xFFFFFFFFu - (unsigned int)(k & 0xFFFFFFFFu));
  }
  __syncthreads();

  // ---- Step 3: keep flags for 5 contiguous sorted slots per thread ----
  int base = tid * 5;
  unsigned char lf[5];
  unsigned short lc[5];
  unsigned int lsum = 0;
  for (int q = 0; q < 5; ++q) {
    int i = base + q;
    unsigned char f = 0; unsigned short cx = 0;
    if (i < 4768) {
      cx = srt[i];
      int l = cx / 1000;
      int r = (int)cx - l * 1000;
      f = P.keep[((size_t)b * 5 + l) * 1024 + r];
    }
    lf[q] = f; lc[q] = cx; lsum += f;
  }
  unsigned int v = lsum;
  for (int d = 1; d < 64; d <<= 1) {
    unsigned int n = __shfl_up(v, (unsigned int)d, 64);
    if (lane >= d) v += n;
  }
  if (lane == 63) wsum[wid] = v;
  __syncthreads();
  if (tid == 0) {
    unsigned int acc = 0;
    for (int w = 0; w < 16; ++w) { unsigned int x = wsum[w]; wsum[w] = acc; acc += x; }
    sTot = acc;
  }
  __syncthreads();
  unsigned int excl = wsum[wid] + (v - lsum);  // kept count before slot `base`
  unsigned int tot = sTot;
  for (int q = 0; q < 5; ++q) {
    int i = base + q;
    if (i >= 4768) break;
    unsigned int cidx = (unsigned int)lc[q];
    int l = (int)(cidx / 1000u);
    int r = (int)cidx - l * 1000;
    size_t sb = ((size_t)b * 5 + l) * 1024 + r;
    unsigned char f = lf[q];
    unsigned int pos = f ? excl : (tot + ((unsigned int)i - excl));
    excl += f;
    if (pos < 1000u) {
      float4 bx = ((const float4*)P.boxes)[sb];
      float sc = f ? P.scores[sb] : -INFINITY;
      float* o = P.out + ((size_t)b * 1000 + pos) * 5;
      o[0] = bx.x; o[1] = bx.y; o[2] = bx.z; o[3] = bx.w; o[4] = sc;
    }
  }
}

}  // namespace

extern "C" void kernel_launch(void* const* d_in, const int* in_sizes, int n_in,
                              void* d_out, int out_size, void* d_ws, size_t ws_size,
                              hipStream_t stream) {
  (void)out_size; (void)ws_size;
  RPNParams P;
  bool interleaved = (n_in >= 3) && (in_sizes[2] == 786432);
  for (int l = 0; l < 5; ++l) {
    if (interleaved) {
      P.deltas[l]  = (const float*)d_in[3 * l + 0];
      P.ctr[l]     = (const float*)d_in[3 * l + 1];
      P.anchors[l] = (const float*)d_in[3 * l + 2];
    } else {
      P.deltas[l]  = (const float*)d_in[l];
      P.ctr[l]     = (const float*)d_in[5 + l];
      P.anchors[l] = (const float*)d_in[10 + l];
    }
  }
  char* ws = (char*)d_ws;
  P.scores = (float*)(ws + 0);               // 163840 B
  P.boxes  = (float*)(ws + 163840);          // 655360 B
  P.keep   = (unsigned char*)(ws + 819200);  // 40960 B
  P.mask   = (unsigned int*)(ws + 860160);   // 5242880 B
  P.cand   = (unsigned long long*)(ws + 860160);  // 1310720 B, aliases mask (used before k_mask)
  P.ghist0 = (unsigned int*)(ws + 6103040);  // 40960 B
  P.ghist1 = (unsigned int*)(ws + 6144000);  // 40960 B
  P.ccount = (unsigned int*)(ws + 6103040);  // aliases ghist0; entry bl at [bl*256] (zeroed in k_thresh)
  P.thresh = (unsigned int*)(ws + 6184960);  // 160 B
  P.out    = (float*)d_out;

  hipMemsetAsync(ws + 6103040, 0, 81920, stream);  // zero both histograms
  hipLaunchKernelGGL(k_hist0, dim3(40, 32), dim3(256), 0, stream, P);
  hipLaunchKernelGGL(k_hist1, dim3(40, 32), dim3(256), 0, stream, P);
  hipLaunchKernelGGL(k_thresh, dim3(40), dim3(256), 0, stream, P);
  hipLaunchKernelGGL(k_compact, dim3(40, 32), dim3(256), 0, stream, P);
  hipLaunchKernelGGL(k_select, dim3(40), dim3(1024), 0, stream, P);
  hipLaunchKernelGGL(k_mask, dim3(40, 16, 2), dim3(64), 0, stream, P);
  hipLaunchKernelGGL(k_sweep, dim3(40), dim3(1024), 0, stream, P);
  hipLaunchKernelGGL(k_merge, dim3(8), dim3(1024), 0, stream, P);
}

// Round 9
// 143.726 us; speedup vs baseline: 2.2203x; 1.1466x over previous
//
#include <hip/hip_runtime.h>
#include <cstdint>
#include <cstddef>
#include <cmath>

#pragma clang fp contract(off)

namespace {

constexpr int kCandMax = 4096;

__device__ __constant__ int c_N[5] = {196608, 49152, 12288, 3072, 768};
__device__ __constant__ int c_K[5] = {1000, 1000, 1000, 1000, 768};

struct RPNParams {
  const float* deltas[5];
  const float* ctr[5];
  const float* anchors[5];
  float* scores;         // [8][5][1024] masked scores, per-level sorted desc
  float* boxes;          // [8][5][1024][4] clipped boxes, per-level sorted
  unsigned char* keep;   // [8][5][1024]
  unsigned int* mask;    // [8][5][1024][32]; diag u64 slot holds TRANSPOSED in-word bits
  unsigned int* ghist0;  // [40][256]
  unsigned int* ghist1;  // [40][256]
  unsigned int* ccount;  // aliases ghist0: counter bl at [bl*256]
  unsigned int* thresh;  // [40]
  unsigned long long* cand;  // [40][4096] (aliases mask region; used before k_mask)
  float* out;            // [8][1000][5]
};

// monotonic float->uint map (larger float => larger uint)
__device__ __forceinline__ unsigned int fkey(float f) {
  unsigned int u = __float_as_uint(f);
  return (u & 0x80000000u) ? ~u : (u | 0x80000000u);
}

__device__ __forceinline__ unsigned long long readlane64(unsigned long long v, int lane) {
  unsigned int lo = __builtin_amdgcn_readlane((unsigned int)v, lane);
  unsigned int hi = __builtin_amdgcn_readlane((unsigned int)(v >> 32), lane);
  return ((unsigned long long)hi << 32) | (unsigned long long)lo;
}

// ---------------- Phase 1a: 8-bit histogram of score keys ----------------
__global__ __launch_bounds__(256) void k_hist0(RPNParams P) {
  int bl = blockIdx.x, b = bl / 5, l = bl % 5;
  int N = c_N[l];
  int chunk = (N + 31) / 32;  // all chunks are multiples of 4
  int i0 = blockIdx.y * chunk;
  int i1 = i0 + chunk; if (i1 > N) i1 = N;
  const float4* c4 = (const float4*)(P.ctr[l] + (size_t)b * N);
  __shared__ unsigned int wh[4][256];
  int tid = threadIdx.x, wid = tid >> 6;
  for (int i = tid; i < 1024; i += 256) ((unsigned int*)wh)[i] = 0u;
  __syncthreads();
  int q0 = i0 >> 2, q1 = i1 >> 2;
  for (int q = q0 + tid; q < q1; q += 256) {
    float4 v = c4[q];
    atomicAdd(&wh[wid][fkey(v.x) >> 24], 1u);
    atomicAdd(&wh[wid][fkey(v.y) >> 24], 1u);
    atomicAdd(&wh[wid][fkey(v.z) >> 24], 1u);
    atomicAdd(&wh[wid][fkey(v.w) >> 24], 1u);
  }
  __syncthreads();
  int bin = tid;
  unsigned int s = wh[0][bin] + wh[1][bin] + wh[2][bin] + wh[3][bin];
  if (s) atomicAdd(&P.ghist0[bl * 256 + bin], s);
}

// ---------------- Phase 1b: refine to 16-bit within chosen top byte ------
__global__ __launch_bounds__(256) void k_hist1(RPNParams P) {
  int bl = blockIdx.x, b = bl / 5, l = bl % 5;
  int N = c_N[l], K = c_K[l];
  int chunk = (N + 31) / 32;
  int i0 = blockIdx.y * chunk;
  int i1 = i0 + chunk; if (i1 > N) i1 = N;
  const float4* c4 = (const float4*)(P.ctr[l] + (size_t)b * N);
  __shared__ unsigned int wh[4][256];
  __shared__ unsigned int sV0;
  int tid = threadIdx.x, wid = tid >> 6;
  if (tid < 256) wh[0][tid] = P.ghist0[bl * 256 + tid];
  __syncthreads();
  if (tid == 0) {
    unsigned int kk = (unsigned int)K, cum = 0;
    int v = 255;
    for (; v > 0; --v) { unsigned int x = wh[0][v]; if (cum + x >= kk) break; cum += x; }
    sV0 = (unsigned int)v;
  }
  __syncthreads();
  unsigned int v0 = sV0;
  for (int i = tid; i < 1024; i += 256) ((unsigned int*)wh)[i] = 0u;
  __syncthreads();
  int q0 = i0 >> 2, q1 = i1 >> 2;
  for (int q = q0 + tid; q < q1; q += 256) {
    float4 v = c4[q];
    unsigned int u0 = fkey(v.x), u1 = fkey(v.y), u2 = fkey(v.z), u3 = fkey(v.w);
    if ((u0 >> 24) == v0) atomicAdd(&wh[wid][(u0 >> 16) & 255u], 1u);
    if ((u1 >> 24) == v0) atomicAdd(&wh[wid][(u1 >> 16) & 255u], 1u);
    if ((u2 >> 24) == v0) atomicAdd(&wh[wid][(u2 >> 16) & 255u], 1u);
    if ((u3 >> 24) == v0) atomicAdd(&wh[wid][(u3 >> 16) & 255u], 1u);
  }
  __syncthreads();
  int bin = tid;
  unsigned int s = wh[0][bin] + wh[1][bin] + wh[2][bin] + wh[3][bin];
  if (s) atomicAdd(&P.ghist1[bl * 256 + bin], s);
}

// ------- Phase 1c: per-(img,lvl) threshold via suffix-scan + bsearch -----
__global__ __launch_bounds__(256) void k_thresh(RPNParams P) {
  int bl = blockIdx.x;
  int K = c_K[bl % 5];
  __shared__ unsigned int S[257];
  __shared__ unsigned int sV0, sKK;
  int tid = threadIdx.x;
  S[tid] = P.ghist0[bl * 256 + tid];
  if (tid == 0) S[256] = 0u;
  __syncthreads();
  if (tid == 0) P.ccount[bl * 256] = 0u;  // after row read; row bl is block-private
  for (int d = 1; d < 256; d <<= 1) {
    unsigned int v = (tid + d < 256) ? S[tid + d] : 0u;
    __syncthreads();
    S[tid] += v;
    __syncthreads();
  }
  if (tid == 0) {
    int lo = 0, hi = 255;
    while (lo < hi) { int mid = (lo + hi + 1) >> 1; if (S[mid] >= (unsigned int)K) lo = mid; else hi = mid - 1; }
    sV0 = (unsigned int)lo;
    sKK = (unsigned int)K - S[lo + 1];
  }
  __syncthreads();
  S[tid] = P.ghist1[bl * 256 + tid];
  __syncthreads();
  for (int d = 1; d < 256; d <<= 1) {
    unsigned int v = (tid + d < 256) ? S[tid + d] : 0u;
    __syncthreads();
    S[tid] += v;
    __syncthreads();
  }
  if (tid == 0) {
    unsigned int kk = sKK;
    int lo = 0, hi = 255;
    while (lo < hi) { int mid = (lo + hi + 1) >> 1; if (S[mid] >= kk) lo = mid; else hi = mid - 1; }
    P.thresh[bl] = ((sV0 << 8) | (unsigned int)lo) << 16;
  }
}

// ------- Phase 1d: compaction, ONE global atomic per block ---------------
__global__ __launch_bounds__(256) void k_compact(RPNParams P) {
  int bl = blockIdx.x, b = bl / 5, l = bl % 5;
  int N = c_N[l];
  int chunk = (N + 31) / 32;
  int i0 = blockIdx.y * chunk;
  int i1 = i0 + chunk; if (i1 > N) i1 = N;
  const float4* c4 = (const float4*)(P.ctr[l] + (size_t)b * N);
  unsigned int T = P.thresh[bl];
  unsigned long long* cand = P.cand + (size_t)bl * kCandMax;
  __shared__ unsigned int wcnt[4], wbase[4];
  int tid = threadIdx.x, lane = tid & 63, wid = tid >> 6;
  int q0 = i0 >> 2, q1 = i1 >> 2;
  // pass 1: count
  unsigned int cnt = 0;
  for (int q = q0 + tid; q < q1; q += 256) {
    float4 v = c4[q];
    cnt += (fkey(v.x) >= T) + (fkey(v.y) >= T) + (fkey(v.z) >= T) + (fkey(v.w) >= T);
  }
  for (int d = 32; d > 0; d >>= 1) cnt += (unsigned int)__shfl_xor((int)cnt, d, 64);
  if (lane == 0) wcnt[wid] = cnt;
  __syncthreads();
  if (tid == 0) {
    unsigned int tot = wcnt[0] + wcnt[1] + wcnt[2] + wcnt[3];
    unsigned int base = tot ? atomicAdd(&P.ccount[bl * 256], tot) : 0u;
    unsigned int acc = base;
    for (int w = 0; w < 4; ++w) { unsigned int x = wcnt[w]; wbase[w] = acc; acc += x; }
  }
  __syncthreads();
  unsigned int off = wbase[wid];
  unsigned long long lmlt = (1ull << lane) - 1ull;
  for (int q = q0 + tid; q < q1; q += 256) {
    float4 v = c4[q];
    unsigned int u[4] = {fkey(v.x), fkey(v.y), fkey(v.z), fkey(v.w)};
    #pragma unroll
    for (int k = 0; k < 4; ++k) {
      bool pred = (u[k] >= T);
      unsigned long long m = __ballot(pred);
      if (pred) {
        unsigned int pos = off + (unsigned int)__popcll(m & lmlt);
        if (pos < (unsigned int)kCandMax) {
          unsigned int idx = (unsigned int)(q * 4 + k);
          cand[pos] = ((unsigned long long)u[k] << 32) |
                      (unsigned long long)(0xFFFFFFFFu - idx);
        }
      }
      off += (unsigned int)__popcll(m);
    }
  }
}

// ---- Phase 1e: sort candidates, decode+clip boxes (40 blocks) -----------
__global__ __launch_bounds__(1024) void k_select(RPNParams P) {
  int bl = blockIdx.x, b = bl / 5, l = bl % 5;
  int N = c_N[l], K = c_K[l];
  const float* ctr = P.ctr[l] + (size_t)b * N;
  __shared__ unsigned long long cand[kCandMax];
  int tid = threadIdx.x;
  int cc = (int)P.ccount[bl * 256]; if (cc > kCandMax) cc = kCandMax;
  const unsigned long long* gc = P.cand + (size_t)bl * kCandMax;
  for (int i = tid; i < cc; i += 1024) cand[i] = gc[i];
  int n2 = 1; while (n2 < cc) n2 <<= 1;
  for (int i = cc + tid; i < n2; i += 1024) cand[i] = 0ull;
  __syncthreads();
  // bitonic sort descending by (key desc, idx asc) composite
  for (int size = 2; size <= n2; size <<= 1) {
    for (int stride = size >> 1; stride > 0; stride >>= 1) {
      for (int i = tid; i < n2; i += 1024) {
        int j = i ^ stride;
        if (j > i) {
          unsigned long long a = cand[i], c2 = cand[j];
          bool sw = ((i & size) == 0) ? (a < c2) : (a > c2);
          if (sw) { cand[i] = c2; cand[j] = a; }
        }
      }
      __syncthreads();
    }
  }
  size_t sbase = ((size_t)b * 5 + l) * 1024;
  for (int r = tid; r < K; r += 1024) {
    unsigned long long cv = cand[r];
    unsigned int idx = 0xFFFFFFFFu - (unsigned int)(cv & 0xFFFFFFFFu);
    float s = ctr[idx];
    float4 anc = *(const float4*)(P.anchors[l] + (size_t)idx * 4);
    float4 dd  = *(const float4*)(P.deltas[l] + ((size_t)b * N + idx) * 4);
    // Box2BoxTransformLinear decode (same op order as reference, no fma)
    float w = anc.z - anc.x, hgt = anc.w - anc.y;
    float cx = (anc.x + anc.z) * 0.5f, cy = (anc.y + anc.w) * 0.5f;
    float x1 = cx - dd.x * w;
    float y1 = cy - dd.y * hgt;
    float x2 = cx + dd.z * w;
    float y2 = cy + dd.w * hgt;
    x1 = fminf(fmaxf(x1, 0.0f), 1024.0f);
    y1 = fminf(fmaxf(y1, 0.0f), 1024.0f);
    x2 = fminf(fmaxf(x2, 0.0f), 1024.0f);
    y2 = fminf(fmaxf(y2, 0.0f), 1024.0f);
    bool valid = ((x2 - x1) > 0.0f) && ((y2 - y1) > 0.0f);
    P.scores[sbase + r] = valid ? s : -INFINITY;
    *(float4*)(P.boxes + (sbase + r) * 4) = make_float4(x1, y1, x2, y2);
  }
}

// ---------------- Phase 2a: suppression bitmask (per level) ---------------
// 4 waves/block share one staging; float4+area LDS (2 broadcast reads/pair);
// division-free exact predicate: RN32(inter/uni) > 0.7f  <=>
// (double)inter >= M*(double)uni with M = 0.7f + 2^-25 (25b x 24b product is
// exact in double; tie at the midpoint rounds to even mantissa 0x333334 > 0.7f).
// Row's own 64-box word pair stores TRANSPOSED bits (j < i) for k_sweep's peel.
__global__ __launch_bounds__(256) void k_mask(RPNParams P) {
  int bl = blockIdx.x, b = bl / 5, l = bl % 5;
  int K = c_K[l];
  int tid = threadIdx.x;
  int lane = tid & 63;
  int yg = blockIdx.y * 4 + (tid >> 6);   // row-group 0..15
  int zc = blockIdx.z;                    // column quarter 0..3
  float off = (float)l * 1025.0f;  // lvl * (IMG + 1) — replicate offset rounding!
  size_t sbase = ((size_t)b * 5 + l) * 1024;
  __shared__ alignas(16) float4 obox[1024];
  __shared__ float area[1024];
  for (int i = tid; i < 1024; i += 256) {
    float4 v = make_float4(0.f, 0.f, 0.f, 0.f);
    if (i < K) {
      v = ((const float4*)P.boxes)[sbase + i];
      v.x += off; v.y += off; v.z += off; v.w += off;
    }
    obox[i] = v;
    area[i] = fmaxf(v.z - v.x, 0.0f) * fmaxf(v.w - v.y, 0.0f);
  }
  __syncthreads();
  int i = yg * 64 + lane;
  if (i >= K) return;  // after the barrier; no further barriers below
  float4 bi = obox[i];
  float ai = area[i];
  unsigned int* mrow = P.mask + (sbase + (size_t)i) * 32;
  int w0 = 2 * yg;                 // first word of range (own pair first)
  int nw = 32 - w0;
  int qlen = (nw + 3) >> 2;        // per-quarter word count (wave-uniform)
  int wbeg = w0 + zc * qlen;
  int wend = wbeg + qlen; if (wend > 32) wend = 32;
  if (zc == 0)
    for (int w = 0; w < w0; ++w) mrow[w] = 0u;  // low words: all j < own word-pair
  const double M = 0x1.666667p-1;  // 0.7f + 2^-25
  for (int w = wbeg; w < wend; ++w) {
    bool own = ((w >> 1) == yg);   // own word pair -> transposed bits
    unsigned int bits = 0u;
    int j0 = w << 5;
    for (int jj = 0; jj < 32; ++jj) {
      int j = j0 + jj;
      float4 bj = obox[j];
      float aj = area[j];
      float xx1 = fmaxf(bi.x, bj.x);
      float yy1 = fmaxf(bi.y, bj.y);
      float xx2 = fminf(bi.z, bj.z);
      float yy2 = fminf(bi.w, bj.w);
      float ww = fmaxf(xx2 - xx1, 0.0f);
      float hh = fmaxf(yy2 - yy1, 0.0f);
      float inter = ww * hh;
      float uni = ai + aj - inter + 1e-8f;  // ((ai+aj)-inter)+eps, f32 order
      bool pr = ((double)inter >= M * (double)uni);
      bool dir = own ? (j < i) : (j > i);
      if (pr && dir) bits |= (1u << jj);
    }
    mrow[w] = bits;
  }
}

// ---------------- Phase 2b: greedy sweep, parallel peel -------------------
__global__ __launch_bounds__(1024) void k_sweep(RPNParams P) {
  int bl = blockIdx.x, b = bl / 5, l = bl % 5;
  int K = c_K[l];
  int NW = (K + 63) >> 6;
  size_t sbase = ((size_t)b * 5 + l) * 1024;
  __shared__ alignas(16) unsigned long long lmask[16 * 1000];  // 125 KiB [row][16]
  __shared__ unsigned long long rdiag[1024];  // colmask per row (earlier in-word)
  __shared__ unsigned long long svalid[16];
  __shared__ unsigned long long skept[16];
  int tid = threadIdx.x;
  const ulonglong2* gm2 = (const ulonglong2*)(P.mask + sbase * 32);
  for (int j = tid; j < K * 8; j += 1024) {
    ulonglong2 v = gm2[j];
    ((ulonglong2*)lmask)[j] = v;
    int w0i = j * 2;       // u64 index within the matrix
    int row = w0i >> 4;
    int dcol = row >> 6;   // the row's own-word u64 slot
    int col0 = w0i & 15;
    if (col0 == dcol) rdiag[row] = v.x;
    else if (col0 + 1 == dcol) rdiag[row] = v.y;
  }
  __syncthreads();
  if (tid >= 64) return;  // single wave from here; no further barriers
  int lane = tid;
  for (int g = 0; g < NW; ++g) {
    int e = g * 64 + lane;
    bool pred = (e < K) && (P.scores[sbase + e] > -INFINITY);
    unsigned long long m = __ballot(pred);
    if (lane == 0) svalid[g] = m;
  }
  int sub = lane >> 4, col = lane & 15;
  unsigned long long accA = 0ull, accB = 0ull;  // per-lane partial OR of kept rows
  for (int g = 0; g < NW; ++g) {
    // combine the 4 subset-partials for column g (lanes g, g+16, g+32, g+48)
    unsigned long long am = accA | accB;
    unsigned long long suppr = readlane64(am, g) | readlane64(am, g + 16) |
                               readlane64(am, g + 32) | readlane64(am, g + 48);
    unsigned long long A = svalid[g] & ~suppr;   // alive set (wave-uniform value)
    unsigned long long colmask = rdiag[g * 64 + lane];  // earlier in-word suppressors
    unsigned long long kept = 0ull;
    while (A) {  // level-synchronous peel == sequential greedy
      bool cand = (A >> lane) & 1ull;
      unsigned long long D = __ballot(cand && ((colmask & A) == 0ull));
      kept |= D;
      unsigned long long sup = __ballot((colmask & D) != 0ull);
      A &= ~(D | sup);
    }
    if (lane == 0) skept[g] = kept;
    // static unrolled OR of kept rows into per-lane acc (columns for later words)
    const unsigned long long* rowbase = &lmask[((size_t)g * 64 + (size_t)sub) * 16 + col];
    #pragma unroll
    for (int t = 0; t < 8; ++t) {
      int p0 = (2 * t) * 4 + sub;
      int p1 = (2 * t + 1) * 4 + sub;
      unsigned long long s0 = 0ull - ((kept >> p0) & 1ull);
      unsigned long long s1 = 0ull - ((kept >> p1) & 1ull);
      accA |= rowbase[(size_t)(2 * t) * 64] & s0;
      accB |= rowbase[(size_t)(2 * t + 1) * 64] & s1;
    }
  }
  for (int g = 0; g < NW; ++g) {
    unsigned long long kv = skept[g];
    int e = g * 64 + lane;
    if (e < K) P.keep[sbase + e] = (unsigned char)((kv >> lane) & 1ull);
  }
}

// ------- Phase 3: per-image 5-way merge-by-rank + keep-partition + out ----
__global__ __launch_bounds__(1024) void k_merge(RPNParams P) {
  int b = blockIdx.x;
  __shared__ unsigned long long keyL[5][1000];  // 40 KB, strictly desc per level
  __shared__ unsigned short srt[4768];          // rank -> concat idx
  __shared__ unsigned int wsum[16];
  __shared__ unsigned int sTot;
  int tid = threadIdx.x;
  int lane = tid & 63, wid = tid >> 6;

  // ---- Step 1: load + stable partition (valid first) per level ----
  for (int l = 0; l < 5; ++l) {
    int Kl = c_K[l];
    int r = tid;
    bool active = r < Kl;
    unsigned long long k = 0ull;
    bool flag = false;
    if (active) {
      float s = P.scores[((size_t)b * 5 + l) * 1024 + r];
      unsigned int fk = fkey(s);
      flag = fk > 0x007FFFFFu;  // score > -inf
      unsigned int cidx = (unsigned int)(l * 1000 + r);
      k = ((unsigned long long)fk << 32) |
          (unsigned long long)(0xFFFFFFFFu - cidx);
    }
    unsigned int fv = flag ? 1u : 0u;
    unsigned int v = fv;
    for (int d = 1; d < 64; d <<= 1) {
      unsigned int n = __shfl_up(v, (unsigned int)d, 64);
      if (lane >= d) v += n;
    }
    if (lane == 63) wsum[wid] = v;
    __syncthreads();
    if (tid == 0) {
      unsigned int acc = 0;
      for (int w = 0; w < 16; ++w) { unsigned int x = wsum[w]; wsum[w] = acc; acc += x; }
      sTot = acc;
    }
    __syncthreads();
    unsigned int excl = wsum[wid] + (v - fv);
    unsigned int nValid = sTot;
    if (active) {
      unsigned int dest = flag ? excl : (nValid + ((unsigned int)r - excl));
      keyL[l][dest] = k;
    }
    __syncthreads();
  }

  // ---- Step 2: global rank via binary search in the other 4 lists ----
  for (int e = tid; e < 4768; e += 1024) {
    int l = (e < 4000) ? (e / 1000) : 4;
    int p = e - l * 1000;
    unsigned long long k = keyL[l][p];
    int rank = p;
    #pragma unroll
    for (int l2 = 0; l2 < 5; ++l2) {
      if (l2 == l) continue;
      int lo = 0, hi = c_K[l2];
      while (lo < hi) {
        int mid = (lo + hi) >> 1;
        if (keyL[l2][mid] > k) lo = mid + 1; else hi = mid;
      }
      rank += lo;
    }
    srt[rank] = (unsigned short)(0xFFFFFFFFu - (unsigned int)(k & 0xFFFFFFFFu));
  }
  __syncthreads();

  // ---- Step 3: keep flags for 5 contiguous sorted slots per thread ----
  int base = tid * 5;
  unsigned char lf[5];
  unsigned short lc[5];
  unsigned int lsum = 0;
  for (int q = 0; q < 5; ++q) {
    int i = base + q;
    unsigned char f = 0; unsigned short cx = 0;
    if (i < 4768) {
      cx = srt[i];
      int l = cx / 1000;
      int r = (int)cx - l * 1000;
      f = P.keep[((size_t)b * 5 + l) * 1024 + r];
    }
    lf[q] = f; lc[q] = cx; lsum += f;
  }
  unsigned int v = lsum;
  for (int d = 1; d < 64; d <<= 1) {
    unsigned int n = __shfl_up(v, (unsigned int)d, 64);
    if (lane >= d) v += n;
  }
  if (lane == 63) wsum[wid] = v;
  __syncthreads();
  if (tid == 0) {
    unsigned int acc = 0;
    for (int w = 0; w < 16; ++w) { unsigned int x = wsum[w]; wsum[w] = acc; acc += x; }
    sTot = acc;
  }
  __syncthreads();
  unsigned int excl = wsum[wid] + (v - lsum);  // kept count before slot `base`
  unsigned int tot = sTot;
  for (int q = 0; q < 5; ++q) {
    int i = base + q;
    if (i >= 4768) break;
    unsigned int cidx = (unsigned int)lc[q];
    int l = (int)(cidx / 1000u);
    int r = (int)cidx - l * 1000;
    size_t sb = ((size_t)b * 5 + l) * 1024 + r;
    unsigned char f = lf[q];
    unsigned int pos = f ? excl : (tot + ((unsigned int)i - excl));
    excl += f;
    if (pos < 1000u) {
      float4 bx = ((const float4*)P.boxes)[sb];
      float sc = f ? P.scores[sb] : -INFINITY;
      float* o = P.out + ((size_t)b * 1000 + pos) * 5;
      o[0] = bx.x; o[1] = bx.y; o[2] = bx.z; o[3] = bx.w; o[4] = sc;
    }
  }
}

}  // namespace

extern "C" void kernel_launch(void* const* d_in, const int* in_sizes, int n_in,
                              void* d_out, int out_size, void* d_ws, size_t ws_size,
                              hipStream_t stream) {
  (void)out_size; (void)ws_size;
  RPNParams P;
  bool interleaved = (n_in >= 3) && (in_sizes[2] == 786432);
  for (int l = 0; l < 5; ++l) {
    if (interleaved) {
      P.deltas[l]  = (const float*)d_in[3 * l + 0];
      P.ctr[l]     = (const float*)d_in[3 * l + 1];
      P.anchors[l] = (const float*)d_in[3 * l + 2];
    } else {
      P.deltas[l]  = (const float*)d_in[l];
      P.ctr[l]     = (const float*)d_in[5 + l];
      P.anchors[l] = (const float*)d_in[10 + l];
    }
  }
  char* ws = (char*)d_ws;
  P.scores = (float*)(ws + 0);               // 163840 B
  P.boxes  = (float*)(ws + 163840);          // 655360 B
  P.keep   = (unsigned char*)(ws + 819200);  // 40960 B
  P.mask   = (unsigned int*)(ws + 860160);   // 5242880 B
  P.cand   = (unsigned long long*)(ws + 860160);  // 1310720 B, aliases mask (used before k_mask)
  P.ghist0 = (unsigned int*)(ws + 6103040);  // 40960 B
  P.ghist1 = (unsigned int*)(ws + 6144000);  // 40960 B
  P.ccount = (unsigned int*)(ws + 6103040);  // aliases ghist0; entry bl at [bl*256] (zeroed in k_thresh)
  P.thresh = (unsigned int*)(ws + 6184960);  // 160 B
  P.out    = (float*)d_out;

  hipMemsetAsync(ws + 6103040, 0, 81920, stream);  // zero both histograms
  hipLaunchKernelGGL(k_hist0, dim3(40, 32), dim3(256), 0, stream, P);
  hipLaunchKernelGGL(k_hist1, dim3(40, 32), dim3(256), 0, stream, P);
  hipLaunchKernelGGL(k_thresh, dim3(40), dim3(256), 0, stream, P);
  hipLaunchKernelGGL(k_compact, dim3(40, 32), dim3(256), 0, stream, P);
  hipLaunchKernelGGL(k_select, dim3(40), dim3(1024), 0, stream, P);
  hipLaunchKernelGGL(k_mask, dim3(40, 4, 4), dim3(256), 0, stream, P);
  hipLaunchKernelGGL(k_sweep, dim3(40), dim3(1024), 0, stream, P);
  hipLaunchKernelGGL(k_merge, dim3(8), dim3(1024), 0, stream, P);
}

// Round 10
// 118.733 us; speedup vs baseline: 2.6877x; 1.2105x over previous
//
#include <hip/hip_runtime.h>
#include <cstdint>
#include <cstddef>
#include <cmath>

#pragma clang fp contract(off)

namespace {

constexpr int kCandMax = 4096;

__device__ __constant__ int c_N[5] = {196608, 49152, 12288, 3072, 768};
__device__ __constant__ int c_K[5] = {1000, 1000, 1000, 1000, 768};

struct RPNParams {
  const float* deltas[5];
  const float* ctr[5];
  const float* anchors[5];
  float* scores;         // [8][5][1024] masked scores, per-level sorted desc
  float* boxes;          // [8][5][1024][4] clipped boxes, per-level sorted
  unsigned char* keep;   // [8][5][1024]
  unsigned int* mask;    // [8][5][1024][32]; own-pair u64 holds TRANSPOSED bits
  unsigned int* g0p;     // [40][32][256] partial hist level 0 (aliases mask region)
  unsigned int* g1p;     // [40][32][256] partial hist level 1 (aliases mask region)
  unsigned int* ccount;  // [40] at stride 256 u32 (own cache line each)
  unsigned int* thresh;  // [40]
  unsigned int* v0kk;    // [40][2]: (v0, kk)
  unsigned long long* cand;  // [40][4096] (aliases mask region; used before k_mask)
  float* out;            // [8][1000][5]
};

// monotonic float->uint map (larger float => larger uint)
__device__ __forceinline__ unsigned int fkey(float f) {
  unsigned int u = __float_as_uint(f);
  return (u & 0x80000000u) ? ~u : (u | 0x80000000u);
}

__device__ __forceinline__ unsigned long long readlane64(unsigned long long v, int lane) {
  unsigned int lo = __builtin_amdgcn_readlane((unsigned int)v, lane);
  unsigned int hi = __builtin_amdgcn_readlane((unsigned int)(v >> 32), lane);
  return ((unsigned long long)hi << 32) | (unsigned long long)lo;
}

// ---------------- Phase 1a: 8-bit partial histograms (plain stores) ------
__global__ __launch_bounds__(256) void k_hist0(RPNParams P) {
  int bl = blockIdx.x, b = bl / 5, l = bl % 5;
  int N = c_N[l];
  int chunk = (N + 31) / 32;  // multiples of 4
  int i0 = blockIdx.y * chunk;
  int i1 = i0 + chunk; if (i1 > N) i1 = N;
  const float4* c4 = (const float4*)(P.ctr[l] + (size_t)b * N);
  __shared__ unsigned int wh[4][256];
  int tid = threadIdx.x, wid = tid >> 6;
  for (int i = tid; i < 1024; i += 256) ((unsigned int*)wh)[i] = 0u;
  __syncthreads();
  int q0 = i0 >> 2, q1 = i1 >> 2;
  for (int q = q0 + tid; q < q1; q += 256) {
    float4 v = c4[q];
    atomicAdd(&wh[wid][fkey(v.x) >> 24], 1u);
    atomicAdd(&wh[wid][fkey(v.y) >> 24], 1u);
    atomicAdd(&wh[wid][fkey(v.z) >> 24], 1u);
    atomicAdd(&wh[wid][fkey(v.w) >> 24], 1u);
  }
  __syncthreads();
  int bin = tid;
  P.g0p[((size_t)bl * 32 + blockIdx.y) * 256 + bin] =
      wh[0][bin] + wh[1][bin] + wh[2][bin] + wh[3][bin];
}

// ------- Phase 1a': sum partials, pick top byte v0 and residual kk -------
__global__ __launch_bounds__(256) void k_sum0(RPNParams P) {
  int bl = blockIdx.x;
  int K = c_K[bl % 5];
  __shared__ unsigned int S[257];
  int tid = threadIdx.x;
  unsigned int s = 0;
  const unsigned int* base = P.g0p + (size_t)bl * 32 * 256 + tid;
  #pragma unroll 8
  for (int p = 0; p < 32; ++p) s += base[p * 256];
  S[tid] = s;
  if (tid == 0) S[256] = 0u;
  __syncthreads();
  for (int d = 1; d < 256; d <<= 1) {
    unsigned int v = (tid + d < 256) ? S[tid + d] : 0u;
    __syncthreads();
    S[tid] += v;
    __syncthreads();
  }
  if (tid == 0) {
    int lo = 0, hi = 255;
    while (lo < hi) { int mid = (lo + hi + 1) >> 1; if (S[mid] >= (unsigned int)K) lo = mid; else hi = mid - 1; }
    P.v0kk[bl * 2] = (unsigned int)lo;
    P.v0kk[bl * 2 + 1] = (unsigned int)K - S[lo + 1];
  }
}

// ---------------- Phase 1b: 16-bit partial refine histograms -------------
__global__ __launch_bounds__(256) void k_hist1(RPNParams P) {
  int bl = blockIdx.x, b = bl / 5, l = bl % 5;
  int N = c_N[l];
  int chunk = (N + 31) / 32;
  int i0 = blockIdx.y * chunk;
  int i1 = i0 + chunk; if (i1 > N) i1 = N;
  const float4* c4 = (const float4*)(P.ctr[l] + (size_t)b * N);
  unsigned int v0 = P.v0kk[bl * 2];
  __shared__ unsigned int wh[4][256];
  int tid = threadIdx.x, wid = tid >> 6;
  for (int i = tid; i < 1024; i += 256) ((unsigned int*)wh)[i] = 0u;
  __syncthreads();
  int q0 = i0 >> 2, q1 = i1 >> 2;
  for (int q = q0 + tid; q < q1; q += 256) {
    float4 v = c4[q];
    unsigned int u0 = fkey(v.x), u1 = fkey(v.y), u2 = fkey(v.z), u3 = fkey(v.w);
    if ((u0 >> 24) == v0) atomicAdd(&wh[wid][(u0 >> 16) & 255u], 1u);
    if ((u1 >> 24) == v0) atomicAdd(&wh[wid][(u1 >> 16) & 255u], 1u);
    if ((u2 >> 24) == v0) atomicAdd(&wh[wid][(u2 >> 16) & 255u], 1u);
    if ((u3 >> 24) == v0) atomicAdd(&wh[wid][(u3 >> 16) & 255u], 1u);
  }
  __syncthreads();
  int bin = tid;
  P.g1p[((size_t)bl * 32 + blockIdx.y) * 256 + bin] =
      wh[0][bin] + wh[1][bin] + wh[2][bin] + wh[3][bin];
}

// ------- Phase 1c: final 16-bit threshold; zero candidate counter --------
__global__ __launch_bounds__(256) void k_thresh(RPNParams P) {
  int bl = blockIdx.x;
  __shared__ unsigned int S[257];
  int tid = threadIdx.x;
  if (tid == 0) P.ccount[bl * 256] = 0u;
  unsigned int s = 0;
  const unsigned int* base = P.g1p + (size_t)bl * 32 * 256 + tid;
  #pragma unroll 8
  for (int p = 0; p < 32; ++p) s += base[p * 256];
  S[tid] = s;
  if (tid == 0) S[256] = 0u;
  __syncthreads();
  for (int d = 1; d < 256; d <<= 1) {
    unsigned int v = (tid + d < 256) ? S[tid + d] : 0u;
    __syncthreads();
    S[tid] += v;
    __syncthreads();
  }
  if (tid == 0) {
    unsigned int kk = P.v0kk[bl * 2 + 1];
    unsigned int v0 = P.v0kk[bl * 2];
    int lo = 0, hi = 255;
    while (lo < hi) { int mid = (lo + hi + 1) >> 1; if (S[mid] >= kk) lo = mid; else hi = mid - 1; }
    P.thresh[bl] = ((v0 << 8) | (unsigned int)lo) << 16;
  }
}

// ------- Phase 1d: compaction, ONE global atomic per block ---------------
__global__ __launch_bounds__(256) void k_compact(RPNParams P) {
  int bl = blockIdx.x, b = bl / 5, l = bl % 5;
  int N = c_N[l];
  int chunk = (N + 31) / 32;
  int i0 = blockIdx.y * chunk;
  int i1 = i0 + chunk; if (i1 > N) i1 = N;
  const float4* c4 = (const float4*)(P.ctr[l] + (size_t)b * N);
  unsigned int T = P.thresh[bl];
  unsigned long long* cand = P.cand + (size_t)bl * kCandMax;
  __shared__ unsigned int wcnt[4], wbase[4];
  int tid = threadIdx.x, lane = tid & 63, wid = tid >> 6;
  int q0 = i0 >> 2, q1 = i1 >> 2;
  // pass 1: count
  unsigned int cnt = 0;
  for (int q = q0 + tid; q < q1; q += 256) {
    float4 v = c4[q];
    cnt += (fkey(v.x) >= T) + (fkey(v.y) >= T) + (fkey(v.z) >= T) + (fkey(v.w) >= T);
  }
  for (int d = 32; d > 0; d >>= 1) cnt += (unsigned int)__shfl_xor((int)cnt, d, 64);
  if (lane == 0) wcnt[wid] = cnt;
  __syncthreads();
  if (tid == 0) {
    unsigned int tot = wcnt[0] + wcnt[1] + wcnt[2] + wcnt[3];
    unsigned int base = tot ? atomicAdd(&P.ccount[bl * 256], tot) : 0u;
    unsigned int acc = base;
    for (int w = 0; w < 4; ++w) { unsigned int x = wcnt[w]; wbase[w] = acc; acc += x; }
  }
  __syncthreads();
  unsigned int off = wbase[wid];
  unsigned long long lmlt = (1ull << lane) - 1ull;
  for (int q = q0 + tid; q < q1; q += 256) {
    float4 v = c4[q];
    unsigned int u[4] = {fkey(v.x), fkey(v.y), fkey(v.z), fkey(v.w)};
    #pragma unroll
    for (int k = 0; k < 4; ++k) {
      bool pred = (u[k] >= T);
      unsigned long long m = __ballot(pred);
      if (pred) {
        unsigned int pos = off + (unsigned int)__popcll(m & lmlt);
        if (pos < (unsigned int)kCandMax) {
          unsigned int idx = (unsigned int)(q * 4 + k);
          cand[pos] = ((unsigned long long)u[k] << 32) |
                      (unsigned long long)(0xFFFFFFFFu - idx);
        }
      }
      off += (unsigned int)__popcll(m);
    }
  }
}

// ---- Phase 1e: sort candidates, decode+clip boxes (40 blocks) -----------
__global__ __launch_bounds__(1024) void k_select(RPNParams P) {
  int bl = blockIdx.x, b = bl / 5, l = bl % 5;
  int N = c_N[l], K = c_K[l];
  const float* ctr = P.ctr[l] + (size_t)b * N;
  __shared__ unsigned long long cand[kCandMax];
  int tid = threadIdx.x;
  int cc = (int)P.ccount[bl * 256]; if (cc > kCandMax) cc = kCandMax;
  const unsigned long long* gc = P.cand + (size_t)bl * kCandMax;
  for (int i = tid; i < cc; i += 1024) cand[i] = gc[i];
  int n2 = 1; while (n2 < cc) n2 <<= 1;
  for (int i = cc + tid; i < n2; i += 1024) cand[i] = 0ull;
  __syncthreads();
  // bitonic sort descending by (key desc, idx asc) composite
  for (int size = 2; size <= n2; size <<= 1) {
    for (int stride = size >> 1; stride > 0; stride >>= 1) {
      for (int i = tid; i < n2; i += 1024) {
        int j = i ^ stride;
        if (j > i) {
          unsigned long long a = cand[i], c2 = cand[j];
          bool sw = ((i & size) == 0) ? (a < c2) : (a > c2);
          if (sw) { cand[i] = c2; cand[j] = a; }
        }
      }
      __syncthreads();
    }
  }
  size_t sbase = ((size_t)b * 5 + l) * 1024;
  for (int r = tid; r < K; r += 1024) {
    unsigned long long cv = cand[r];
    unsigned int idx = 0xFFFFFFFFu - (unsigned int)(cv & 0xFFFFFFFFu);
    float s = ctr[idx];
    float4 anc = *(const float4*)(P.anchors[l] + (size_t)idx * 4);
    float4 dd  = *(const float4*)(P.deltas[l] + ((size_t)b * N + idx) * 4);
    // Box2BoxTransformLinear decode (same op order as reference, no fma)
    float w = anc.z - anc.x, hgt = anc.w - anc.y;
    float cx = (anc.x + anc.z) * 0.5f, cy = (anc.y + anc.w) * 0.5f;
    float x1 = cx - dd.x * w;
    float y1 = cy - dd.y * hgt;
    float x2 = cx + dd.z * w;
    float y2 = cy + dd.w * hgt;
    x1 = fminf(fmaxf(x1, 0.0f), 1024.0f);
    y1 = fminf(fmaxf(y1, 0.0f), 1024.0f);
    x2 = fminf(fmaxf(x2, 0.0f), 1024.0f);
    y2 = fminf(fmaxf(y2, 0.0f), 1024.0f);
    bool valid = ((x2 - x1) > 0.0f) && ((y2 - y1) > 0.0f);
    P.scores[sbase + r] = valid ? s : -INFINITY;
    *(float4*)(P.boxes + (sbase + r) * 4) = make_float4(x1, y1, x2, y2);
  }
}

// ---------------- Phase 2a: suppression bitmask (per level) ---------------
// 4 waves/block share staging; 8-way column split (5120 waves). Words above
// the row's own 64-pair need NO direction test (j > i always); the own pair
// stores TRANSPOSED (j < i) bits via per-lane constant masks. Predicate is
// division-free exact: RN32(inter/uni) > 0.7f <=> (double)inter >= M*uni,
// M = 0.7f + 2^-25 (25x24-bit product exact in double; tie -> even > 0.7f).
__global__ __launch_bounds__(256) void k_mask(RPNParams P) {
  int bl = blockIdx.x, b = bl / 5, l = bl % 5;
  int K = c_K[l];
  int tid = threadIdx.x;
  int lane = tid & 63;
  int yg = blockIdx.y * 4 + (tid >> 6);   // row-group 0..15
  int zc = blockIdx.z;                    // column eighth 0..7
  float off = (float)l * 1025.0f;  // lvl * (IMG + 1) — replicate offset rounding!
  size_t sbase = ((size_t)b * 5 + l) * 1024;
  __shared__ alignas(16) float4 obox[1024];
  __shared__ float area[1024];
  for (int i = tid; i < 1024; i += 256) {
    float4 v = make_float4(0.f, 0.f, 0.f, 0.f);
    if (i < K) {
      v = ((const float4*)P.boxes)[sbase + i];
      v.x += off; v.y += off; v.z += off; v.w += off;
    }
    obox[i] = v;
    area[i] = fmaxf(v.z - v.x, 0.0f) * fmaxf(v.w - v.y, 0.0f);
  }
  __syncthreads();
  int i = yg * 64 + lane;
  if (i >= K) return;  // after the barrier; no further barriers below
  float4 bi = obox[i];
  float ai = area[i];
  unsigned int* mrow = P.mask + (sbase + (size_t)i) * 32;
  const double M = 0x1.666667p-1;  // 0.7f + 2^-25
  auto pr = [&](int j) -> bool {
    float4 bj = obox[j];
    float aj = area[j];
    float xx1 = fmaxf(bi.x, bj.x);
    float yy1 = fmaxf(bi.y, bj.y);
    float xx2 = fminf(bi.z, bj.z);
    float yy2 = fminf(bi.w, bj.w);
    float ww = fmaxf(xx2 - xx1, 0.0f);
    float hh = fmaxf(yy2 - yy1, 0.0f);
    float inter = ww * hh;
    float uni = ai + aj - inter + 1e-8f;  // ((ai+aj)-inter)+eps, f32 order
    return (double)inter >= M * (double)uni;
  };
  int wown = 2 * yg;
  if (zc == 0) {
    for (int w = 0; w < wown; ++w) mrow[w] = 0u;  // low words: all j < own pair
    // own word pair: transposed (j < i) bits
    unsigned int m0, m1;
    if (lane < 32) { m0 = (1u << lane) - 1u; m1 = 0u; }
    else           { m0 = 0xFFFFFFFFu; m1 = (1u << (lane - 32)) - 1u; }
    #pragma unroll
    for (int h = 0; h < 2; ++h) {
      unsigned int bits = 0u;
      int j0 = (wown + h) << 5;
      for (int jj = 0; jj < 32; ++jj)
        if (pr(j0 + jj)) bits |= (1u << jj);
      mrow[wown + h] = bits & (h ? m1 : m0);
    }
  }
  int wstart = wown + 2;
  int nw = 32 - wstart;
  int qlen = (nw + 7) >> 3;
  int wbeg = wstart + zc * qlen;
  int wend = wbeg + qlen; if (wend > 32) wend = 32;
  for (int w = wbeg; w < wend; ++w) {
    unsigned int bits = 0u;
    int j0 = w << 5;
    for (int jj = 0; jj < 32; ++jj)
      if (pr(j0 + jj)) bits |= (1u << jj);  // j > i guaranteed (w > own pair)
    mrow[w] = bits;
  }
}

// ---------------- Phase 2b: greedy sweep, parallel peel -------------------
__global__ __launch_bounds__(1024) void k_sweep(RPNParams P) {
  int bl = blockIdx.x, b = bl / 5, l = bl % 5;
  int K = c_K[l];
  int NW = (K + 63) >> 6;
  size_t sbase = ((size_t)b * 5 + l) * 1024;
  __shared__ alignas(16) unsigned long long lmask[16 * 1000];  // 125 KiB [row][16]
  __shared__ unsigned long long rdiag[1024];  // colmask per row (earlier in-word)
  __shared__ unsigned long long svalid[16];
  __shared__ unsigned long long skept[16];
  int tid = threadIdx.x;
  const ulonglong2* gm2 = (const ulonglong2*)(P.mask + sbase * 32);
  for (int j = tid; j < K * 8; j += 1024) {
    ulonglong2 v = gm2[j];
    ((ulonglong2*)lmask)[j] = v;
    int w0i = j * 2;       // u64 index within the matrix
    int row = w0i >> 4;
    int dcol = row >> 6;   // the row's own-word u64 slot
    int col0 = w0i & 15;
    if (col0 == dcol) rdiag[row] = v.x;
    else if (col0 + 1 == dcol) rdiag[row] = v.y;
  }
  __syncthreads();
  if (tid >= 64) return;  // single wave from here; no further barriers
  int lane = tid;
  for (int g = 0; g < NW; ++g) {
    int e = g * 64 + lane;
    bool pred = (e < K) && (P.scores[sbase + e] > -INFINITY);
    unsigned long long m = __ballot(pred);
    if (lane == 0) svalid[g] = m;
  }
  int sub = lane >> 4, col = lane & 15;
  unsigned long long accA = 0ull, accB = 0ull;  // per-lane partial OR of kept rows
  for (int g = 0; g < NW; ++g) {
    // combine the 4 subset-partials for column g (lanes g, g+16, g+32, g+48)
    unsigned long long am = accA | accB;
    unsigned long long suppr = readlane64(am, g) | readlane64(am, g + 16) |
                               readlane64(am, g + 32) | readlane64(am, g + 48);
    unsigned long long A = svalid[g] & ~suppr;   // alive set (wave-uniform value)
    unsigned long long colmask = rdiag[g * 64 + lane];  // earlier in-word suppressors
    unsigned long long kept = 0ull;
    while (A) {  // level-synchronous peel == sequential greedy
      bool cand = (A >> lane) & 1ull;
      unsigned long long D = __ballot(cand && ((colmask & A) == 0ull));
      kept |= D;
      unsigned long long sup = __ballot((colmask & D) != 0ull);
      A &= ~(D | sup);
    }
    if (lane == 0) skept[g] = kept;
    // static unrolled OR of kept rows into per-lane acc (columns for later words)
    const unsigned long long* rowbase = &lmask[((size_t)g * 64 + (size_t)sub) * 16 + col];
    #pragma unroll
    for (int t = 0; t < 8; ++t) {
      int p0 = (2 * t) * 4 + sub;
      int p1 = (2 * t + 1) * 4 + sub;
      unsigned long long s0 = 0ull - ((kept >> p0) & 1ull);
      unsigned long long s1 = 0ull - ((kept >> p1) & 1ull);
      accA |= rowbase[(size_t)(2 * t) * 64] & s0;
      accB |= rowbase[(size_t)(2 * t + 1) * 64] & s1;
    }
  }
  for (int g = 0; g < NW; ++g) {
    unsigned long long kv = skept[g];
    int e = g * 64 + lane;
    if (e < K) P.keep[sbase + e] = (unsigned char)((kv >> lane) & 1ull);
  }
}

// ------- Phase 3: per-image 5-way merge-by-rank + keep-partition + out ----
__global__ __launch_bounds__(1024) void k_merge(RPNParams P) {
  int b = blockIdx.x;
  __shared__ unsigned long long keyL[5][1000];  // 40 KB, strictly desc per level
  __shared__ unsigned short srt[4768];          // rank -> concat idx
  __shared__ unsigned int wsum[16];
  __shared__ unsigned int sTot;
  int tid = threadIdx.x;
  int lane = tid & 63, wid = tid >> 6;

  // ---- Step 1: load + stable partition (valid first) per level ----
  for (int l = 0; l < 5; ++l) {
    int Kl = c_K[l];
    int r = tid;
    bool active = r < Kl;
    unsigned long long k = 0ull;
    bool flag = false;
    if (active) {
      float s = P.scores[((size_t)b * 5 + l) * 1024 + r];
      unsigned int fk = fkey(s);
      flag = fk > 0x007FFFFFu;  // score > -inf
      unsigned int cidx = (unsigned int)(l * 1000 + r);
      k = ((unsigned long long)fk << 32) |
          (unsigned long long)(0xFFFFFFFFu - cidx);
    }
    unsigned int fv = flag ? 1u : 0u;
    unsigned int v = fv;
    for (int d = 1; d < 64; d <<= 1) {
      unsigned int n = __shfl_up(v, (unsigned int)d, 64);
      if (lane >= d) v += n;
    }
    if (lane == 63) wsum[wid] = v;
    __syncthreads();
    if (tid == 0) {
      unsigned int acc = 0;
      for (int w = 0; w < 16; ++w) { unsigned int x = wsum[w]; wsum[w] = acc; acc += x; }
      sTot = acc;
    }
    __syncthreads();
    unsigned int excl = wsum[wid] + (v - fv);
    unsigned int nValid = sTot;
    if (active) {
      unsigned int dest = flag ? excl : (nValid + ((unsigned int)r - excl));
      keyL[l][dest] = k;
    }
    __syncthreads();
  }

  // ---- Step 2: global rank via binary search in the other 4 lists ----
  for (int e = tid; e < 4768; e += 1024) {
    int l = (e < 4000) ? (e / 1000) : 4;
    int p = e - l * 1000;
    unsigned long long k = keyL[l][p];
    int rank = p;
    #pragma unroll
    for (int l2 = 0; l2 < 5; ++l2) {
      if (l2 == l) continue;
      int lo = 0, hi = c_K[l2];
      while (lo < hi) {
        int mid = (lo + hi) >> 1;
        if (keyL[l2][mid] > k) lo = mid + 1; else hi = mid;
      }
      rank += lo;
    }
    srt[rank] = (unsigned short)(0xFFFFFFFFu - (unsigned int)(k & 0xFFFFFFFFu));
  }
  __syncthreads();

  // ---- Step 3: keep flags for 5 contiguous sorted slots per thread ----
  int base = tid * 5;
  unsigned char lf[5];
  unsigned short lc[5];
  unsigned int lsum = 0;
  for (int q = 0; q < 5; ++q) {
    int i = base + q;
    unsigned char f = 0; unsigned short cx = 0;
    if (i < 4768) {
      cx = srt[i];
      int l = cx / 1000;
      int r = (int)cx - l * 1000;
      f = P.keep[((size_t)b * 5 + l) * 1024 + r];
    }
    lf[q] = f; lc[q] = cx; lsum += f;
  }
  unsigned int v = lsum;
  for (int d = 1; d < 64; d <<= 1) {
    unsigned int n = __shfl_up(v, (unsigned int)d, 64);
    if (lane >= d) v += n;
  }
  if (lane == 63) wsum[wid] = v;
  __syncthreads();
  if (tid == 0) {
    unsigned int acc = 0;
    for (int w = 0; w < 16; ++w) { unsigned int x = wsum[w]; wsum[w] = acc; acc += x; }
    sTot = acc;
  }
  __syncthreads();
  unsigned int excl = wsum[wid] + (v - lsum);  // kept count before slot `base`
  unsigned int tot = sTot;
  for (int q = 0; q < 5; ++q) {
    int i = base + q;
    if (i >= 4768) break;
    unsigned int cidx = (unsigned int)lc[q];
    int l = (int)(cidx / 1000u);
    int r = (int)cidx - l * 1000;
    size_t sb = ((size_t)b * 5 + l) * 1024 + r;
    unsigned char f = lf[q];
    unsigned int pos = f ? excl : (tot + ((unsigned int)i - excl));
    excl += f;
    if (pos < 1000u) {
      float4 bx = ((const float4*)P.boxes)[sb];
      float sc = f ? P.scores[sb] : -INFINITY;
      float* o = P.out + ((size_t)b * 1000 + pos) * 5;
      o[0] = bx.x; o[1] = bx.y; o[2] = bx.z; o[3] = bx.w; o[4] = sc;
    }
  }
}

}  // namespace

extern "C" void kernel_launch(void* const* d_in, const int* in_sizes, int n_in,
                              void* d_out, int out_size, void* d_ws, size_t ws_size,
                              hipStream_t stream) {
  (void)out_size; (void)ws_size;
  RPNParams P;
  bool interleaved = (n_in >= 3) && (in_sizes[2] == 786432);
  for (int l = 0; l < 5; ++l) {
    if (interleaved) {
      P.deltas[l]  = (const float*)d_in[3 * l + 0];
      P.ctr[l]     = (const float*)d_in[3 * l + 1];
      P.anchors[l] = (const float*)d_in[3 * l + 2];
    } else {
      P.deltas[l]  = (const float*)d_in[l];
      P.ctr[l]     = (const float*)d_in[5 + l];
      P.anchors[l] = (const float*)d_in[10 + l];
    }
  }
  char* ws = (char*)d_ws;
  P.scores = (float*)(ws + 0);                    // 163840 B
  P.boxes  = (float*)(ws + 163840);               // 655360 B
  P.keep   = (unsigned char*)(ws + 819200);       // 40960 B
  P.mask   = (unsigned int*)(ws + 860160);        // 5242880 B
  // aliases inside the mask region (all used strictly before k_mask writes):
  P.cand   = (unsigned long long*)(ws + 860160);  // 1310720 B
  P.g0p    = (unsigned int*)(ws + 2170880);       // 1310720 B
  P.g1p    = (unsigned int*)(ws + 3481600);       // 1310720 B
  // small control arrays (all rewritten every launch; no init needed):
  P.ccount = (unsigned int*)(ws + 6103040);       // 40 entries at stride 256 u32
  P.thresh = (unsigned int*)(ws + 6144000);       // 160 B
  P.v0kk   = (unsigned int*)(ws + 6144160);       // 320 B
  P.out    = (float*)d_out;

  hipLaunchKernelGGL(k_hist0, dim3(40, 32), dim3(256), 0, stream, P);
  hipLaunchKernelGGL(k_sum0, dim3(40), dim3(256), 0, stream, P);
  hipLaunchKernelGGL(k_hist1, dim3(40, 32), dim3(256), 0, stream, P);
  hipLaunchKernelGGL(k_thresh, dim3(40), dim3(256), 0, stream, P);
  hipLaunchKernelGGL(k_compact, dim3(40, 32), dim3(256), 0, stream, P);
  hipLaunchKernelGGL(k_select, dim3(40), dim3(1024), 0, stream, P);
  hipLaunchKernelGGL(k_mask, dim3(40, 4, 8), dim3(256), 0, stream, P);
  hipLaunchKernelGGL(k_sweep, dim3(40), dim3(1024), 0, stream, P);
  hipLaunchKernelGGL(k_merge, dim3(8), dim3(1024), 0, stream, P);
}

// Round 11
// 113.118 us; speedup vs baseline: 2.8211x; 1.0496x over previous
//
#include <hip/hip_runtime.h>
#include <cstdint>
#include <cstddef>
#include <cmath>

#pragma clang fp contract(off)

namespace {

constexpr int kCandMax = 4096;

__device__ __constant__ int c_N[5] = {196608, 49152, 12288, 3072, 768};
__device__ __constant__ int c_K[5] = {1000, 1000, 1000, 1000, 768};

struct RPNParams {
  const float* deltas[5];
  const float* ctr[5];
  const float* anchors[5];
  float* scores;         // [8][5][1024] masked scores, per-level sorted desc
  float* boxes;          // [8][5][1024][4] clipped boxes, per-level sorted
  unsigned char* keep;   // [8][5][1024]
  unsigned int* mask;    // [8][5][1024][32]; own-pair u64 holds TRANSPOSED bits
  unsigned int* g0p;     // [40][32][256] partial hist level 0 (aliases mask region)
  unsigned int* g1p;     // [40][32][256] partial hist level 1 (aliases mask region)
  unsigned int* ccount;  // [40] at stride 256 u32 (own cache line each)
  unsigned int* v0kk;    // [40][2]: (v0, kk)
  unsigned long long* cand;  // [40][4096] (aliases mask region; used before k_mask)
  unsigned long long* keyC;  // [40][1024] valid-partitioned composite keys
  float* out;            // [8][1000][5]
};

// monotonic float->uint map (larger float => larger uint)
__device__ __forceinline__ unsigned int fkey(float f) {
  unsigned int u = __float_as_uint(f);
  return (u & 0x80000000u) ? ~u : (u | 0x80000000u);
}

__device__ __forceinline__ unsigned long long readlane64(unsigned long long v, int lane) {
  unsigned int lo = __builtin_amdgcn_readlane((unsigned int)v, lane);
  unsigned int hi = __builtin_amdgcn_readlane((unsigned int)(v >> 32), lane);
  return ((unsigned long long)hi << 32) | (unsigned long long)lo;
}

// ---------------- Phase 1a: 8-bit partial histograms (plain stores) ------
__global__ __launch_bounds__(256) void k_hist0(RPNParams P) {
  int bl = blockIdx.x, b = bl / 5, l = bl % 5;
  int N = c_N[l];
  int chunk = (N + 31) / 32;  // multiples of 4
  int i0 = blockIdx.y * chunk;
  int i1 = i0 + chunk; if (i1 > N) i1 = N;
  const float4* c4 = (const float4*)(P.ctr[l] + (size_t)b * N);
  __shared__ unsigned int wh[4][256];
  int tid = threadIdx.x, wid = tid >> 6;
  if (blockIdx.y == 0 && tid == 0) P.ccount[bl * 256] = 0u;  // pre-zero for k_compact
  for (int i = tid; i < 1024; i += 256) ((unsigned int*)wh)[i] = 0u;
  __syncthreads();
  int q0 = i0 >> 2, q1 = i1 >> 2;
  for (int q = q0 + tid; q < q1; q += 256) {
    float4 v = c4[q];
    atomicAdd(&wh[wid][fkey(v.x) >> 24], 1u);
    atomicAdd(&wh[wid][fkey(v.y) >> 24], 1u);
    atomicAdd(&wh[wid][fkey(v.z) >> 24], 1u);
    atomicAdd(&wh[wid][fkey(v.w) >> 24], 1u);
  }
  __syncthreads();
  int bin = tid;
  P.g0p[((size_t)bl * 32 + blockIdx.y) * 256 + bin] =
      wh[0][bin] + wh[1][bin] + wh[2][bin] + wh[3][bin];
}

// -------- Phase 1b: 16-bit partial refine (v0 computed per block) --------
__global__ __launch_bounds__(256) void k_hist1(RPNParams P) {
  int bl = blockIdx.x, b = bl / 5, l = bl % 5;
  int N = c_N[l], K = c_K[l];
  int chunk = (N + 31) / 32;
  int i0 = blockIdx.y * chunk;
  int i1 = i0 + chunk; if (i1 > N) i1 = N;
  const float4* c4 = (const float4*)(P.ctr[l] + (size_t)b * N);
  __shared__ unsigned int S[257];
  __shared__ unsigned int wh[4][256];
  int tid = threadIdx.x, wid = tid >> 6;
  // redundant per-block v0 from g0p partials (L2-hot; hidden by occupancy)
  {
    unsigned int s = 0;
    const unsigned int* base0 = P.g0p + (size_t)bl * 32 * 256 + tid;
    #pragma unroll 8
    for (int p = 0; p < 32; ++p) s += base0[p * 256];
    S[tid] = s;
    if (tid == 0) S[256] = 0u;
  }
  __syncthreads();
  for (int d = 1; d < 256; d <<= 1) {
    unsigned int v = (tid + d < 256) ? S[tid + d] : 0u;
    __syncthreads();
    S[tid] += v;
    __syncthreads();
  }
  int lo = 0, hi = 255;
  while (lo < hi) { int mid = (lo + hi + 1) >> 1; if (S[mid] >= (unsigned int)K) lo = mid; else hi = mid - 1; }
  unsigned int v0 = (unsigned int)lo;
  if (blockIdx.y == 0 && tid == 0) {
    P.v0kk[bl * 2] = v0;
    P.v0kk[bl * 2 + 1] = (unsigned int)K - S[lo + 1];
  }
  for (int i = tid; i < 1024; i += 256) ((unsigned int*)wh)[i] = 0u;
  __syncthreads();
  int q0 = i0 >> 2, q1 = i1 >> 2;
  for (int q = q0 + tid; q < q1; q += 256) {
    float4 v = c4[q];
    unsigned int u0 = fkey(v.x), u1 = fkey(v.y), u2 = fkey(v.z), u3 = fkey(v.w);
    if ((u0 >> 24) == v0) atomicAdd(&wh[wid][(u0 >> 16) & 255u], 1u);
    if ((u1 >> 24) == v0) atomicAdd(&wh[wid][(u1 >> 16) & 255u], 1u);
    if ((u2 >> 24) == v0) atomicAdd(&wh[wid][(u2 >> 16) & 255u], 1u);
    if ((u3 >> 24) == v0) atomicAdd(&wh[wid][(u3 >> 16) & 255u], 1u);
  }
  __syncthreads();
  int bin = tid;
  P.g1p[((size_t)bl * 32 + blockIdx.y) * 256 + bin] =
      wh[0][bin] + wh[1][bin] + wh[2][bin] + wh[3][bin];
}

// ---- Phase 1c: compaction; T computed per block; one atomic per block ----
__global__ __launch_bounds__(256) void k_compact(RPNParams P) {
  int bl = blockIdx.x, b = bl / 5, l = bl % 5;
  int N = c_N[l];
  int chunk = (N + 31) / 32;
  int i0 = blockIdx.y * chunk;
  int i1 = i0 + chunk; if (i1 > N) i1 = N;
  const float4* c4 = (const float4*)(P.ctr[l] + (size_t)b * N);
  unsigned long long* cand = P.cand + (size_t)bl * kCandMax;
  __shared__ unsigned int S[257];
  __shared__ unsigned int wcnt[4], wbase[4];
  int tid = threadIdx.x, lane = tid & 63, wid = tid >> 6;
  // redundant per-block threshold from g1p partials + v0kk
  {
    unsigned int s = 0;
    const unsigned int* base1 = P.g1p + (size_t)bl * 32 * 256 + tid;
    #pragma unroll 8
    for (int p = 0; p < 32; ++p) s += base1[p * 256];
    S[tid] = s;
    if (tid == 0) S[256] = 0u;
  }
  __syncthreads();
  for (int d = 1; d < 256; d <<= 1) {
    unsigned int v = (tid + d < 256) ? S[tid + d] : 0u;
    __syncthreads();
    S[tid] += v;
    __syncthreads();
  }
  unsigned int v0 = P.v0kk[bl * 2], kk = P.v0kk[bl * 2 + 1];
  int lo = 0, hi = 255;
  while (lo < hi) { int mid = (lo + hi + 1) >> 1; if (S[mid] >= kk) lo = mid; else hi = mid - 1; }
  unsigned int T = ((v0 << 8) | (unsigned int)lo) << 16;
  int q0 = i0 >> 2, q1 = i1 >> 2;
  // pass 1: count
  unsigned int cnt = 0;
  for (int q = q0 + tid; q < q1; q += 256) {
    float4 v = c4[q];
    cnt += (fkey(v.x) >= T) + (fkey(v.y) >= T) + (fkey(v.z) >= T) + (fkey(v.w) >= T);
  }
  for (int d = 32; d > 0; d >>= 1) cnt += (unsigned int)__shfl_xor((int)cnt, d, 64);
  if (lane == 0) wcnt[wid] = cnt;
  __syncthreads();
  if (tid == 0) {
    unsigned int tot = wcnt[0] + wcnt[1] + wcnt[2] + wcnt[3];
    unsigned int base = tot ? atomicAdd(&P.ccount[bl * 256], tot) : 0u;
    unsigned int acc = base;
    for (int w = 0; w < 4; ++w) { unsigned int x = wcnt[w]; wbase[w] = acc; acc += x; }
  }
  __syncthreads();
  unsigned int off = wbase[wid];
  unsigned long long lmlt = (1ull << lane) - 1ull;
  for (int q = q0 + tid; q < q1; q += 256) {
    float4 v = c4[q];
    unsigned int u[4] = {fkey(v.x), fkey(v.y), fkey(v.z), fkey(v.w)};
    #pragma unroll
    for (int k = 0; k < 4; ++k) {
      bool pred = (u[k] >= T);
      unsigned long long m = __ballot(pred);
      if (pred) {
        unsigned int pos = off + (unsigned int)__popcll(m & lmlt);
        if (pos < (unsigned int)kCandMax) {
          unsigned int idx = (unsigned int)(q * 4 + k);
          cand[pos] = ((unsigned long long)u[k] << 32) |
                      (unsigned long long)(0xFFFFFFFFu - idx);
        }
      }
      off += (unsigned int)__popcll(m);
    }
  }
}

// -- Phase 1d: sort, decode+clip, write valid-partitioned keyC (40 blocks) --
__global__ __launch_bounds__(1024) void k_select(RPNParams P) {
  int bl = blockIdx.x, b = bl / 5, l = bl % 5;
  int N = c_N[l], K = c_K[l];
  const float* ctr = P.ctr[l] + (size_t)b * N;
  __shared__ unsigned long long cand[kCandMax];
  __shared__ unsigned int wsum[16];
  __shared__ unsigned int sTot;
  int tid = threadIdx.x;
  int lane = tid & 63, wid = tid >> 6;
  int cc = (int)P.ccount[bl * 256]; if (cc > kCandMax) cc = kCandMax;
  const unsigned long long* gc = P.cand + (size_t)bl * kCandMax;
  for (int i = tid; i < cc; i += 1024) cand[i] = gc[i];
  int n2 = 1; while (n2 < cc) n2 <<= 1;
  for (int i = cc + tid; i < n2; i += 1024) cand[i] = 0ull;
  __syncthreads();
  // bitonic sort descending by (key desc, idx asc) composite
  for (int size = 2; size <= n2; size <<= 1) {
    for (int stride = size >> 1; stride > 0; stride >>= 1) {
      for (int i = tid; i < n2; i += 1024) {
        int j = i ^ stride;
        if (j > i) {
          unsigned long long a = cand[i], c2 = cand[j];
          bool sw = ((i & size) == 0) ? (a < c2) : (a > c2);
          if (sw) { cand[i] = c2; cand[j] = a; }
        }
      }
      __syncthreads();
    }
  }
  size_t sbase = ((size_t)b * 5 + l) * 1024;
  int r = tid;  // K <= 1000 < 1024: single round
  unsigned long long kc = 0ull;
  bool flag = false;
  if (r < K) {
    unsigned long long cv = cand[r];
    unsigned int idx = 0xFFFFFFFFu - (unsigned int)(cv & 0xFFFFFFFFu);
    float s = ctr[idx];
    float4 anc = *(const float4*)(P.anchors[l] + (size_t)idx * 4);
    float4 dd  = *(const float4*)(P.deltas[l] + ((size_t)b * N + idx) * 4);
    // Box2BoxTransformLinear decode (same op order as reference, no fma)
    float w = anc.z - anc.x, hgt = anc.w - anc.y;
    float cx = (anc.x + anc.z) * 0.5f, cy = (anc.y + anc.w) * 0.5f;
    float x1 = cx - dd.x * w;
    float y1 = cy - dd.y * hgt;
    float x2 = cx + dd.z * w;
    float y2 = cy + dd.w * hgt;
    x1 = fminf(fmaxf(x1, 0.0f), 1024.0f);
    y1 = fminf(fmaxf(y1, 0.0f), 1024.0f);
    x2 = fminf(fmaxf(x2, 0.0f), 1024.0f);
    y2 = fminf(fmaxf(y2, 0.0f), 1024.0f);
    bool valid = ((x2 - x1) > 0.0f) && ((y2 - y1) > 0.0f);
    float sc = valid ? s : -INFINITY;
    P.scores[sbase + r] = sc;
    *(float4*)(P.boxes + (sbase + r) * 4) = make_float4(x1, y1, x2, y2);
    unsigned int fk = fkey(sc);
    flag = fk > 0x007FFFFFu;  // score > -inf
    unsigned int cidx = (unsigned int)(l * 1000 + r);
    kc = ((unsigned long long)fk << 32) |
         (unsigned long long)(0xFFFFFFFFu - cidx);
  }
  // stable partition (valid first) -> keyC, strictly descending composite
  unsigned int fv = flag ? 1u : 0u, v = fv;
  for (int d = 1; d < 64; d <<= 1) {
    unsigned int n = __shfl_up(v, (unsigned int)d, 64);
    if (lane >= d) v += n;
  }
  if (lane == 63) wsum[wid] = v;
  __syncthreads();
  if (tid == 0) {
    unsigned int acc = 0;
    for (int w = 0; w < 16; ++w) { unsigned int x = wsum[w]; wsum[w] = acc; acc += x; }
    sTot = acc;
  }
  __syncthreads();
  unsigned int excl = wsum[wid] + (v - fv);
  if (r < K) {
    unsigned int dest = flag ? excl : (sTot + ((unsigned int)r - excl));
    P.keyC[(size_t)bl * 1024 + dest] = kc;
  }
}

// ---------------- Phase 2a: suppression bitmask (per level) ---------------
// 4 waves/block share staging; 16-way column split (10240 waves). Words above
// the row's own 64-pair need NO direction test (j > i always); the own pair
// stores TRANSPOSED (j < i) bits via per-lane constant masks. Predicate is
// division-free exact: RN32(inter/uni) > 0.7f <=> (double)inter >= M*uni,
// M = 0.7f + 2^-25 (25x24-bit product exact in double; tie -> even > 0.7f).
__global__ __launch_bounds__(256) void k_mask(RPNParams P) {
  int bl = blockIdx.x, b = bl / 5, l = bl % 5;
  int K = c_K[l];
  int tid = threadIdx.x;
  int lane = tid & 63;
  int yg = blockIdx.y * 4 + (tid >> 6);   // row-group 0..15
  int zc = blockIdx.z;                    // column sixteenth 0..15
  float off = (float)l * 1025.0f;  // lvl * (IMG + 1) — replicate offset rounding!
  size_t sbase = ((size_t)b * 5 + l) * 1024;
  __shared__ alignas(16) float4 obox[1024];
  __shared__ float area[1024];
  for (int i = tid; i < 1024; i += 256) {
    float4 v = make_float4(0.f, 0.f, 0.f, 0.f);
    if (i < K) {
      v = ((const float4*)P.boxes)[sbase + i];
      v.x += off; v.y += off; v.z += off; v.w += off;
    }
    obox[i] = v;
    area[i] = fmaxf(v.z - v.x, 0.0f) * fmaxf(v.w - v.y, 0.0f);
  }
  __syncthreads();
  int i = yg * 64 + lane;
  if (i >= K) return;  // after the barrier; no further barriers below
  float4 bi = obox[i];
  float ai = area[i];
  unsigned int* mrow = P.mask + (sbase + (size_t)i) * 32;
  const double M = 0x1.666667p-1;  // 0.7f + 2^-25
  auto pr = [&](int j) -> bool {
    float4 bj = obox[j];
    float aj = area[j];
    float xx1 = fmaxf(bi.x, bj.x);
    float yy1 = fmaxf(bi.y, bj.y);
    float xx2 = fminf(bi.z, bj.z);
    float yy2 = fminf(bi.w, bj.w);
    float ww = fmaxf(xx2 - xx1, 0.0f);
    float hh = fmaxf(yy2 - yy1, 0.0f);
    float inter = ww * hh;
    float uni = ai + aj - inter + 1e-8f;  // ((ai+aj)-inter)+eps, f32 order
    return (double)inter >= M * (double)uni;
  };
  int wown = 2 * yg;
  if (zc == 0) {
    for (int w = 0; w < wown; ++w) mrow[w] = 0u;  // low words: all j < own pair
    // own word pair: transposed (j < i) bits
    unsigned int m0, m1;
    if (lane < 32) { m0 = (1u << lane) - 1u; m1 = 0u; }
    else           { m0 = 0xFFFFFFFFu; m1 = (1u << (lane - 32)) - 1u; }
    #pragma unroll
    for (int h = 0; h < 2; ++h) {
      unsigned int bits = 0u;
      int j0 = (wown + h) << 5;
      for (int jj = 0; jj < 32; ++jj)
        if (pr(j0 + jj)) bits |= (1u << jj);
      mrow[wown + h] = bits & (h ? m1 : m0);
    }
  }
  int wstart = wown + 2;
  int nw = 32 - wstart;
  int qlen = (nw + 15) >> 4;
  int wbeg = wstart + zc * qlen;
  int wend = wbeg + qlen; if (wend > 32) wend = 32;
  for (int w = wbeg; w < wend; ++w) {
    unsigned int bits = 0u;
    int j0 = w << 5;
    for (int jj = 0; jj < 32; ++jj)
      if (pr(j0 + jj)) bits |= (1u << jj);  // j > i guaranteed (w > own pair)
    mrow[w] = bits;
  }
}

// ---------------- Phase 2b: greedy sweep, parallel peel -------------------
__global__ __launch_bounds__(1024) void k_sweep(RPNParams P) {
  int bl = blockIdx.x, b = bl / 5, l = bl % 5;
  int K = c_K[l];
  int NW = (K + 63) >> 6;
  size_t sbase = ((size_t)b * 5 + l) * 1024;
  __shared__ alignas(16) unsigned long long lmask[16 * 1000];  // 125 KiB [row][16]
  __shared__ unsigned long long rdiag[1024];  // colmask per row (earlier in-word)
  __shared__ unsigned long long svalid[16];
  __shared__ unsigned long long skept[16];
  int tid = threadIdx.x;
  const ulonglong2* gm2 = (const ulonglong2*)(P.mask + sbase * 32);
  for (int j = tid; j < K * 8; j += 1024) {
    ulonglong2 v = gm2[j];
    ((ulonglong2*)lmask)[j] = v;
    int w0i = j * 2;       // u64 index within the matrix
    int row = w0i >> 4;
    int dcol = row >> 6;   // the row's own-word u64 slot
    int col0 = w0i & 15;
    if (col0 == dcol) rdiag[row] = v.x;
    else if (col0 + 1 == dcol) rdiag[row] = v.y;
  }
  // valid ballots computed by all 16 waves in parallel (wave g -> word g)
  {
    int g = tid >> 6;
    int e = g * 64 + (tid & 63);
    bool pred = (e < K) && (P.scores[sbase + e] > -INFINITY);
    unsigned long long m = __ballot(pred);
    if ((tid & 63) == 0) svalid[g] = m;
  }
  __syncthreads();
  if (tid >= 64) return;  // single wave from here; no further barriers
  int lane = tid;
  int sub = lane >> 4, col = lane & 15;
  unsigned long long accA = 0ull, accB = 0ull;  // per-lane partial OR of kept rows
  for (int g = 0; g < NW; ++g) {
    // combine the 4 subset-partials for column g (lanes g, g+16, g+32, g+48)
    unsigned long long am = accA | accB;
    unsigned long long suppr = readlane64(am, g) | readlane64(am, g + 16) |
                               readlane64(am, g + 32) | readlane64(am, g + 48);
    unsigned long long A = svalid[g] & ~suppr;   // alive set (wave-uniform value)
    unsigned long long colmask = rdiag[g * 64 + lane];  // earlier in-word suppressors
    unsigned long long kept = 0ull;
    while (A) {  // level-synchronous peel == sequential greedy
      bool cand = (A >> lane) & 1ull;
      unsigned long long D = __ballot(cand && ((colmask & A) == 0ull));
      kept |= D;
      unsigned long long sup = __ballot((colmask & D) != 0ull);
      A &= ~(D | sup);
    }
    if (lane == 0) skept[g] = kept;
    // static unrolled OR of kept rows into per-lane acc (columns for later words)
    const unsigned long long* rowbase = &lmask[((size_t)g * 64 + (size_t)sub) * 16 + col];
    #pragma unroll
    for (int t = 0; t < 8; ++t) {
      int p0 = (2 * t) * 4 + sub;
      int p1 = (2 * t + 1) * 4 + sub;
      unsigned long long s0 = 0ull - ((kept >> p0) & 1ull);
      unsigned long long s1 = 0ull - ((kept >> p1) & 1ull);
      accA |= rowbase[(size_t)(2 * t) * 64] & s0;
      accB |= rowbase[(size_t)(2 * t + 1) * 64] & s1;
    }
  }
  for (int g = 0; g < NW; ++g) {
    unsigned long long kv = skept[g];
    int e = g * 64 + lane;
    if (e < K) P.keep[sbase + e] = (unsigned char)((kv >> lane) & 1ull);
  }
}

// ------- Phase 3: per-image 5-way merge-by-rank + keep-partition + out ----
__global__ __launch_bounds__(1024) void k_merge(RPNParams P) {
  int b = blockIdx.x;
  __shared__ unsigned long long keyL[5][1000];  // 40 KB, strictly desc per level
  __shared__ unsigned short srt[4768];          // rank -> concat idx
  __shared__ unsigned int wsum[16];
  __shared__ unsigned int sTot;
  int tid = threadIdx.x;
  int lane = tid & 63, wid = tid >> 6;

  // ---- Step 1: load pre-partitioned keys (from k_select) ----
  #pragma unroll
  for (int l = 0; l < 5; ++l)
    if (tid < c_K[l]) keyL[l][tid] = P.keyC[((size_t)b * 5 + l) * 1024 + tid];
  __syncthreads();

  // ---- Step 2: global rank via binary search in the other 4 lists ----
  for (int e = tid; e < 4768; e += 1024) {
    int l = (e < 4000) ? (e / 1000) : 4;
    int p = e - l * 1000;
    unsigned long long k = keyL[l][p];
    int rank = p;
    #pragma unroll
    for (int l2 = 0; l2 < 5; ++l2) {
      if (l2 == l) continue;
      int lo = 0, hi = c_K[l2];
      while (lo < hi) {
        int mid = (lo + hi) >> 1;
        if (keyL[l2][mid] > k) lo = mid + 1; else hi = mid;
      }
      rank += lo;
    }
    srt[rank] = (unsigned short)(0xFFFFFFFFu - (unsigned int)(k & 0xFFFFFFFFu));
  }
  __syncthreads();

  // ---- Step 3: keep flags for 5 contiguous sorted slots per thread ----
  int base = tid * 5;
  unsigned char lf[5];
  unsigned short lc[5];
  unsigned int lsum = 0;
  for (int q = 0; q < 5; ++q) {
    int i = base + q;
    unsigned char f = 0; unsigned short cx = 0;
    if (i < 4768) {
      cx = srt[i];
      int l = cx / 1000;
      int r = (int)cx - l * 1000;
      f = P.keep[((size_t)b * 5 + l) * 1024 + r];
    }
    lf[q] = f; lc[q] = cx; lsum += f;
  }
  unsigned int v = lsum;
  for (int d = 1; d < 64; d <<= 1) {
    unsigned int n = __shfl_up(v, (unsigned int)d, 64);
    if (lane >= d) v += n;
  }
  if (lane == 63) wsum[wid] = v;
  __syncthreads();
  if (tid == 0) {
    unsigned int acc = 0;
    for (int w = 0; w < 16; ++w) { unsigned int x = wsum[w]; wsum[w] = acc; acc += x; }
    sTot = acc;
  }
  __syncthreads();
  unsigned int excl = wsum[wid] + (v - lsum);  // kept count before slot `base`
  unsigned int tot = sTot;
  for (int q = 0; q < 5; ++q) {
    int i = base + q;
    if (i >= 4768) break;
    unsigned int cidx = (unsigned int)lc[q];
    int l = (int)(cidx / 1000u);
    int r = (int)cidx - l * 1000;
    size_t sb = ((size_t)b * 5 + l) * 1024 + r;
    unsigned char f = lf[q];
    unsigned int pos = f ? excl : (tot + ((unsigned int)i - excl));
    excl += f;
    if (pos < 1000u) {
      float4 bx = ((const float4*)P.boxes)[sb];
      float sc = f ? P.scores[sb] : -INFINITY;
      float* o = P.out + ((size_t)b * 1000 + pos) * 5;
      o[0] = bx.x; o[1] = bx.y; o[2] = bx.z; o[3] = bx.w; o[4] = sc;
    }
  }
}

}  // namespace

extern "C" void kernel_launch(void* const* d_in, const int* in_sizes, int n_in,
                              void* d_out, int out_size, void* d_ws, size_t ws_size,
                              hipStream_t stream) {
  (void)out_size; (void)ws_size;
  RPNParams P;
  bool interleaved = (n_in >= 3) && (in_sizes[2] == 786432);
  for (int l = 0; l < 5; ++l) {
    if (interleaved) {
      P.deltas[l]  = (const float*)d_in[3 * l + 0];
      P.ctr[l]     = (const float*)d_in[3 * l + 1];
      P.anchors[l] = (const float*)d_in[3 * l + 2];
    } else {
      P.deltas[l]  = (const float*)d_in[l];
      P.ctr[l]     = (const float*)d_in[5 + l];
      P.anchors[l] = (const float*)d_in[10 + l];
    }
  }
  char* ws = (char*)d_ws;
  P.scores = (float*)(ws + 0);                    // 163840 B
  P.boxes  = (float*)(ws + 163840);               // 655360 B
  P.keep   = (unsigned char*)(ws + 819200);       // 40960 B
  P.mask   = (unsigned int*)(ws + 860160);        // 5242880 B
  // aliases inside the mask region (all used strictly before k_mask writes):
  P.cand   = (unsigned long long*)(ws + 860160);  // 1310720 B
  P.g0p    = (unsigned int*)(ws + 2170880);       // 1310720 B
  P.g1p    = (unsigned int*)(ws + 3481600);       // 1310720 B
  // small control arrays (all rewritten every launch; no init needed):
  P.ccount = (unsigned int*)(ws + 6103040);       // 40 entries at stride 256 u32
  P.v0kk   = (unsigned int*)(ws + 6144000);       // 320 B
  P.keyC   = (unsigned long long*)(ws + 6144320); // 327680 B
  P.out    = (float*)d_out;

  hipLaunchKernelGGL(k_hist0, dim3(40, 32), dim3(256), 0, stream, P);
  hipLaunchKernelGGL(k_hist1, dim3(40, 32), dim3(256), 0, stream, P);
  hipLaunchKernelGGL(k_compact, dim3(40, 32), dim3(256), 0, stream, P);
  hipLaunchKernelGGL(k_select, dim3(40), dim3(1024), 0, stream, P);
  hipLaunchKernelGGL(k_mask, dim3(40, 4, 16), dim3(256), 0, stream, P);
  hipLaunchKernelGGL(k_sweep, dim3(40), dim3(1024), 0, stream, P);
  hipLaunchKernelGGL(k_merge, dim3(8), dim3(1024), 0, stream, P);
}